// Round 17
// baseline (2101.594 us; speedup 1.0000x reference)
//
#include <hip/hip_runtime.h>
#include <math.h>

#define BB 2
#define NSEQ 4096
#define N1 4097
#define NPAD 4352
#define PADR 255
#define DIM 512
#define NH 8
#define DH 64
#define LM 256
#define NT 1536

typedef short bf16x8 __attribute__((ext_vector_type(8)));
typedef float f32x4 __attribute__((ext_vector_type(4)));

__device__ __forceinline__ unsigned short f2bf(float x){
  unsigned int u = __float_as_uint(x);
  unsigned int r = (u + 0x7FFFu + ((u >> 16) & 1u)) >> 16;
  return (unsigned short)r;
}
__device__ __forceinline__ float bf2f(unsigned short h){
  return __uint_as_float(((unsigned int)h) << 16);
}

// ---------------- block reduce helpers (blockDim.x == 256) ----------------
__device__ __forceinline__ float blk_sum(float v, float* red){
  int t = threadIdx.x;
  red[t] = v; __syncthreads();
  for (int s = 128; s > 0; s >>= 1){ if (t < s) red[t] += red[t+s]; __syncthreads(); }
  float r = red[0]; __syncthreads(); return r;
}
__device__ __forceinline__ float blk_max(float v, float* red){
  int t = threadIdx.x;
  red[t] = v; __syncthreads();
  for (int s = 128; s > 0; s >>= 1){ if (t < s) red[t] = fmaxf(red[t], red[t+s]); __syncthreads(); }
  float r = red[0]; __syncthreads(); return r;
}
__device__ __forceinline__ double blk_sumd(double v, double* red){
  int t = threadIdx.x;
  red[t] = v; __syncthreads();
  for (int s = 128; s > 0; s >>= 1){ if (t < s) red[t] += red[t+s]; __syncthreads(); }
  double r = red[0]; __syncthreads(); return r;
}

// ---------------- MFMA split-bf16 GEMM: C = act(A @ W^T + bias + res) ----------------
// LDS-staged, BK=64, XCD-aware bijective block swizzle (m204). K % 64 == 0, N % 128 == 0.
__global__ __launch_bounds__(256) void gemm_mfma(
    const unsigned short* __restrict__ Ah, const unsigned short* __restrict__ Al,
    const unsigned short* __restrict__ Wh, const unsigned short* __restrict__ Wl,
    const float* __restrict__ bias, const float* __restrict__ res,
    float* __restrict__ C, int M, int N, int K, int act,
    unsigned short* __restrict__ outH, unsigned short* __restrict__ outL)
{
  __shared__ unsigned short AsH[128][72], AsL[128][72], BsH[128][72], BsL[128][72];
  int t = threadIdx.x;
  int w = t >> 6, l = t & 63;
  int wr = w >> 1, wc = w & 1;
  // XCD-aware bijective swizzle of linear block id (contiguous chunk per XCD)
  int nbx = gridDim.x;
  int nwg = nbx * gridDim.y;
  int bid = blockIdx.y * nbx + blockIdx.x;
  int q = nwg >> 3, rr = nwg & 7;
  int xcd = bid & 7, pos = bid >> 3;
  int sbid = ((xcd < rr) ? (xcd * (q + 1)) : (rr * (q + 1) + (xcd - rr) * q)) + pos;
  int bx = sbid % nbx, by = sbid / nbx;
  int rowBase = by * 128;
  int colBase = bx * 128;
  int row0 = rowBase + wr * 64;
  int col0 = colBase + wc * 64;
  int lr = l & 15;
  int lk = (l >> 4) << 3;
  f32x4 acc[4][4];
  #pragma unroll
  for (int i = 0; i < 4; ++i)
    #pragma unroll
    for (int j = 0; j < 4; ++j) acc[i][j] = (f32x4){0.f, 0.f, 0.f, 0.f};

  for (int ks = 0; ks < K; ks += 64) {
    // stage A/B 128x64 (H+L): 1024 ushort8 chunks per matrix, 4 per thread
    #pragma unroll
    for (int u = 0; u < 4; ++u) {
      int i = t + u * 256;                 // 0..1023
      int r8 = i >> 3, c8 = (i & 7) << 3;  // row 0..127, col {0,8,...,56}
      int ga = rowBase + r8; ga = (ga < M) ? ga : (M - 1);
      size_t ao = (size_t)ga * K + ks + c8;
      *(bf16x8*)&AsH[r8][c8] = *(const bf16x8*)(Ah + ao);
      *(bf16x8*)&AsL[r8][c8] = *(const bf16x8*)(Al + ao);
      int gb = colBase + r8;
      size_t bo = (size_t)gb * K + ks + c8;
      *(bf16x8*)&BsH[r8][c8] = *(const bf16x8*)(Wh + bo);
      *(bf16x8*)&BsL[r8][c8] = *(const bf16x8*)(Wl + bo);
    }
    __syncthreads();
    #pragma unroll
    for (int s = 0; s < 2; ++s) {
      int ko = lk + s * 32;
      bf16x8 ah[4], al4[4], bh[4], bl4[4];
      #pragma unroll
      for (int i = 0; i < 4; ++i) {
        ah[i]  = *(const bf16x8*)&AsH[wr*64 + i*16 + lr][ko];
        al4[i] = *(const bf16x8*)&AsL[wr*64 + i*16 + lr][ko];
        bh[i]  = *(const bf16x8*)&BsH[wc*64 + i*16 + lr][ko];
        bl4[i] = *(const bf16x8*)&BsL[wc*64 + i*16 + lr][ko];
      }
      #pragma unroll
      for (int i = 0; i < 4; ++i)
        #pragma unroll
        for (int j = 0; j < 4; ++j) {
          acc[i][j] = __builtin_amdgcn_mfma_f32_16x16x32_bf16(ah[i],  bh[j],  acc[i][j], 0, 0, 0);
          acc[i][j] = __builtin_amdgcn_mfma_f32_16x16x32_bf16(ah[i],  bl4[j], acc[i][j], 0, 0, 0);
          acc[i][j] = __builtin_amdgcn_mfma_f32_16x16x32_bf16(al4[i], bh[j],  acc[i][j], 0, 0, 0);
        }
    }
    __syncthreads();
  }
  int crb = (l >> 4) << 2;
  #pragma unroll
  for (int i = 0; i < 4; ++i)
    #pragma unroll
    for (int r = 0; r < 4; ++r) {
      int row = row0 + i * 16 + crb + r;
      if (row >= M) continue;
      #pragma unroll
      for (int j = 0; j < 4; ++j) {
        int col = col0 + j * 16 + lr;
        float v = acc[i][j][r];
        if (bias) v += bias[col];
        if (res)  v += res[(size_t)row * N + col];
        if (act == 1) v = fmaxf(v, 0.f);
        else if (act == 2) v = (v >= 0.f) ? v : 0.01f * v;
        size_t o = (size_t)row * N + col;
        C[o] = v;
        if (outH) {
          unsigned short hh = f2bf(v);
          outH[o] = hh;
          outL[o] = f2bf(v - bf2f(hh));
        }
      }
    }
}

// ---------------- batched(16) MFMA split-bf16 mm for the pinv chain ----------------
__global__ __launch_bounds__(64) void mm_mfma(
    const unsigned short* __restrict__ AH, const unsigned short* __restrict__ AL,
    const unsigned short* __restrict__ BTH, const unsigned short* __restrict__ BTL,
    unsigned short* __restrict__ CH, unsigned short* __restrict__ CL,
    unsigned short* __restrict__ CTH, unsigned short* __restrict__ CTL,
    unsigned short* __restrict__ DTH, unsigned short* __restrict__ DTL,
    float* __restrict__ C32,
    int N, float alpha, float diag, float diag2)
{
  int bh = blockIdx.z;
  size_t offA  = (size_t)bh * 65536;
  size_t offBT = (size_t)bh * N * 256;
  size_t offC  = (size_t)bh * 256 * N;
  size_t offT  = (size_t)bh * 65536;
  int l = threadIdx.x;
  int lr = l & 15, lk = (l >> 4) << 3;
  int row0 = blockIdx.y * 32, col0 = blockIdx.x * 32;
  f32x4 acc[2][2];
  #pragma unroll
  for (int i = 0; i < 2; ++i)
    #pragma unroll
    for (int j = 0; j < 2; ++j) acc[i][j] = (f32x4){0.f,0.f,0.f,0.f};

  bf16x8 A0h[2], A0l[2], B0h[2], B0l[2];
  bf16x8 A1h[2], A1l[2], B1h[2], B1l[2];

#define LDF2(AH_, AL_, BH_, BL_, KS) do {                              \
    _Pragma("unroll")                                                  \
    for (int i = 0; i < 2; ++i) {                                      \
      size_t ao = offA + (size_t)(row0 + i*16 + lr) * 256 + (KS) + lk; \
      AH_[i] = *(const bf16x8*)(AH + ao);                              \
      AL_[i] = *(const bf16x8*)(AL + ao);                              \
      size_t bo = offBT + (size_t)(col0 + i*16 + lr) * 256 + (KS) + lk;\
      BH_[i] = *(const bf16x8*)(BTH + bo);                             \
      BL_[i] = *(const bf16x8*)(BTL + bo);                             \
    } } while (0)

#define DOMFMA2(AH_, AL_, BH_, BL_) do {                               \
    _Pragma("unroll")                                                  \
    for (int i = 0; i < 2; ++i)                                        \
      _Pragma("unroll")                                                \
      for (int j = 0; j < 2; ++j) {                                    \
        acc[i][j] = __builtin_amdgcn_mfma_f32_16x16x32_bf16(AH_[i], BH_[j], acc[i][j], 0,0,0); \
        acc[i][j] = __builtin_amdgcn_mfma_f32_16x16x32_bf16(AH_[i], BL_[j], acc[i][j], 0,0,0); \
        acc[i][j] = __builtin_amdgcn_mfma_f32_16x16x32_bf16(AL_[i], BH_[j], acc[i][j], 0,0,0); \
      } } while (0)

  LDF2(A0h, A0l, B0h, B0l, 0);
  for (int ks = 0; ks < 256; ks += 64) {
    LDF2(A1h, A1l, B1h, B1l, ks + 32);
    DOMFMA2(A0h, A0l, B0h, B0l);
    if (ks + 64 < 256) LDF2(A0h, A0l, B0h, B0l, ks + 64);
    DOMFMA2(A1h, A1l, B1h, B1l);
  }
#undef LDF2
#undef DOMFMA2

  int crb = (l >> 4) << 2;
  #pragma unroll
  for (int i = 0; i < 2; ++i) {
    int rbase = row0 + i*16 + crb;
    #pragma unroll
    for (int j = 0; j < 2; ++j) {
      int colg = col0 + j*16 + lr;
      float v[4];
      #pragma unroll
      for (int r = 0; r < 4; ++r)
        v[r] = alpha * acc[i][j][r] + (((rbase + r) == colg) ? diag : 0.f);
      if (C32) {
        #pragma unroll
        for (int r = 0; r < 4; ++r) C32[offC + (size_t)(rbase + r) * N + colg] = v[r];
      }
      if (CH) {
        #pragma unroll
        for (int r = 0; r < 4; ++r) {
          unsigned short hh = f2bf(v[r]);
          CH[offC + (size_t)(rbase + r) * N + colg] = hh;
          CL[offC + (size_t)(rbase + r) * N + colg] = f2bf(v[r] - bf2f(hh));
        }
      }
      if (CTH) {
        ushort4 th, tl;
        unsigned short* ph = (unsigned short*)&th;
        unsigned short* pl = (unsigned short*)&tl;
        #pragma unroll
        for (int r = 0; r < 4; ++r) { ph[r] = f2bf(v[r]); pl[r] = f2bf(v[r] - bf2f(ph[r])); }
        *(ushort4*)&CTH[offT + (size_t)colg * 256 + rbase] = th;
        *(ushort4*)&CTL[offT + (size_t)colg * 256 + rbase] = tl;
      }
      if (DTH) {
        ushort4 th, tl;
        unsigned short* ph = (unsigned short*)&th;
        unsigned short* pl = (unsigned short*)&tl;
        #pragma unroll
        for (int r = 0; r < 4; ++r) {
          float dv = (((rbase + r) == colg) ? diag2 : 0.f) - v[r];
          ph[r] = f2bf(dv); pl[r] = f2bf(dv - bf2f(ph[r]));
        }
        *(ushort4*)&DTH[offT + (size_t)colg * 256 + rbase] = th;
        *(ushort4*)&DTL[offT + (size_t)colg * 256 + rbase] = tl;
      }
    }
  }
}

// elementwise split fp32 -> (hi, lo) bf16; n4 = count/4
__global__ void split_k(const float* __restrict__ src, unsigned short* __restrict__ dh,
                        unsigned short* __restrict__ dl, int n4){
  int i = blockIdx.x * 256 + threadIdx.x;
  if (i >= n4) return;
  float4 v = ((const float4*)src)[i];
  ushort4 H, L;
  H.x = f2bf(v.x); L.x = f2bf(v.x - bf2f(H.x));
  H.y = f2bf(v.y); L.y = f2bf(v.y - bf2f(H.y));
  H.z = f2bf(v.z); L.z = f2bf(v.z - bf2f(H.z));
  H.w = f2bf(v.w); L.w = f2bf(v.w - bf2f(H.w));
  ((ushort4*)dh)[i] = H;
  ((ushort4*)dl)[i] = L;
}

// split K columns of qkv (cols 512..1024) into compact [row][512] hi/lo
__global__ void split_kcols(const float* __restrict__ qkv,
                            unsigned short* __restrict__ dh, unsigned short* __restrict__ dl){
  size_t idx = (size_t)blockIdx.x * 256 + threadIdx.x;   // BB*NPAD*128 total
  size_t row = idx >> 7;
  int c4 = (int)(idx & 127) << 2;
  float4 v = *(const float4*)&qkv[row * NT + 512 + c4];
  ushort4 H, L;
  H.x = f2bf(v.x); L.x = f2bf(v.x - bf2f(H.x));
  H.y = f2bf(v.y); L.y = f2bf(v.y - bf2f(H.y));
  H.z = f2bf(v.z); L.z = f2bf(v.z - bf2f(H.z));
  H.w = f2bf(v.w); L.w = f2bf(v.w - bf2f(H.w));
  *(ushort4*)&dh[row * 512 + c4] = H;
  *(ushort4*)&dl[row * 512 + c4] = L;
}

// transpose-split V: VT[bh][d][n] hi/lo; grid (NPAD/64, 16)
__global__ __launch_bounds__(256) void transpose_split_v(const float* __restrict__ qkv,
    unsigned short* __restrict__ VTH, unsigned short* __restrict__ VTL){
  __shared__ float tile[64][65];
  int bh = blockIdx.y;
  int n0 = blockIdx.x * 64;
  int b = bh >> 3, hh = bh & 7;
  int t = threadIdx.x;
  for (int i = t; i < 4096; i += 256) {
    int r = i >> 6, c = i & 63;
    tile[r][c] = qkv[((size_t)b * NPAD + n0 + r) * NT + 1024 + hh * 64 + c];
  }
  __syncthreads();
  for (int i = t; i < 4096; i += 256) {
    int d = i >> 6, n = i & 63;
    float v = tile[n][d];
    unsigned short hv = f2bf(v);
    size_t o = ((size_t)bh * 64 + d) * NPAD + n0 + n;
    VTH[o] = hv; VTL[o] = f2bf(v - bf2f(hv));
  }
}

// z0 = a2^T * s : write z (normal, hi/lo) and zT (hi/lo).
__global__ void z0_split(const float* __restrict__ a2, const float* __restrict__ scal,
                         unsigned short* __restrict__ zH, unsigned short* __restrict__ zL,
                         unsigned short* __restrict__ zTH, unsigned short* __restrict__ zTL){
  size_t idx = (size_t)blockIdx.x * 256 + threadIdx.x;   // grid 4096
  size_t bh = idx >> 16;
  int rc = (int)(idx & 65535);
  int r = rc >> 8, c = rc & 255;
  float v = a2[idx] * scal[32];
  unsigned short hh = f2bf(v), ll = f2bf(v - bf2f(hh));
  zTH[idx] = hh; zTL[idx] = ll;
  size_t tidx = (bh << 16) + (size_t)c * 256 + r;
  zH[tidx] = hh; zL[tidx] = ll;
}

// src (bh,256,64) fp32 -> dst (bh,64,256) hi/lo  (used for av and zav)
__global__ void split_T_av(const float* __restrict__ av,
                           unsigned short* __restrict__ TH, unsigned short* __restrict__ TL){
  size_t idx = (size_t)blockIdx.x * 256 + threadIdx.x;   // grid 1024 (16*16384)
  size_t bh = idx >> 14;
  int md = (int)(idx & 16383);
  int m = md >> 6, d = md & 63;
  float v = av[idx];
  unsigned short hh = f2bf(v);
  size_t tix = (bh << 14) + (size_t)d * 256 + m;
  TH[tix] = hh; TL[tix] = f2bf(v - bf2f(hh));
}

// ---------------- LN + front zero-pad, emitting split-bf16 halves ----------------
__global__ __launch_bounds__(256) void ln_pad_split(const float* __restrict__ hsrc,
    unsigned short* __restrict__ dH, unsigned short* __restrict__ dL,
    const float* __restrict__ g, const float* __restrict__ bt){
  __shared__ double red[256];
  int row = blockIdx.x;
  int b = row / NPAD, r = row % NPAD;
  unsigned short* rh = dH + (size_t)row * DIM;
  unsigned short* rl = dL + (size_t)row * DIM;
  int t = threadIdx.x;
  if (r < PADR) { rh[t] = 0; rh[t+256] = 0; rl[t] = 0; rl[t+256] = 0; return; }
  const float* x = hsrc + ((size_t)b * N1 + (r - PADR)) * DIM;
  double x0 = (double)x[t], x1 = (double)x[t + 256];
  double mu = blk_sumd(x0 + x1, red) * (1.0/512.0);
  double d0 = x0 - mu, d1 = x1 - mu;
  double var = blk_sumd(d0*d0 + d1*d1, red) * (1.0/512.0);
  double inv = 1.0 / sqrt(var + 1e-5);
  float y0 = (float)(d0 * inv * (double)g[t]       + (double)bt[t]);
  float y1 = (float)(d1 * inv * (double)g[t + 256] + (double)bt[t + 256]);
  unsigned short h0 = f2bf(y0), h1 = f2bf(y1);
  rh[t] = h0;       rl[t] = f2bf(y0 - bf2f(h0));
  rh[t + 256] = h1; rl[t + 256] = f2bf(y1 - bf2f(h1));
}

// ---------------- landmarks: ql (scaled by 1/8), kl ----------------
__global__ void landmark(const float* __restrict__ qkv, float* __restrict__ ql, float* __restrict__ kl){
  int blk = blockIdx.x;            // bh*256 + m
  int bh = blk >> 8, m = blk & 255;
  int b = bh >> 3, hh = bh & 7;
  int d = threadIdx.x;             // 64
  float sq = 0.f, sk = 0.f;
  for (int l = 0; l < 17; ++l) {
    size_t o = ((size_t)b * NPAD + m * 17 + l) * NT + hh * 64 + d;
    sq += qkv[o];
    sk += qkv[o + 512];
  }
  ql[((size_t)bh * 256 + m) * 64 + d] = 0.125f * sq / 17.f;
  kl[((size_t)bh * 256 + m) * 64 + d] = sk / 17.f;
}

// klT[bh][d][m] = kl[bh][m][d]; grid (LM/64, 16)
__global__ __launch_bounds__(256) void transpose_kl(const float* __restrict__ kl, float* __restrict__ klT){
  __shared__ float tile[64][65];
  int bh = blockIdx.y;
  int m0 = blockIdx.x * 64;
  int t = threadIdx.x;
  for (int i = t; i < 4096; i += 256) {
    int r = i >> 6, c = i & 63;
    tile[r][c] = kl[((size_t)bh * 256 + m0 + r) * 64 + c];
  }
  __syncthreads();
  float* kb = klT + (size_t)bh * 64 * 256;
  for (int i = t; i < 4096; i += 256) {
    int d = i >> 6, mm = i & 63;
    kb[(size_t)d * 256 + m0 + mm] = tile[mm][d];
  }
}

// ---------------- a2 = softmax(ql @ kl^T) ----------------
__global__ __launch_bounds__(256) void a2_kernel(const float* __restrict__ ql, const float* __restrict__ klT,
                                                 float* __restrict__ a2){
  __shared__ float qs[64]; __shared__ float red[256];
  int blk = blockIdx.x;            // bh*256 + i
  int bh = blk >> 8, i = blk & 255;
  int t = threadIdx.x;
  if (t < 64) qs[t] = ql[((size_t)bh * 256 + i) * 64 + t];
  __syncthreads();
  const float* kb = klT + (size_t)bh * 16384;
  float s = 0.f;
  #pragma unroll
  for (int d = 0; d < 64; ++d) s += qs[d] * kb[d * 256 + t];
  float mx = blk_max(s, red);
  float e = expf(s - mx);
  float sum = blk_sum(e, red);
  a2[((size_t)bh * 256 + i) * 256 + t] = e / sum;
}

// per-(b,h) max colsum / rowsum
__global__ __launch_bounds__(256) void colrow_max(const float* __restrict__ a2, float* __restrict__ scal){
  __shared__ float red[256];
  int bh = blockIdx.x, t = threadIdx.x;
  const float* A = a2 + (size_t)bh * 65536;
  float cs = 0.f, rs = 0.f;
  for (int i = 0; i < 256; ++i) cs += A[(size_t)i * 256 + t];
  for (int j = 0; j < 256; ++j) rs += A[(size_t)t * 256 + j];
  float cmax = blk_max(cs, red);
  float rmax = blk_max(rs, red);
  if (t == 0) { scal[bh] = cmax; scal[16 + bh] = rmax; }
}
__global__ void scal_red(float* scal){
  if (threadIdx.x == 0) {
    float cm = scal[0], rm = scal[16];
    for (int i = 1; i < 16; ++i) { cm = fmaxf(cm, scal[i]); rm = fmaxf(rm, scal[16 + i]); }
    scal[32] = 1.f / (rm * cm);
  }
}

// ================= flash-attention tiles (split-bf16 MFMA matmuls, fp32 online softmax) =================
// fa3v: Q=ql (64 rows/block), K from KsH/KsL [row][512], V^T from VTH/VTL [bh][64][NPAD].
// grid (17, 4, 16)
__global__ __launch_bounds__(256) void fa3v_kernel(const unsigned short* __restrict__ KsH,
                                                   const unsigned short* __restrict__ KsL,
                                                   const unsigned short* __restrict__ VTH,
                                                   const unsigned short* __restrict__ VTL,
                                                   const float* __restrict__ ql,
                                                   float* __restrict__ accp, float* __restrict__ mlp){
  int part = blockIdx.x, qt = blockIdx.y, bh = blockIdx.z;
  int b = bh >> 3, hh = bh & 7;
  int t = threadIdx.x;
  int w = t >> 6, l = t & 63;
  int lr = l & 15, lk = (l >> 4) << 3;
  int w16 = w * 16;
  int crb = (l >> 4) << 2;
  __shared__ unsigned short KH[64][72], KL[64][72];   // K [krow][d]; later V^T [d][krow]
  __shared__ unsigned short PH[64][72], PL[64][72];   // P [qrow][krow]
  __shared__ float Ss[64][68];
  __shared__ float redm[64][4];
  __shared__ float mrow[64], lrow[64], scales[64];
  bf16x8 qh[2], qlo[2];
  {
    const float* qrow = ql + ((size_t)bh * 256 + qt * 64 + w16 + lr) * 64;
    #pragma unroll
    for (int s = 0; s < 2; ++s) {
      #pragma unroll
      for (int e = 0; e < 8; ++e) {
        float v = qrow[s * 32 + lk + e];
        unsigned short hv = f2bf(v);
        qh[s][e]  = (short)hv;
        qlo[s][e] = (short)f2bf(v - bf2f(hv));
      }
    }
  }
  if (t < 64) { mrow[t] = -3.4e38f; lrow[t] = 0.f; }
  f32x4 acc[4];
  #pragma unroll
  for (int j = 0; j < 4; ++j) acc[j] = (f32x4){0.f,0.f,0.f,0.f};
  __syncthreads();
  int rr = t >> 2, sg = (t & 3) << 4;
  for (int tile = 0; tile < 4; ++tile) {
    int nbase = part * 256 + tile * 64;
    {
      const unsigned short* kbH = KsH + ((size_t)b * NPAD + nbase) * 512 + hh * 64;
      const unsigned short* kbL = KsL + ((size_t)b * NPAD + nbase) * 512 + hh * 64;
      #pragma unroll
      for (int u = 0; u < 2; ++u) {
        int i = t + u * 256;
        int r = i >> 3, c8 = (i & 7) << 3;
        *(bf16x8*)&KH[r][c8] = *(const bf16x8*)(kbH + (size_t)r * 512 + c8);
        *(bf16x8*)&KL[r][c8] = *(const bf16x8*)(kbL + (size_t)r * 512 + c8);
      }
    }
    __syncthreads();
    #pragma unroll
    for (int j = 0; j < 4; ++j) {
      f32x4 sf = (f32x4){0.f,0.f,0.f,0.f};
      #pragma unroll
      for (int s = 0; s < 2; ++s) {
        bf16x8 kh8 = *(const bf16x8*)&KH[j*16 + lr][s*32 + lk];
        bf16x8 kl8 = *(const bf16x8*)&KL[j*16 + lr][s*32 + lk];
        sf = __builtin_amdgcn_mfma_f32_16x16x32_bf16(qh[s],  kh8, sf, 0,0,0);
        sf = __builtin_amdgcn_mfma_f32_16x16x32_bf16(qh[s],  kl8, sf, 0,0,0);
        sf = __builtin_amdgcn_mfma_f32_16x16x32_bf16(qlo[s], kh8, sf, 0,0,0);
      }
      #pragma unroll
      for (int r = 0; r < 4; ++r) Ss[w16 + crb + r][j*16 + lr] = sf[r];
    }
    __syncthreads();   // S complete; K reads done
    {
      const unsigned short* vbH = VTH + (size_t)bh * 64 * NPAD + nbase;
      const unsigned short* vbL = VTL + (size_t)bh * 64 * NPAD + nbase;
      #pragma unroll
      for (int u = 0; u < 2; ++u) {
        int i = t + u * 256;
        int d = i >> 3, c8 = (i & 7) << 3;
        *(bf16x8*)&KH[d][c8] = *(const bf16x8*)(vbH + (size_t)d * NPAD + c8);
        *(bf16x8*)&KL[d][c8] = *(const bf16x8*)(vbL + (size_t)d * NPAD + c8);
      }
    }
    float lm = -3.4e38f;
    #pragma unroll
    for (int c = 0; c < 16; ++c) lm = fmaxf(lm, Ss[rr][sg + c]);
    redm[rr][t & 3] = lm;
    float mold = mrow[rr];
    float rm = fmaxf(fmaxf(redm[rr][0], redm[rr][1]), fmaxf(redm[rr][2], redm[rr][3]));
    float mnew = fmaxf(mold, rm);
    float sc_r = expf(mold - mnew);
    if ((t & 3) == 0) { scales[rr] = sc_r; mrow[rr] = mnew; }
    float ls = 0.f;
    #pragma unroll
    for (int c = 0; c < 16; ++c) {
      float p = expf(Ss[rr][sg + c] - mnew);
      unsigned short hv = f2bf(p);
      PH[rr][sg + c] = hv; PL[rr][sg + c] = f2bf(p - bf2f(hv));
      ls += p;
    }
    redm[rr][t & 3] = ls;
    __syncthreads();   // V^T staged, P split, scales ready
    if ((t & 3) == 0) lrow[rr] = lrow[rr] * sc_r + redm[rr][0]+redm[rr][1]+redm[rr][2]+redm[rr][3];
    {
      float s0 = scales[w16 + crb], s1 = scales[w16 + crb + 1],
            s2 = scales[w16 + crb + 2], s3 = scales[w16 + crb + 3];
      #pragma unroll
      for (int j = 0; j < 4; ++j) { acc[j][0]*=s0; acc[j][1]*=s1; acc[j][2]*=s2; acc[j][3]*=s3; }
    }
    bf16x8 pah[2], pal[2];
    #pragma unroll
    for (int s = 0; s < 2; ++s) {
      pah[s] = *(const bf16x8*)&PH[w16 + lr][s*32 + lk];
      pal[s] = *(const bf16x8*)&PL[w16 + lr][s*32 + lk];
    }
    #pragma unroll
    for (int j = 0; j < 4; ++j) {
      #pragma unroll
      for (int s = 0; s < 2; ++s) {
        bf16x8 vh = *(const bf16x8*)&KH[j*16 + lr][s*32 + lk];
        bf16x8 vl = *(const bf16x8*)&KL[j*16 + lr][s*32 + lk];
        acc[j] = __builtin_amdgcn_mfma_f32_16x16x32_bf16(pah[s], vh, acc[j], 0,0,0);
        acc[j] = __builtin_amdgcn_mfma_f32_16x16x32_bf16(pah[s], vl, acc[j], 0,0,0);
        acc[j] = __builtin_amdgcn_mfma_f32_16x16x32_bf16(pal[s], vh, acc[j], 0,0,0);
      }
    }
    __syncthreads();   // before next tile overwrites KH/PH
  }
  int blk = (bh * 4 + qt) * 17 + part;
  float* ap = accp + (size_t)blk * 4096;
  #pragma unroll
  for (int j = 0; j < 4; ++j)
    #pragma unroll
    for (int r = 0; r < 4; ++r)
      ap[(w16 + crb + r) * 64 + j*16 + lr] = acc[j][r];
  if (t < 64) { mlp[(size_t)blk*128 + t] = mrow[t]; mlp[(size_t)blk*128 + 64 + t] = lrow[t]; }
}

// combine 17 partials -> av ; grid 64 = bh*4+qt
__global__ __launch_bounds__(256) void fa3v_combine(const float* __restrict__ accp, const float* __restrict__ mlp,
                                                    float* __restrict__ av){
  int g = blockIdx.x;
  int t = threadIdx.x;
  int r = t >> 2, sg = (t & 3) << 4;
  int bh = g >> 2, qt = g & 3;
  float mp[17], lp[17];
  #pragma unroll
  for (int p = 0; p < 17; ++p) {
    mp[p] = mlp[(size_t)(g*17+p)*128 + r];
    lp[p] = mlp[(size_t)(g*17+p)*128 + 64 + r];
  }
  float M = mp[0];
  #pragma unroll
  for (int p = 1; p < 17; ++p) M = fmaxf(M, mp[p]);
  float w[17]; float L = 0.f;
  #pragma unroll
  for (int p = 0; p < 17; ++p) { w[p] = expf(mp[p] - M); L += w[p] * lp[p]; }
  float invL = 1.f / L;
  #pragma unroll
  for (int c = 0; c < 16; ++c) {
    float s = 0.f;
    #pragma unroll
    for (int p = 0; p < 17; ++p) s += w[p] * accp[(size_t)(g*17+p)*4096 + r*64 + sg + c];
    av[((size_t)(bh*256 + qt*64 + r))*64 + sg + c] = s * invL;
  }
}

// fa1: Q = qkv.q*0.125; K from klsH/L; V^T from zavTH/L. merged += P@V/l; emits merged splits.
// grid (68, 16)
__global__ __launch_bounds__(256) void fa1_kernel(const float* __restrict__ qkv,
                                                  const unsigned short* __restrict__ klsH,
                                                  const unsigned short* __restrict__ klsL,
                                                  const unsigned short* __restrict__ zavTH,
                                                  const unsigned short* __restrict__ zavTL,
                                                  float* __restrict__ merged,
                                                  unsigned short* __restrict__ merH,
                                                  unsigned short* __restrict__ merL){
  int nt = blockIdx.x, bh = blockIdx.y;
  int b = bh >> 3, hh = bh & 7;
  int t = threadIdx.x;
  int w = t >> 6, l = t & 63;
  int lr = l & 15, lk = (l >> 4) << 3;
  int w16 = w * 16;
  int crb = (l >> 4) << 2;
  int n0 = nt * 64;
  __shared__ unsigned short KH[64][72], KL[64][72];
  __shared__ unsigned short PH[64][72], PL[64][72];
  __shared__ float Ss[64][68];
  __shared__ float redm[64][4];
  __shared__ float mrow[64], lrow[64], scales[64];
  bf16x8 qh[2], qlo[2];
  {
    const float* qrow = qkv + ((size_t)b * NPAD + n0 + w16 + lr) * NT + hh * 64;
    #pragma unroll
    for (int s = 0; s < 2; ++s) {
      #pragma unroll
      for (int e = 0; e < 8; ++e) {
        float v = 0.125f * qrow[s * 32 + lk + e];
        unsigned short hv = f2bf(v);
        qh[s][e]  = (short)hv;
        qlo[s][e] = (short)f2bf(v - bf2f(hv));
      }
    }
  }
  if (t < 64) { mrow[t] = -3.4e38f; lrow[t] = 0.f; }
  f32x4 acc[4];
  #pragma unroll
  for (int j = 0; j < 4; ++j) acc[j] = (f32x4){0.f,0.f,0.f,0.f};
  __syncthreads();
  int rr = t >> 2, sg = (t & 3) << 4;
  for (int tile = 0; tile < 4; ++tile) {
    int mbase = tile * 64;
    {
      const unsigned short* kbH = klsH + ((size_t)bh * 256 + mbase) * 64;
      const unsigned short* kbL = klsL + ((size_t)bh * 256 + mbase) * 64;
      #pragma unroll
      for (int u = 0; u < 2; ++u) {
        int i = t + u * 256;
        int r = i >> 3, c8 = (i & 7) << 3;
        *(bf16x8*)&KH[r][c8] = *(const bf16x8*)(kbH + (size_t)r * 64 + c8);
        *(bf16x8*)&KL[r][c8] = *(const bf16x8*)(kbL + (size_t)r * 64 + c8);
      }
    }
    __syncthreads();
    #pragma unroll
    for (int j = 0; j < 4; ++j) {
      f32x4 sf = (f32x4){0.f,0.f,0.f,0.f};
      #pragma unroll
      for (int s = 0; s < 2; ++s) {
        bf16x8 kh8 = *(const bf16x8*)&KH[j*16 + lr][s*32 + lk];
        bf16x8 kl8 = *(const bf16x8*)&KL[j*16 + lr][s*32 + lk];
        sf = __builtin_amdgcn_mfma_f32_16x16x32_bf16(qh[s],  kh8, sf, 0,0,0);
        sf = __builtin_amdgcn_mfma_f32_16x16x32_bf16(qh[s],  kl8, sf, 0,0,0);
        sf = __builtin_amdgcn_mfma_f32_16x16x32_bf16(qlo[s], kh8, sf, 0,0,0);
      }
      #pragma unroll
      for (int r = 0; r < 4; ++r) Ss[w16 + crb + r][j*16 + lr] = sf[r];
    }
    __syncthreads();
    {
      const unsigned short* vbH = zavTH + (size_t)bh * 64 * 256 + mbase;
      const unsigned short* vbL = zavTL + (size_t)bh * 64 * 256 + mbase;
      #pragma unroll
      for (int u = 0; u < 2; ++u) {
        int i = t + u * 256;
        int d = i >> 3, c8 = (i & 7) << 3;
        *(bf16x8*)&KH[d][c8] = *(const bf16x8*)(vbH + (size_t)d * 256 + c8);
        *(bf16x8*)&KL[d][c8] = *(const bf16x8*)(vbL + (size_t)d * 256 + c8);
      }
    }
    float lm = -3.4e38f;
    #pragma unroll
    for (int c = 0; c < 16; ++c) lm = fmaxf(lm, Ss[rr][sg + c]);
    redm[rr][t & 3] = lm;
    float mold = mrow[rr];
    float rm = fmaxf(fmaxf(redm[rr][0], redm[rr][1]), fmaxf(redm[rr][2], redm[rr][3]));
    float mnew = fmaxf(mold, rm);
    float sc_r = expf(mold - mnew);
    if ((t & 3) == 0) { scales[rr] = sc_r; mrow[rr] = mnew; }
    float ls = 0.f;
    #pragma unroll
    for (int c = 0; c < 16; ++c) {
      float p = expf(Ss[rr][sg + c] - mnew);
      unsigned short hv = f2bf(p);
      PH[rr][sg + c] = hv; PL[rr][sg + c] = f2bf(p - bf2f(hv));
      ls += p;
    }
    redm[rr][t & 3] = ls;
    __syncthreads();
    if ((t & 3) == 0) lrow[rr] = lrow[rr] * sc_r + redm[rr][0]+redm[rr][1]+redm[rr][2]+redm[rr][3];
    {
      float s0 = scales[w16 + crb], s1 = scales[w16 + crb + 1],
            s2 = scales[w16 + crb + 2], s3 = scales[w16 + crb + 3];
      #pragma unroll
      for (int j = 0; j < 4; ++j) { acc[j][0]*=s0; acc[j][1]*=s1; acc[j][2]*=s2; acc[j][3]*=s3; }
    }
    bf16x8 pah[2], pal[2];
    #pragma unroll
    for (int s = 0; s < 2; ++s) {
      pah[s] = *(const bf16x8*)&PH[w16 + lr][s*32 + lk];
      pal[s] = *(const bf16x8*)&PL[w16 + lr][s*32 + lk];
    }
    #pragma unroll
    for (int j = 0; j < 4; ++j) {
      #pragma unroll
      for (int s = 0; s < 2; ++s) {
        bf16x8 vh = *(const bf16x8*)&KH[j*16 + lr][s*32 + lk];
        bf16x8 vl = *(const bf16x8*)&KL[j*16 + lr][s*32 + lk];
        acc[j] = __builtin_amdgcn_mfma_f32_16x16x32_bf16(pah[s], vh, acc[j], 0,0,0);
        acc[j] = __builtin_amdgcn_mfma_f32_16x16x32_bf16(pah[s], vl, acc[j], 0,0,0);
        acc[j] = __builtin_amdgcn_mfma_f32_16x16x32_bf16(pal[s], vh, acc[j], 0,0,0);
      }
    }
    __syncthreads();
  }
  #pragma unroll
  for (int r = 0; r < 4; ++r) {
    float invl = 1.f / lrow[w16 + crb + r];
    size_t rowoff = ((size_t)b * NPAD + n0 + w16 + crb + r) * DIM + hh * 64;
    float* mp = &merged[rowoff];
    #pragma unroll
    for (int j = 0; j < 4; ++j) {
      float v = mp[j*16 + lr] + acc[j][r] * invl;
      mp[j*16 + lr] = v;
      unsigned short hv = f2bf(v);
      merH[rowoff + j*16 + lr] = hv;
      merL[rowoff + j*16 + lr] = f2bf(v - bf2f(hv));
    }
  }
}

// ---------------- depthwise 33x1 residual conv on v -> merged (LDS strip tiled) ----------------
__global__ __launch_bounds__(256) void conv_res(const float* __restrict__ qkv, const float* __restrict__ rk,
                                                float* __restrict__ merged){
  __shared__ float vt[288][16];
  __shared__ float rks[33];
  int n0 = blockIdx.x * 256;
  int c0 = blockIdx.y * 16;
  int b  = blockIdx.z;
  int t = threadIdx.x;
  int hh = c0 >> 6;
  if (t < 33) rks[t] = rk[hh * 33 + t];
  for (int i = t; i < 288 * 4; i += 256) {
    int sp = i >> 2, q = (i & 3) << 2;
    int n = n0 - 16 + sp;
    float4 v = make_float4(0.f,0.f,0.f,0.f);
    if (n >= 0 && n < NPAD)
      v = *(const float4*)&qkv[((size_t)b * NPAD + n) * NT + 1024 + c0 + q];
    vt[sp][q] = v.x; vt[sp][q+1] = v.y; vt[sp][q+2] = v.z; vt[sp][q+3] = v.w;
  }
  __syncthreads();
  int c = t & 15, g = t >> 4;
  for (int m = 0; m < 16; ++m) {
    int nl = g + m * 16;
    float acc = 0.f;
    #pragma unroll
    for (int kk = 0; kk < 33; ++kk) acc += rks[kk] * vt[nl + kk][c];
    merged[((size_t)b * NPAD + n0 + nl) * DIM + c0 + c] = acc;
  }
}

// ---------------- PPEG depthwise convs (LDS tiled) ----------------
__global__ __launch_bounds__(256) void dwconv(const float* __restrict__ hsrc,
    const float* __restrict__ w7, const float* __restrict__ b7,
    const float* __restrict__ w5, const float* __restrict__ b5,
    const float* __restrict__ w3, const float* __restrict__ b3,
    float* __restrict__ hdst){
  __shared__ float tile[484][16];
  __shared__ float wS7[49][16], wS5[25][16], wS3[9][16];
  int st = blockIdx.x;
  int y0 = (st >> 2) * 16, x0 = (st & 3) * 16;
  int c0 = blockIdx.y * 16;
  int b  = blockIdx.z;
  int t = threadIdx.x;
  const float* fb = hsrc + ((size_t)b * N1 + 1) * DIM;
  for (int i = t; i < 49 * 16; i += 256) { int k = i >> 4, c = i & 15; wS7[k][c] = w7[(size_t)(c0 + c) * 49 + k]; }
  for (int i = t; i < 25 * 16; i += 256) { int k = i >> 4, c = i & 15; wS5[k][c] = w5[(size_t)(c0 + c) * 25 + k]; }
  for (int i = t; i <  9 * 16; i += 256) { int k = i >> 4, c = i & 15; wS3[k][c] = w3[(size_t)(c0 + c) * 9 + k]; }
  for (int i = t; i < 484 * 4; i += 256) {
    int sp = i >> 2, q = (i & 3) << 2;
    int yy = y0 - 3 + sp / 22, xx = x0 - 3 + sp % 22;
    float4 v = make_float4(0.f,0.f,0.f,0.f);
    if (yy >= 0 && yy < 64 && xx >= 0 && xx < 64)
      v = *(const float4*)&fb[(size_t)(yy * 64 + xx) * DIM + c0 + q];
    tile[sp][q] = v.x; tile[sp][q+1] = v.y; tile[sp][q+2] = v.z; tile[sp][q+3] = v.w;
  }
  __syncthreads();
  int c = t & 15, g = t >> 4;
  float bsum = b7[c0 + c] + b5[c0 + c] + b3[c0 + c];
  for (int m = 0; m < 16; ++m) {
    int p = g + m * 16;
    int y = p >> 4, x = p & 15;
    float acc = tile[(y + 3) * 22 + (x + 3)][c] + bsum;
    #pragma unroll
    for (int ky = 0; ky < 7; ++ky)
      #pragma unroll
      for (int kx = 0; kx < 7; ++kx)
        acc += wS7[ky * 7 + kx][c] * tile[(y + ky) * 22 + (x + kx)][c];
    #pragma unroll
    for (int ky = 0; ky < 5; ++ky)
      #pragma unroll
      for (int kx = 0; kx < 5; ++kx)
        acc += wS5[ky * 5 + kx][c] * tile[(y + 1 + ky) * 22 + (x + 1 + kx)][c];
    #pragma unroll
    for (int ky = 0; ky < 3; ++ky)
      #pragma unroll
      for (int kx = 0; kx < 3; ++kx)
        acc += wS3[ky * 3 + kx][c] * tile[(y + 2 + ky) * 22 + (x + 2 + kx)][c];
    int spg = (y0 + y) * 64 + (x0 + x);
    hdst[((size_t)b * N1 + 1 + spg) * DIM + c0 + c] = acc;
  }
}

__global__ void set_cls(float* h, const float* cls){
  int t = threadIdx.x;
  if (t < 1024) { int b = t >> 9, c = t & 511; h[(size_t)b * N1 * DIM + c] = cls[c]; }
}
__global__ void copy_cls(float* dst, const float* src){
  int t = threadIdx.x;
  if (t < 1024) { int b = t >> 9, c = t & 511; dst[(size_t)b * N1 * DIM + c] = src[(size_t)b * N1 * DIM + c]; }
}

__global__ __launch_bounds__(256) void final_ln(const float* __restrict__ h2, const float* __restrict__ g,
                                                const float* __restrict__ bt, float* __restrict__ hcls){
  __shared__ double red[256];
  int b = blockIdx.x, t = threadIdx.x;
  const float* x = h2 + (size_t)b * N1 * DIM;
  double x0 = (double)x[t], x1 = (double)x[t + 256];
  double mu = blk_sumd(x0 + x1, red) * (1.0/512.0);
  double d0 = x0 - mu, d1 = x1 - mu;
  double var = blk_sumd(d0*d0 + d1*d1, red) * (1.0/512.0);
  double inv = 1.0 / sqrt(var + 1e-5);
  hcls[b * 512 + t]       = (float)(d0 * inv * (double)g[t]       + (double)bt[t]);
  hcls[b * 512 + t + 256] = (float)(d1 * inv * (double)g[t + 256] + (double)bt[t + 256]);
}

// xc rows (split-bf16 only; feeds dsl1 MFMA gemm)
__global__ void build_xc_split(const float* __restrict__ hcls, const float* __restrict__ reh,
                               unsigned short* __restrict__ xcH, unsigned short* __restrict__ xcL){
  size_t idx = (size_t)blockIdx.x * 256 + threadIdx.x;
  int row = (int)(idx >> 9), c = (int)(idx & 511);
  float v = (row < 2) ? hcls[row * 512 + c] : reh[(size_t)(row - 2) * 512 + c];
  unsigned short hh = f2bf(v);
  xcH[idx] = hh; xcL[idx] = f2bf(v - bf2f(hh));
}

__global__ __launch_bounds__(256) void norms_k(const float* __restrict__ xg, double* __restrict__ rn){
  __shared__ double red[256];
  int i = blockIdx.x, t = threadIdx.x;
  double a = (double)xg[(size_t)i * 512 + t], b = (double)xg[(size_t)i * 512 + t + 256];
  double s = blk_sumd(a*a + b*b, red);
  if (t == 0) rn[i] = sqrt(s);
}

__global__ __launch_bounds__(256) void topk_k(const float* __restrict__ xg, const double* __restrict__ rn,
                                              int* __restrict__ idxb){
  __shared__ double sc[256]; __shared__ double redv[256]; __shared__ int redi[256];
  int i = blockIdx.x, j = threadIdx.x;
  const float* xi = xg + (size_t)i * 512;
  const float* xj = xg + (size_t)j * 512;
  double s = 0.;
  for (int c = 0; c < 512; ++c) s += (double)xi[c] * (double)xj[c];
  s /= (rn[i] * rn[j]);
  sc[j] = s; __syncthreads();
  for (int r = 0; r < 4; ++r) {
    redv[j] = sc[j]; redi[j] = j; __syncthreads();
    for (int st = 128; st > 0; st >>= 1) {
      if (j < st) {
        if (redv[j + st] > redv[j] || (redv[j + st] == redv[j] && redi[j + st] < redi[j])) {
          redv[j] = redv[j + st]; redi[j] = redi[j + st];
        }
      }
      __syncthreads();
    }
    if (j == 0) { idxb[i * 4 + r] = redi[0]; sc[redi[0]] = -1e300; }
    __syncthreads();
  }
}

// edge = mean of 4 gathered xg rows; writes fp32 + split
__global__ void edge_k_split(const float* __restrict__ xg, const int* __restrict__ idxb,
                             float* __restrict__ edge,
                             unsigned short* __restrict__ eH, unsigned short* __restrict__ eL){
  size_t idx = (size_t)blockIdx.x * 256 + threadIdx.x;
  int i = (int)(idx >> 9), c = (int)(idx & 511);
  const int* id = idxb + i * 4;
  float v = 0.25f * (xg[(size_t)id[0]*512 + c] + xg[(size_t)id[1]*512 + c] +
                     xg[(size_t)id[2]*512 + c] + xg[(size_t)id[3]*512 + c]);
  edge[idx] = v;
  unsigned short hh = f2bf(v);
  eH[idx] = hh; eL[idx] = f2bf(v - bf2f(hh));
}
// h1pn = xg + edge (split only)
__global__ void vadd_split(const float* __restrict__ a, const float* __restrict__ b,
                           unsigned short* __restrict__ oH, unsigned short* __restrict__ oL){
  size_t idx = (size_t)blockIdx.x * 256 + threadIdx.x;
  float v = a[idx] + b[idx];
  unsigned short hh = f2bf(v);
  oH[idx] = hh; oL[idx] = f2bf(v - bf2f(hh));
}
// h1pn2 = h1 + mean(h1[idx]) (split only)
__global__ void h1gather_split(const float* __restrict__ h1, const int* __restrict__ idxb,
                               unsigned short* __restrict__ oH, unsigned short* __restrict__ oL){
  size_t idx = (size_t)blockIdx.x * 256 + threadIdx.x;
  int i = (int)(idx >> 9), c = (int)(idx & 511);
  const int* id = idxb + i * 4;
  float v = h1[idx] + 0.25f * (h1[(size_t)id[0]*512 + c] + h1[(size_t)id[1]*512 + c] +
                               h1[(size_t)id[2]*512 + c] + h1[(size_t)id[3]*512 + c]);
  unsigned short hh = f2bf(v);
  oH[idx] = hh; oL[idx] = f2bf(v - bf2f(hh));
}

__global__ void logits2(const float* __restrict__ src, const float* __restrict__ w,
                        const float* __restrict__ bias, float* __restrict__ out){
  int rc = blockIdx.x; int r = rc >> 1, c = rc & 1;
  int t = threadIdx.x; // 64
  double s = 0.;
  for (int k = t; k < 512; k += 64) s += (double)src[(size_t)r * 512 + k] * (double)w[(size_t)c * 512 + k];
  for (int off = 32; off > 0; off >>= 1) s += __shfl_down(s, off);
  if (t == 0) out[rc] = (float)(s + (double)bias[c]);
}

__global__ void sentinel_k(float* out){ if (threadIdx.x < 12) out[threadIdx.x] = 1e30f; }

// ---------------- host-side nystrom block ----------------
struct NysBufs {
  float *qkv, *ql, *kl, *klT, *av, *zav, *merged;
  float *a2f32, *scal, *accp, *mlp;
  unsigned short *padH, *padL, *merH, *merL, *wqH, *wqL, *owH, *owL;
  unsigned short *a2H, *a2L;
  unsigned short *zAH, *zAL, *zATH, *zATL;
  unsigned short *zBH, *zBL, *zBTH, *zBTL;
  unsigned short *azH, *azL, *t1TH, *t1TL, *t2TH, *t2TL;
  unsigned short *avTH, *avTL;
  unsigned short *KsH, *KsL, *VTH, *VTL;
  unsigned short *klsH, *klsL, *zavTH, *zavTL;
};

static void run_nystrom(hipStream_t stream, float* hbuf,
                        const float* lng, const float* lnb, const float* qkvw,
                        const float* outw, const float* outb, const float* rk,
                        const NysBufs& w)
{
  ln_pad_split<<<BB * NPAD, 256, 0, stream>>>(hbuf, w.padH, w.padL, lng, lnb);
  split_k<<<(NT * DIM / 4 + 255) / 256, 256, 0, stream>>>(qkvw, w.wqH, w.wqL, NT * DIM / 4);
  gemm_mfma<<<dim3(NT/128, (BB*NPAD)/128), 256, 0, stream>>>(w.padH, w.padL, w.wqH, w.wqL,
                                                             nullptr, nullptr, w.qkv,
                                                             BB*NPAD, NT, DIM, 0, nullptr, nullptr);
  split_kcols<<<BB * NPAD * 128 / 256, 256, 0, stream>>>(w.qkv, w.KsH, w.KsL);
  transpose_split_v<<<dim3(NPAD/64, 16), 256, 0, stream>>>(w.qkv, w.VTH, w.VTL);
  landmark<<<BB * NH * LM, 64, 0, stream>>>(w.qkv, w.ql, w.kl);
  transpose_kl<<<dim3(LM/64, 16), 256, 0, stream>>>(w.kl, w.klT);
  split_k<<<(16 * LM * DH / 4 + 255) / 256, 256, 0, stream>>>(w.kl, w.klsH, w.klsL, 16 * LM * DH / 4);
  fa3v_kernel<<<dim3(17, 4, 16), 256, 0, stream>>>(w.KsH, w.KsL, w.VTH, w.VTL, w.ql, w.accp, w.mlp);
  fa3v_combine<<<64, 256, 0, stream>>>(w.accp, w.mlp, w.av);
  split_T_av<<<1024, 256, 0, stream>>>(w.av, w.avTH, w.avTL);
  a2_kernel<<<BB * NH * LM, 256, 0, stream>>>(w.ql, w.klT, w.a2f32);
  colrow_max<<<16, 256, 0, stream>>>(w.a2f32, w.scal);
  scal_red<<<1, 64, 0, stream>>>(w.scal);
  split_k<<<(16 * 65536 / 4 + 255) / 256, 256, 0, stream>>>(w.a2f32, w.a2H, w.a2L, 16 * 65536 / 4);
  z0_split<<<4096, 256, 0, stream>>>(w.a2f32, w.scal, w.zAH, w.zAL, w.zATH, w.zATL);
  const unsigned short *zcH = w.zAH, *zcL = w.zAL, *zcTH = w.zATH, *zcTL = w.zATL;
  unsigned short *znH = w.zBH, *znL = w.zBL, *znTH = w.zBTH, *znTL = w.zBTL;
  for (int it = 0; it < 6; ++it) {
    mm_mfma<<<dim3(8,8,16), 64, 0, stream>>>(w.a2H, w.a2L, zcTH, zcTL,
        w.azH, w.azL, nullptr, nullptr, w.t1TH, w.t1TL, nullptr, 256, 1.f, 0.f, 7.f);
    mm_mfma<<<dim3(8,8,16), 64, 0, stream>>>(w.azH, w.azL, w.t1TH, w.t1TL,
        nullptr, nullptr, w.t2TH, w.t2TL, nullptr, nullptr, nullptr, 256, -1.f, 15.f, 0.f);
    mm_mfma<<<dim3(8,8,16), 64, 0, stream>>>(w.azH, w.azL, w.t2TH, w.t2TL,
        nullptr, nullptr, w.t1TH, w.t1TL, nullptr, nullptr, nullptr, 256, -1.f, 13.f, 0.f);
    mm_mfma<<<dim3(8,8,16), 64, 0, stream>>>(zcH, zcL, w.t1TH, w.t1TL,
        znH, znL, znTH, znTL, nullptr, nullptr, nullptr, 256, 0.25f, 0.f, 0.f);
    const unsigned short* t;
    t = zcH; zcH = znH; znH = (unsigned short*)t;
    t = zcL; zcL = znL; znL = (unsigned short*)t;
    t = zcTH; zcTH = znTH; znTH = (unsigned short*)t;
    t = zcTL; zcTL = znTL; znTL = (unsigned short*)t;
  }
  mm_mfma<<<dim3(2,8,16), 64, 0, stream>>>(zcH, zcL, w.avTH, w.avTL,
      nullptr, nullptr, nullptr, nullptr, nullptr, nullptr, w.zav, 64, 1.f, 0.f, 0.f);
  split_T_av<<<1024, 256, 0, stream>>>(w.zav, w.zavTH, w.zavTL);
  conv_res<<<dim3(17, 32, 2), 256, 0, stream>>>(w.qkv, rk, w.merged);
  fa1_kernel<<<dim3(NPAD/64, 16), 256, 0, stream>>>(w.qkv, w.klsH, w.klsL, w.zavTH, w.zavTL,
                                                    w.merged, w.merH, w.merL);
  split_k<<<(DIM*DIM/4 + 255) / 256, 256, 0, stream>>>(outw, w.owH, w.owL, DIM*DIM/4);
  for (int b = 0; b < BB; ++b)
    gemm_mfma<<<dim3(DIM/128, (N1+127)/128), 256, 0, stream>>>(
        w.merH + ((size_t)b*NPAD + PADR)*DIM, w.merL + ((size_t)b*NPAD + PADR)*DIM,
        w.owH, w.owL, outb,
        hbuf + (size_t)b*N1*DIM, hbuf + (size_t)b*N1*DIM,
        N1, DIM, DIM, 0, nullptr, nullptr);
}

extern "C" void kernel_launch(void* const* d_in, const int* in_sizes, int n_in,
                              void* d_out, int out_size, void* d_ws, size_t ws_size,
                              hipStream_t stream) {
  (void)in_sizes; (void)n_in; (void)out_size;
  const float* x        = (const float*)d_in[0];
  const float* fc1_w    = (const float*)d_in[1];
  const float* fc1_b    = (const float*)d_in[2];
  const float* cls_tok  = (const float*)d_in[3];
  const float* ln1_g    = (const float*)d_in[4];
  const float* ln1_b    = (const float*)d_in[5];
  const float* qkv1_w   = (const float*)d_in[6];
  const float* out1_w   = (const float*)d_in[7];
  const float* out1_b   = (const float*)d_in[8];
  const float* res1_k   = (const float*)d_in[9];
  const float* ppeg_w7  = (const float*)d_in[10];
  const float* ppeg_b7  = (const float*)d_in[11];
  const float* ppeg_w5  = (const float*)d_in[12];
  const float* ppeg_b5  = (const float*)d_in[13];
  const float* ppeg_w3  = (const float*)d_in[14];
  const float* ppeg_b3  = (const float*)d_in[15];
  const float* ln2_g    = (const float*)d_in[16];
  const float* ln2_b    = (const float*)d_in[17];
  const float* qkv2_w   = (const float*)d_in[18];
  const float* out2_w   = (const float*)d_in[19];
  const float* out2_b   = (const float*)d_in[20];
  const float* res2_k   = (const float*)d_in[21];
  const float* norm_g   = (const float*)d_in[22];
  const float* norm_b   = (const float*)d_in[23];
  const float* fc2_w    = (const float*)d_in[24];
  const float* fc2_b    = (const float*)d_in[25];
  const float* dsl_w1   = (const float*)d_in[26];
  const float* dsl_b1   = (const float*)d_in[27];
  const float* dsl_w2   = (const float*)d_in[28];
  const float* dsl_b2   = (const float*)d_in[29];
  const float* gcn_w1   = (const float*)d_in[30];
  const float* gcn_we   = (const float*)d_in[31];
  const float* gcn_b1   = (const float*)d_in[32];
  const float* gcn_w2   = (const float*)d_in[33];
  const float* gcn_b2   = (const float*)d_in[34];
  const float* gcn_hw   = (const float*)d_in[35];
  const float* gcn_hb   = (const float*)d_in[36];
  const float* gcn_dw   = (const float*)d_in[37];
  const float* gcn_db   = (const float*)d_in[38];
  const float* rehearsal= (const float*)d_in[39];
  float* out = (float*)d_out;

  char* base = (char*)d_ws;
  size_t off = 0;
  auto takeb = [&](size_t bytes) { void* p = base + off; off += (bytes + 255) & ~(size_t)255; return p; };

  float* h    = (float*)takeb((size_t)BB * N1 * DIM * 4);
  float* h2   = (float*)takeb((size_t)BB * N1 * DIM * 4);
  NysBufs nb;
  nb.padH   = (unsigned short*)takeb((size_t)BB * NPAD * DIM * 2);
  nb.padL   = (unsigned short*)takeb((size_t)BB * NPAD * DIM * 2);
  nb.qkv    = (float*)takeb((size_t)BB * NPAD * NT * 4);
  nb.ql     = (float*)takeb((size_t)BB * NH * LM * DH * 4);
  nb.kl     = (float*)takeb((size_t)BB * NH * LM * DH * 4);
  nb.klT    = (float*)takeb((size_t)BB * NH * LM * DH * 4);
  nb.av     = (float*)takeb((size_t)BB * NH * LM * DH * 4);
  nb.zav    = (float*)takeb((size_t)BB * NH * LM * DH * 4);
  nb.merged = (float*)takeb((size_t)BB * NPAD * DIM * 4);
  nb.merH   = (unsigned short*)takeb((size_t)BB * NPAD * DIM * 2);
  nb.merL   = (unsigned short*)takeb((size_t)BB * NPAD * DIM * 2);
  nb.wqH    = (unsigned short*)takeb((size_t)NT * DIM * 2);
  nb.wqL    = (unsigned short*)takeb((size_t)NT * DIM * 2);
  nb.owH    = (unsigned short*)takeb((size_t)DIM * DIM * 2);
  nb.owL    = (unsigned short*)takeb((size_t)DIM * DIM * 2);
  nb.avTH   = (unsigned short*)takeb((size_t)16 * 64 * 256 * 2);
  nb.avTL   = (unsigned short*)takeb((size_t)16 * 64 * 256 * 2);
  nb.klsH   = (unsigned short*)takeb((size_t)16 * LM * DH * 2);
  nb.klsL   = (unsigned short*)takeb((size_t)16 * LM * DH * 2);
  nb.zavTH  = (unsigned short*)takeb((size_t)16 * 64 * 256 * 2);
  nb.zavTL  = (unsigned short*)takeb((size_t)16 * 64 * 256 * 2);
  nb.scal   = (float*)takeb(64 * 4);
  nb.mlp    = (float*)takeb((size_t)1088 * 128 * 4);
  float* hcls = (float*)takeb((size_t)BB * DIM * 4);
  float* xg1  = (float*)takeb((size_t)256 * 256 * 4);
  float* xg   = (float*)takeb((size_t)256 * 512 * 4);
  double* rn  = (double*)takeb(256 * 8);
  int*   idxb = (int*)takeb(1024 * 4);
  float* edge = (float*)takeb((size_t)256 * 512 * 4);
  float* h1g  = (float*)takeb((size_t)256 * 512 * 4);
  float* h2g  = (float*)takeb((size_t)256 * 512 * 4);
  unsigned short* xcH   = (unsigned short*)takeb((size_t)256 * 512 * 2);
  unsigned short* xcL   = (unsigned short*)takeb((size_t)256 * 512 * 2);
  unsigned short* dw1H  = (unsigned short*)takeb((size_t)256 * 512 * 2);
  unsigned short* dw1L  = (unsigned short*)takeb((size_t)256 * 512 * 2);
  unsigned short* xg1H  = (unsigned short*)takeb((size_t)256 * 256 * 2);
  unsigned short* xg1L  = (unsigned short*)takeb((size_t)256 * 256 * 2);
  unsigned short* dw2H  = (unsigned short*)takeb((size_t)512 * 256 * 2);
  unsigned short* dw2L  = (unsigned short*)takeb((size_t)512 * 256 * 2);
  unsigned short* h1pH  = (unsigned short*)takeb((size_t)256 * 512 * 2);
  unsigned short* h1pL  = (unsigned short*)takeb((size_t)256 * 512 * 2);
  unsigned short* gw1H  = (unsigned short*)takeb((size_t)512 * 512 * 2);
  unsigned short* gw1L  = (unsigned short*)takeb((size_t)512 * 512 * 2);
  unsigned short* edgeH = (unsigned short*)takeb((size_t)256 * 512 * 2);
  unsigned short* edgeL = (unsigned short*)takeb((size_t)256 * 512 * 2);
  unsigned short* gweH  = (unsigned short*)takeb((size_t)512 * 512 * 2);
  unsigned short* gweL  = (unsigned short*)takeb((size_t)512 * 512 * 2);
  unsigned short* h1p2H = (unsigned short*)takeb((size_t)256 * 512 * 2);
  unsigned short* h1p2L = (unsigned short*)takeb((size_t)256 * 512 * 2);
  unsigned short* gw2H  = (unsigned short*)takeb((size_t)512 * 512 * 2);
  unsigned short* gw2L  = (unsigned short*)takeb((size_t)512 * 512 * 2);

  const size_t MB2 = (size_t)16 * 65536;
  unsigned short* pr = nb.padH;
  nb.a2H  = pr;            nb.a2L  = pr + MB2;
  nb.zAH  = pr + 2*MB2;    nb.zAL  = pr + 3*MB2;
  nb.zATH = pr + 4*MB2;    nb.zATL = pr + 5*MB2;
  nb.azH  = pr + 6*MB2;    nb.azL  = pr + 7*MB2;
  unsigned short* mr = (unsigned short*)nb.merged;
  nb.zBH  = mr;            nb.zBL  = mr + MB2;
  nb.zBTH = mr + 2*MB2;    nb.zBTL = mr + 3*MB2;
  nb.t1TH = mr + 4*MB2;    nb.t1TL = mr + 5*MB2;
  nb.t2TH = mr + 6*MB2;    nb.t2TL = mr + 7*MB2;
  nb.a2f32 = (float*)(mr + 4*MB2);
  nb.accp  = nb.merged;
  nb.KsH = nb.padH;
  nb.KsL = nb.padL;
  nb.VTH = nb.merH;
  nb.VTL = nb.merL;

  if (ws_size < off) { sentinel_k<<<1, 64, 0, stream>>>(out); return; }

  // --- stage A: fc1 (MFMA split-bf16) + cls ---
  set_cls<<<1, 1024, 0, stream>>>(h, cls_tok);
  split_k<<<(BB*NSEQ*DIM/4 + 255) / 256, 256, 0, stream>>>(x, nb.merH, nb.merL, BB*NSEQ*DIM/4);
  split_k<<<(DIM*DIM/4 + 255) / 256, 256, 0, stream>>>(fc1_w, nb.owH, nb.owL, DIM*DIM/4);
  for (int b = 0; b < BB; ++b)
    gemm_mfma<<<dim3(DIM/128, NSEQ/128), 256, 0, stream>>>(
        nb.merH + (size_t)b*NSEQ*DIM, nb.merL + (size_t)b*NSEQ*DIM,
        nb.owH, nb.owL, fc1_b, nullptr,
        h + ((size_t)b*N1 + 1)*DIM, NSEQ, DIM, DIM, 1, nullptr, nullptr);
  // --- nystrom block 1 (residual into h) ---
  run_nystrom(stream, h, ln1_g, ln1_b, qkv1_w, out1_w, out1_b, res1_k, nb);

  // --- PPEG ---
  copy_cls<<<1, 1024, 0, stream>>>(h2, h);
  dwconv<<<dim3(16, 32, 2), 256, 0, stream>>>(h, ppeg_w7, ppeg_b7, ppeg_w5, ppeg_b5,
                                              ppeg_w3, ppeg_b3, h2);
  // --- nystrom block 2 (residual into h2) ---
  run_nystrom(stream, h2, ln2_g, ln2_b, qkv2_w, out2_w, out2_b, res2_k, nb);

  // --- final LN (row 0) + heads ---
  final_ln<<<BB, 256, 0, stream>>>(h2, norm_g, norm_b, hcls);
  logits2<<<4, 64, 0, stream>>>(hcls, fc2_w, fc2_b, out + 0);

  // --- GCN branch (MFMA split-bf16, barrier-free gemms) ---
  build_xc_split<<<512, 256, 0, stream>>>(hcls, rehearsal, xcH, xcL);
  split_k<<<(256*512/4 + 255) / 256, 256, 0, stream>>>(dsl_w1, dw1H, dw1L, 256*512/4);
  split_k<<<(512*256/4 + 255) / 256, 256, 0, stream>>>(dsl_w2, dw2H, dw2L, 512*256/4);
  split_k<<<(512*512/4 + 255) / 256, 256, 0, stream>>>(gcn_w1, gw1H, gw1L, 512*512/4);
  split_k<<<(512*512/4 + 255) / 256, 256, 0, stream>>>(gcn_we, gweH, gweL, 512*512/4);
  split_k<<<(512*512/4 + 255) / 256, 256, 0, stream>>>(gcn_w2, gw2H, gw2L, 512*512/4);
  gemm_mfma<<<dim3(2, 2), 256, 0, stream>>>(xcH, xcL, dw1H, dw1L, dsl_b1, nullptr,
                                            xg1, 256, 256, 512, 2, xg1H, xg1L);
  gemm_mfma<<<dim3(4, 2), 256, 0, stream>>>(xg1H, xg1L, dw2H, dw2L, dsl_b2, nullptr,
                                            xg, 256, 512, 256, 2, nullptr, nullptr);
  norms_k<<<256, 256, 0, stream>>>(xg, rn);
  topk_k<<<256, 256, 0, stream>>>(xg, rn, idxb);
  edge_k_split<<<512, 256, 0, stream>>>(xg, idxb, edge, edgeH, edgeL);
  vadd_split<<<512, 256, 0, stream>>>(xg, edge, h1pH, h1pL);
  gemm_mfma<<<dim3(4, 2), 256, 0, stream>>>(h1pH, h1pL, gw1H, gw1L, nullptr, nullptr,
                                            h1g, 256, 512, 512, 0, nullptr, nullptr);
  gemm_mfma<<<dim3(4, 2), 256, 0, stream>>>(edgeH, edgeL, gweH, gweL, gcn_b1, h1g,
                                            h1g, 256, 512, 512, 1, nullptr, nullptr);
  h1gather_split<<<512, 256, 0, stream>>>(h1g, idxb, h1p2H, h1p2L);
  gemm_mfma<<<dim3(4, 2), 256, 0, stream>>>(h1p2H, h1p2L, gw2H, gw2L, gcn_b2, nullptr,
                                            h2g, 256, 512, 512, 0, nullptr, nullptr);
  logits2<<<4, 64, 0, stream>>>(h2g, gcn_hw, gcn_hb, out + 4);
  logits2<<<4, 64, 0, stream>>>(h1g, gcn_dw, gcn_db, out + 8);
}

// Round 18
// 1739.814 us; speedup vs baseline: 1.2079x; 1.2079x over previous
//
#include <hip/hip_runtime.h>
#include <math.h>

#define BB 2
#define NSEQ 4096
#define N1 4097
#define NPAD 4352
#define PADR 255
#define DIM 512
#define NH 8
#define DH 64
#define LM 256
#define NT 1536

typedef short bf16x8 __attribute__((ext_vector_type(8)));
typedef float f32x4 __attribute__((ext_vector_type(4)));

__device__ __forceinline__ unsigned short f2bf(float x){
  unsigned int u = __float_as_uint(x);
  unsigned int r = (u + 0x7FFFu + ((u >> 16) & 1u)) >> 16;
  return (unsigned short)r;
}
__device__ __forceinline__ float bf2f(unsigned short h){
  return __uint_as_float(((unsigned int)h) << 16);
}

// ---------------- block reduce helpers (blockDim.x == 256) ----------------
__device__ __forceinline__ float blk_sum(float v, float* red){
  int t = threadIdx.x;
  red[t] = v; __syncthreads();
  for (int s = 128; s > 0; s >>= 1){ if (t < s) red[t] += red[t+s]; __syncthreads(); }
  float r = red[0]; __syncthreads(); return r;
}
__device__ __forceinline__ float blk_max(float v, float* red){
  int t = threadIdx.x;
  red[t] = v; __syncthreads();
  for (int s = 128; s > 0; s >>= 1){ if (t < s) red[t] = fmaxf(red[t], red[t+s]); __syncthreads(); }
  float r = red[0]; __syncthreads(); return r;
}
__device__ __forceinline__ double blk_sumd(double v, double* red){
  int t = threadIdx.x;
  red[t] = v; __syncthreads();
  for (int s = 128; s > 0; s >>= 1){ if (t < s) red[t] += red[t+s]; __syncthreads(); }
  double r = red[0]; __syncthreads(); return r;
}

// ---------------- MFMA split-bf16 GEMM: C = act(A @ W^T + bias + res) ----------------
// LDS-staged BK=32 (round-16 proven, 40KB LDS) + XCD-aware bijective block swizzle
// (kept from round 17: FETCH 76->35MB). K % 32 == 0, N % 128 == 0.
__global__ __launch_bounds__(256) void gemm_mfma(
    const unsigned short* __restrict__ Ah, const unsigned short* __restrict__ Al,
    const unsigned short* __restrict__ Wh, const unsigned short* __restrict__ Wl,
    const float* __restrict__ bias, const float* __restrict__ res,
    float* __restrict__ C, int M, int N, int K, int act,
    unsigned short* __restrict__ outH, unsigned short* __restrict__ outL)
{
  __shared__ unsigned short AsH[128][40], AsL[128][40], BsH[128][40], BsL[128][40];
  int t = threadIdx.x;
  int w = t >> 6, l = t & 63;
  int wr = w >> 1, wc = w & 1;
  // XCD-aware bijective swizzle of linear block id (contiguous chunk per XCD, m204)
  int nbx = gridDim.x;
  int nwg = nbx * gridDim.y;
  int bid = blockIdx.y * nbx + blockIdx.x;
  int q = nwg >> 3, rr = nwg & 7;
  int xcd = bid & 7, pos = bid >> 3;
  int sbid = ((xcd < rr) ? (xcd * (q + 1)) : (rr * (q + 1) + (xcd - rr) * q)) + pos;
  int bx = sbid % nbx, by = sbid / nbx;
  int rowBase = by * 128;
  int colBase = bx * 128;
  int row0 = rowBase + wr * 64;
  int col0 = colBase + wc * 64;
  int lr = l & 15;
  int lk = (l >> 4) << 3;
  f32x4 acc[4][4];
  #pragma unroll
  for (int i = 0; i < 4; ++i)
    #pragma unroll
    for (int j = 0; j < 4; ++j) acc[i][j] = (f32x4){0.f, 0.f, 0.f, 0.f};

  for (int ks = 0; ks < K; ks += 32) {
    #pragma unroll
    for (int u = 0; u < 2; ++u) {
      int i = t + u * 256;
      int r = i >> 2, c8 = (i & 3) << 3;
      int ga = rowBase + r; ga = (ga < M) ? ga : (M - 1);
      size_t ao = (size_t)ga * K + ks + c8;
      *(bf16x8*)&AsH[r][c8] = *(const bf16x8*)(Ah + ao);
      *(bf16x8*)&AsL[r][c8] = *(const bf16x8*)(Al + ao);
      int gb = colBase + r;
      size_t bo = (size_t)gb * K + ks + c8;
      *(bf16x8*)&BsH[r][c8] = *(const bf16x8*)(Wh + bo);
      *(bf16x8*)&BsL[r][c8] = *(const bf16x8*)(Wl + bo);
    }
    __syncthreads();
    bf16x8 ah[4], al4[4], bh[4], bl4[4];
    #pragma unroll
    for (int i = 0; i < 4; ++i) {
      ah[i]  = *(const bf16x8*)&AsH[wr*64 + i*16 + lr][lk];
      al4[i] = *(const bf16x8*)&AsL[wr*64 + i*16 + lr][lk];
      bh[i]  = *(const bf16x8*)&BsH[wc*64 + i*16 + lr][lk];
      bl4[i] = *(const bf16x8*)&BsL[wc*64 + i*16 + lr][lk];
    }
    #pragma unroll
    for (int i = 0; i < 4; ++i)
      #pragma unroll
      for (int j = 0; j < 4; ++j) {
        acc[i][j] = __builtin_amdgcn_mfma_f32_16x16x32_bf16(ah[i],  bh[j],  acc[i][j], 0, 0, 0);
        acc[i][j] = __builtin_amdgcn_mfma_f32_16x16x32_bf16(ah[i],  bl4[j], acc[i][j], 0, 0, 0);
        acc[i][j] = __builtin_amdgcn_mfma_f32_16x16x32_bf16(al4[i], bh[j],  acc[i][j], 0, 0, 0);
      }
    __syncthreads();
  }
  int crb = (l >> 4) << 2;
  #pragma unroll
  for (int i = 0; i < 4; ++i)
    #pragma unroll
    for (int r = 0; r < 4; ++r) {
      int row = row0 + i * 16 + crb + r;
      if (row >= M) continue;
      #pragma unroll
      for (int j = 0; j < 4; ++j) {
        int col = col0 + j * 16 + lr;
        float v = acc[i][j][r];
        if (bias) v += bias[col];
        if (res)  v += res[(size_t)row * N + col];
        if (act == 1) v = fmaxf(v, 0.f);
        else if (act == 2) v = (v >= 0.f) ? v : 0.01f * v;
        size_t o = (size_t)row * N + col;
        C[o] = v;
        if (outH) {
          unsigned short hh = f2bf(v);
          outH[o] = hh;
          outL[o] = f2bf(v - bf2f(hh));
        }
      }
    }
}

// ---------------- batched(16) MFMA split-bf16 mm for the pinv chain ----------------
__global__ __launch_bounds__(64) void mm_mfma(
    const unsigned short* __restrict__ AH, const unsigned short* __restrict__ AL,
    const unsigned short* __restrict__ BTH, const unsigned short* __restrict__ BTL,
    unsigned short* __restrict__ CH, unsigned short* __restrict__ CL,
    unsigned short* __restrict__ CTH, unsigned short* __restrict__ CTL,
    unsigned short* __restrict__ DTH, unsigned short* __restrict__ DTL,
    float* __restrict__ C32,
    int N, float alpha, float diag, float diag2)
{
  int bh = blockIdx.z;
  size_t offA  = (size_t)bh * 65536;
  size_t offBT = (size_t)bh * N * 256;
  size_t offC  = (size_t)bh * 256 * N;
  size_t offT  = (size_t)bh * 65536;
  int l = threadIdx.x;
  int lr = l & 15, lk = (l >> 4) << 3;
  int row0 = blockIdx.y * 32, col0 = blockIdx.x * 32;
  f32x4 acc[2][2];
  #pragma unroll
  for (int i = 0; i < 2; ++i)
    #pragma unroll
    for (int j = 0; j < 2; ++j) acc[i][j] = (f32x4){0.f,0.f,0.f,0.f};

  bf16x8 A0h[2], A0l[2], B0h[2], B0l[2];
  bf16x8 A1h[2], A1l[2], B1h[2], B1l[2];

#define LDF2(AH_, AL_, BH_, BL_, KS) do {                              \
    _Pragma("unroll")                                                  \
    for (int i = 0; i < 2; ++i) {                                      \
      size_t ao = offA + (size_t)(row0 + i*16 + lr) * 256 + (KS) + lk; \
      AH_[i] = *(const bf16x8*)(AH + ao);                              \
      AL_[i] = *(const bf16x8*)(AL + ao);                              \
      size_t bo = offBT + (size_t)(col0 + i*16 + lr) * 256 + (KS) + lk;\
      BH_[i] = *(const bf16x8*)(BTH + bo);                             \
      BL_[i] = *(const bf16x8*)(BTL + bo);                             \
    } } while (0)

#define DOMFMA2(AH_, AL_, BH_, BL_) do {                               \
    _Pragma("unroll")                                                  \
    for (int i = 0; i < 2; ++i)                                        \
      _Pragma("unroll")                                                \
      for (int j = 0; j < 2; ++j) {                                    \
        acc[i][j] = __builtin_amdgcn_mfma_f32_16x16x32_bf16(AH_[i], BH_[j], acc[i][j], 0,0,0); \
        acc[i][j] = __builtin_amdgcn_mfma_f32_16x16x32_bf16(AH_[i], BL_[j], acc[i][j], 0,0,0); \
        acc[i][j] = __builtin_amdgcn_mfma_f32_16x16x32_bf16(AL_[i], BH_[j], acc[i][j], 0,0,0); \
      } } while (0)

  LDF2(A0h, A0l, B0h, B0l, 0);
  for (int ks = 0; ks < 256; ks += 64) {
    LDF2(A1h, A1l, B1h, B1l, ks + 32);
    DOMFMA2(A0h, A0l, B0h, B0l);
    if (ks + 64 < 256) LDF2(A0h, A0l, B0h, B0l, ks + 64);
    DOMFMA2(A1h, A1l, B1h, B1l);
  }
#undef LDF2
#undef DOMFMA2

  int crb = (l >> 4) << 2;
  #pragma unroll
  for (int i = 0; i < 2; ++i) {
    int rbase = row0 + i*16 + crb;
    #pragma unroll
    for (int j = 0; j < 2; ++j) {
      int colg = col0 + j*16 + lr;
      float v[4];
      #pragma unroll
      for (int r = 0; r < 4; ++r)
        v[r] = alpha * acc[i][j][r] + (((rbase + r) == colg) ? diag : 0.f);
      if (C32) {
        #pragma unroll
        for (int r = 0; r < 4; ++r) C32[offC + (size_t)(rbase + r) * N + colg] = v[r];
      }
      if (CH) {
        #pragma unroll
        for (int r = 0; r < 4; ++r) {
          unsigned short hh = f2bf(v[r]);
          CH[offC + (size_t)(rbase + r) * N + colg] = hh;
          CL[offC + (size_t)(rbase + r) * N + colg] = f2bf(v[r] - bf2f(hh));
        }
      }
      if (CTH) {
        ushort4 th, tl;
        unsigned short* ph = (unsigned short*)&th;
        unsigned short* pl = (unsigned short*)&tl;
        #pragma unroll
        for (int r = 0; r < 4; ++r) { ph[r] = f2bf(v[r]); pl[r] = f2bf(v[r] - bf2f(ph[r])); }
        *(ushort4*)&CTH[offT + (size_t)colg * 256 + rbase] = th;
        *(ushort4*)&CTL[offT + (size_t)colg * 256 + rbase] = tl;
      }
      if (DTH) {
        ushort4 th, tl;
        unsigned short* ph = (unsigned short*)&th;
        unsigned short* pl = (unsigned short*)&tl;
        #pragma unroll
        for (int r = 0; r < 4; ++r) {
          float dv = (((rbase + r) == colg) ? diag2 : 0.f) - v[r];
          ph[r] = f2bf(dv); pl[r] = f2bf(dv - bf2f(ph[r]));
        }
        *(ushort4*)&DTH[offT + (size_t)colg * 256 + rbase] = th;
        *(ushort4*)&DTL[offT + (size_t)colg * 256 + rbase] = tl;
      }
    }
  }
}

// elementwise split fp32 -> (hi, lo) bf16; n4 = count/4
__global__ void split_k(const float* __restrict__ src, unsigned short* __restrict__ dh,
                        unsigned short* __restrict__ dl, int n4){
  int i = blockIdx.x * 256 + threadIdx.x;
  if (i >= n4) return;
  float4 v = ((const float4*)src)[i];
  ushort4 H, L;
  H.x = f2bf(v.x); L.x = f2bf(v.x - bf2f(H.x));
  H.y = f2bf(v.y); L.y = f2bf(v.y - bf2f(H.y));
  H.z = f2bf(v.z); L.z = f2bf(v.z - bf2f(H.z));
  H.w = f2bf(v.w); L.w = f2bf(v.w - bf2f(H.w));
  ((ushort4*)dh)[i] = H;
  ((ushort4*)dl)[i] = L;
}

// split K columns of qkv (cols 512..1024) into compact [row][512] hi/lo; grid 4352
__global__ void split_kcols(const float* __restrict__ qkv,
                            unsigned short* __restrict__ dh, unsigned short* __restrict__ dl){
  size_t idx = (size_t)blockIdx.x * 256 + threadIdx.x;   // BB*NPAD*128 total
  size_t row = idx >> 7;
  int c4 = (int)(idx & 127) << 2;
  float4 v = *(const float4*)&qkv[row * NT + 512 + c4];
  ushort4 H, L;
  H.x = f2bf(v.x); L.x = f2bf(v.x - bf2f(H.x));
  H.y = f2bf(v.y); L.y = f2bf(v.y - bf2f(H.y));
  H.z = f2bf(v.z); L.z = f2bf(v.z - bf2f(H.z));
  H.w = f2bf(v.w); L.w = f2bf(v.w - bf2f(H.w));
  *(ushort4*)&dh[row * 512 + c4] = H;
  *(ushort4*)&dl[row * 512 + c4] = L;
}

// transpose-split V: VT[bh][d][n] hi/lo; grid (NPAD/64, 16)
__global__ __launch_bounds__(256) void transpose_split_v(const float* __restrict__ qkv,
    unsigned short* __restrict__ VTH, unsigned short* __restrict__ VTL){
  __shared__ float tile[64][65];
  int bh = blockIdx.y;
  int n0 = blockIdx.x * 64;
  int b = bh >> 3, hh = bh & 7;
  int t = threadIdx.x;
  for (int i = t; i < 4096; i += 256) {
    int r = i >> 6, c = i & 63;
    tile[r][c] = qkv[((size_t)b * NPAD + n0 + r) * NT + 1024 + hh * 64 + c];
  }
  __syncthreads();
  for (int i = t; i < 4096; i += 256) {
    int d = i >> 6, n = i & 63;
    float v = tile[n][d];
    unsigned short hv = f2bf(v);
    size_t o = ((size_t)bh * 64 + d) * NPAD + n0 + n;
    VTH[o] = hv; VTL[o] = f2bf(v - bf2f(hv));
  }
}

// z0 = a2^T * s : write z (normal, hi/lo) and zT (hi/lo). zT = a2 * s elementwise.
__global__ void z0_split(const float* __restrict__ a2, const float* __restrict__ scal,
                         unsigned short* __restrict__ zH, unsigned short* __restrict__ zL,
                         unsigned short* __restrict__ zTH, unsigned short* __restrict__ zTL){
  size_t idx = (size_t)blockIdx.x * 256 + threadIdx.x;   // grid 4096
  size_t bh = idx >> 16;
  int rc = (int)(idx & 65535);
  int r = rc >> 8, c = rc & 255;
  float v = a2[idx] * scal[32];
  unsigned short hh = f2bf(v), ll = f2bf(v - bf2f(hh));
  zTH[idx] = hh; zTL[idx] = ll;
  size_t tidx = (bh << 16) + (size_t)c * 256 + r;
  zH[tidx] = hh; zL[tidx] = ll;
}

// src (bh,256,64) fp32 -> dst (bh,64,256) hi/lo  (used for av and zav)
__global__ void split_T_av(const float* __restrict__ av,
                           unsigned short* __restrict__ TH, unsigned short* __restrict__ TL){
  size_t idx = (size_t)blockIdx.x * 256 + threadIdx.x;   // grid 1024 (16*16384)
  size_t bh = idx >> 14;
  int md = (int)(idx & 16383);
  int m = md >> 6, d = md & 63;
  float v = av[idx];
  unsigned short hh = f2bf(v);
  size_t tix = (bh << 14) + (size_t)d * 256 + m;
  TH[tix] = hh; TL[tix] = f2bf(v - bf2f(hh));
}

// ---------------- LN + front zero-pad, emitting split-bf16 halves ----------------
__global__ __launch_bounds__(256) void ln_pad_split(const float* __restrict__ hsrc,
    unsigned short* __restrict__ dH, unsigned short* __restrict__ dL,
    const float* __restrict__ g, const float* __restrict__ bt){
  __shared__ double red[256];
  int row = blockIdx.x;
  int b = row / NPAD, r = row % NPAD;
  unsigned short* rh = dH + (size_t)row * DIM;
  unsigned short* rl = dL + (size_t)row * DIM;
  int t = threadIdx.x;
  if (r < PADR) { rh[t] = 0; rh[t+256] = 0; rl[t] = 0; rl[t+256] = 0; return; }
  const float* x = hsrc + ((size_t)b * N1 + (r - PADR)) * DIM;
  double x0 = (double)x[t], x1 = (double)x[t + 256];
  double mu = blk_sumd(x0 + x1, red) * (1.0/512.0);
  double d0 = x0 - mu, d1 = x1 - mu;
  double var = blk_sumd(d0*d0 + d1*d1, red) * (1.0/512.0);
  double inv = 1.0 / sqrt(var + 1e-5);
  float y0 = (float)(d0 * inv * (double)g[t]       + (double)bt[t]);
  float y1 = (float)(d1 * inv * (double)g[t + 256] + (double)bt[t + 256]);
  unsigned short h0 = f2bf(y0), h1 = f2bf(y1);
  rh[t] = h0;       rl[t] = f2bf(y0 - bf2f(h0));
  rh[t + 256] = h1; rl[t + 256] = f2bf(y1 - bf2f(h1));
}

// ---------------- landmarks: ql (scaled by 1/8), kl ----------------
__global__ void landmark(const float* __restrict__ qkv, float* __restrict__ ql, float* __restrict__ kl){
  int blk = blockIdx.x;            // bh*256 + m
  int bh = blk >> 8, m = blk & 255;
  int b = bh >> 3, hh = bh & 7;
  int d = threadIdx.x;             // 64
  float sq = 0.f, sk = 0.f;
  for (int l = 0; l < 17; ++l) {
    size_t o = ((size_t)b * NPAD + m * 17 + l) * NT + hh * 64 + d;
    sq += qkv[o];
    sk += qkv[o + 512];
  }
  ql[((size_t)bh * 256 + m) * 64 + d] = 0.125f * sq / 17.f;
  kl[((size_t)bh * 256 + m) * 64 + d] = sk / 17.f;
}

// klT[bh][d][m] = kl[bh][m][d]; grid (LM/64, 16)
__global__ __launch_bounds__(256) void transpose_kl(const float* __restrict__ kl, float* __restrict__ klT){
  __shared__ float tile[64][65];
  int bh = blockIdx.y;
  int m0 = blockIdx.x * 64;
  int t = threadIdx.x;
  for (int i = t; i < 4096; i += 256) {
    int r = i >> 6, c = i & 63;
    tile[r][c] = kl[((size_t)bh * 256 + m0 + r) * 64 + c];
  }
  __syncthreads();
  float* kb = klT + (size_t)bh * 64 * 256;
  for (int i = t; i < 4096; i += 256) {
    int d = i >> 6, mm = i & 63;
    kb[(size_t)d * 256 + m0 + mm] = tile[mm][d];
  }
}

// ---------------- a2 = softmax(ql @ kl^T) ----------------
__global__ __launch_bounds__(256) void a2_kernel(const float* __restrict__ ql, const float* __restrict__ klT,
                                                 float* __restrict__ a2){
  __shared__ float qs[64]; __shared__ float red[256];
  int blk = blockIdx.x;            // bh*256 + i
  int bh = blk >> 8, i = blk & 255;
  int t = threadIdx.x;
  if (t < 64) qs[t] = ql[((size_t)bh * 256 + i) * 64 + t];
  __syncthreads();
  const float* kb = klT + (size_t)bh * 16384;
  float s = 0.f;
  #pragma unroll
  for (int d = 0; d < 64; ++d) s += qs[d] * kb[d * 256 + t];
  float mx = blk_max(s, red);
  float e = expf(s - mx);
  float sum = blk_sum(e, red);
  a2[((size_t)bh * 256 + i) * 256 + t] = e / sum;
}

// per-(b,h) max colsum / rowsum
__global__ __launch_bounds__(256) void colrow_max(const float* __restrict__ a2, float* __restrict__ scal){
  __shared__ float red[256];
  int bh = blockIdx.x, t = threadIdx.x;
  const float* A = a2 + (size_t)bh * 65536;
  float cs = 0.f, rs = 0.f;
  for (int i = 0; i < 256; ++i) cs += A[(size_t)i * 256 + t];
  for (int j = 0; j < 256; ++j) rs += A[(size_t)t * 256 + j];
  float cmax = blk_max(cs, red);
  float rmax = blk_max(rs, red);
  if (t == 0) { scal[bh] = cmax; scal[16 + bh] = rmax; }
}
__global__ void scal_red(float* scal){
  if (threadIdx.x == 0) {
    float cm = scal[0], rm = scal[16];
    for (int i = 1; i < 16; ++i) { cm = fmaxf(cm, scal[i]); rm = fmaxf(rm, scal[16 + i]); }
    scal[32] = 1.f / (rm * cm);
  }
}

// ================= flash-attention tiles (split-bf16 MFMA matmuls, fp32 online softmax) =================
// fa3v: Q=ql (64 rows/block), K from KsH/KsL [row][512], V^T from VTH/VTL [bh][64][NPAD].
// grid (17, 4, 16)
__global__ __launch_bounds__(256) void fa3v_kernel(const unsigned short* __restrict__ KsH,
                                                   const unsigned short* __restrict__ KsL,
                                                   const unsigned short* __restrict__ VTH,
                                                   const unsigned short* __restrict__ VTL,
                                                   const float* __restrict__ ql,
                                                   float* __restrict__ accp, float* __restrict__ mlp){
  int part = blockIdx.x, qt = blockIdx.y, bh = blockIdx.z;
  int b = bh >> 3, hh = bh & 7;
  int t = threadIdx.x;
  int w = t >> 6, l = t & 63;
  int lr = l & 15, lk = (l >> 4) << 3;
  int w16 = w * 16;
  int crb = (l >> 4) << 2;
  __shared__ unsigned short KH[64][72], KL[64][72];   // K [krow][d]; later V^T [d][krow]
  __shared__ unsigned short PH[64][72], PL[64][72];   // P [qrow][krow]
  __shared__ float Ss[64][68];
  __shared__ float redm[64][4];
  __shared__ float mrow[64], lrow[64], scales[64];
  bf16x8 qh[2], qlo[2];
  {
    const float* qrow = ql + ((size_t)bh * 256 + qt * 64 + w16 + lr) * 64;
    #pragma unroll
    for (int s = 0; s < 2; ++s) {
      #pragma unroll
      for (int e = 0; e < 8; ++e) {
        float v = qrow[s * 32 + lk + e];
        unsigned short hv = f2bf(v);
        qh[s][e]  = (short)hv;
        qlo[s][e] = (short)f2bf(v - bf2f(hv));
      }
    }
  }
  if (t < 64) { mrow[t] = -3.4e38f; lrow[t] = 0.f; }
  f32x4 acc[4];
  #pragma unroll
  for (int j = 0; j < 4; ++j) acc[j] = (f32x4){0.f,0.f,0.f,0.f};
  __syncthreads();
  int rr = t >> 2, sg = (t & 3) << 4;
  for (int tile = 0; tile < 4; ++tile) {
    int nbase = part * 256 + tile * 64;
    // stage K (pure ushort8 copies)
    {
      const unsigned short* kbH = KsH + ((size_t)b * NPAD + nbase) * 512 + hh * 64;
      const unsigned short* kbL = KsL + ((size_t)b * NPAD + nbase) * 512 + hh * 64;
      #pragma unroll
      for (int u = 0; u < 2; ++u) {
        int i = t + u * 256;
        int r = i >> 3, c8 = (i & 7) << 3;
        *(bf16x8*)&KH[r][c8] = *(const bf16x8*)(kbH + (size_t)r * 512 + c8);
        *(bf16x8*)&KL[r][c8] = *(const bf16x8*)(kbL + (size_t)r * 512 + c8);
      }
    }
    __syncthreads();
    #pragma unroll
    for (int j = 0; j < 4; ++j) {
      f32x4 sf = (f32x4){0.f,0.f,0.f,0.f};
      #pragma unroll
      for (int s = 0; s < 2; ++s) {
        bf16x8 kh8 = *(const bf16x8*)&KH[j*16 + lr][s*32 + lk];
        bf16x8 kl8 = *(const bf16x8*)&KL[j*16 + lr][s*32 + lk];
        sf = __builtin_amdgcn_mfma_f32_16x16x32_bf16(qh[s],  kh8, sf, 0,0,0);
        sf = __builtin_amdgcn_mfma_f32_16x16x32_bf16(qh[s],  kl8, sf, 0,0,0);
        sf = __builtin_amdgcn_mfma_f32_16x16x32_bf16(qlo[s], kh8, sf, 0,0,0);
      }
      #pragma unroll
      for (int r = 0; r < 4; ++r) Ss[w16 + crb + r][j*16 + lr] = sf[r];
    }
    __syncthreads();   // S complete; K reads done
    // stage V^T (row-contiguous copies)
    {
      const unsigned short* vbH = VTH + (size_t)bh * 64 * NPAD + nbase;
      const unsigned short* vbL = VTL + (size_t)bh * 64 * NPAD + nbase;
      #pragma unroll
      for (int u = 0; u < 2; ++u) {
        int i = t + u * 256;
        int d = i >> 3, c8 = (i & 7) << 3;
        *(bf16x8*)&KH[d][c8] = *(const bf16x8*)(vbH + (size_t)d * NPAD + c8);
        *(bf16x8*)&KL[d][c8] = *(const bf16x8*)(vbL + (size_t)d * NPAD + c8);
      }
    }
    float lm = -3.4e38f;
    #pragma unroll
    for (int c = 0; c < 16; ++c) lm = fmaxf(lm, Ss[rr][sg + c]);
    redm[rr][t & 3] = lm;
    float mold = mrow[rr];
    float rm = fmaxf(fmaxf(redm[rr][0], redm[rr][1]), fmaxf(redm[rr][2], redm[rr][3]));
    float mnew = fmaxf(mold, rm);
    float sc_r = expf(mold - mnew);
    if ((t & 3) == 0) { scales[rr] = sc_r; mrow[rr] = mnew; }
    float ls = 0.f;
    #pragma unroll
    for (int c = 0; c < 16; ++c) {
      float p = expf(Ss[rr][sg + c] - mnew);
      unsigned short hv = f2bf(p);
      PH[rr][sg + c] = hv; PL[rr][sg + c] = f2bf(p - bf2f(hv));
      ls += p;
    }
    redm[rr][t & 3] = ls;
    __syncthreads();   // V^T staged, P split, scales ready
    if ((t & 3) == 0) lrow[rr] = lrow[rr] * sc_r + redm[rr][0]+redm[rr][1]+redm[rr][2]+redm[rr][3];
    {
      float s0 = scales[w16 + crb], s1 = scales[w16 + crb + 1],
            s2 = scales[w16 + crb + 2], s3 = scales[w16 + crb + 3];
      #pragma unroll
      for (int j = 0; j < 4; ++j) { acc[j][0]*=s0; acc[j][1]*=s1; acc[j][2]*=s2; acc[j][3]*=s3; }
    }
    bf16x8 pah[2], pal[2];
    #pragma unroll
    for (int s = 0; s < 2; ++s) {
      pah[s] = *(const bf16x8*)&PH[w16 + lr][s*32 + lk];
      pal[s] = *(const bf16x8*)&PL[w16 + lr][s*32 + lk];
    }
    #pragma unroll
    for (int j = 0; j < 4; ++j) {
      #pragma unroll
      for (int s = 0; s < 2; ++s) {
        bf16x8 vh = *(const bf16x8*)&KH[j*16 + lr][s*32 + lk];
        bf16x8 vl = *(const bf16x8*)&KL[j*16 + lr][s*32 + lk];
        acc[j] = __builtin_amdgcn_mfma_f32_16x16x32_bf16(pah[s], vh, acc[j], 0,0,0);
        acc[j] = __builtin_amdgcn_mfma_f32_16x16x32_bf16(pah[s], vl, acc[j], 0,0,0);
        acc[j] = __builtin_amdgcn_mfma_f32_16x16x32_bf16(pal[s], vh, acc[j], 0,0,0);
      }
    }
    __syncthreads();   // before next tile overwrites KH/PH
  }
  int blk = (bh * 4 + qt) * 17 + part;
  float* ap = accp + (size_t)blk * 4096;
  #pragma unroll
  for (int j = 0; j < 4; ++j)
    #pragma unroll
    for (int r = 0; r < 4; ++r)
      ap[(w16 + crb + r) * 64 + j*16 + lr] = acc[j][r];
  if (t < 64) { mlp[(size_t)blk*128 + t] = mrow[t]; mlp[(size_t)blk*128 + 64 + t] = lrow[t]; }
}

// combine 17 partials -> av ; grid 64 = bh*4+qt
__global__ __launch_bounds__(256) void fa3v_combine(const float* __restrict__ accp, const float* __restrict__ mlp,
                                                    float* __restrict__ av){
  int g = blockIdx.x;
  int t = threadIdx.x;
  int r = t >> 2, sg = (t & 3) << 4;
  int bh = g >> 2, qt = g & 3;
  float mp[17], lp[17];
  #pragma unroll
  for (int p = 0; p < 17; ++p) {
    mp[p] = mlp[(size_t)(g*17+p)*128 + r];
    lp[p] = mlp[(size_t)(g*17+p)*128 + 64 + r];
  }
  float M = mp[0];
  #pragma unroll
  for (int p = 1; p < 17; ++p) M = fmaxf(M, mp[p]);
  float w[17]; float L = 0.f;
  #pragma unroll
  for (int p = 0; p < 17; ++p) { w[p] = expf(mp[p] - M); L += w[p] * lp[p]; }
  float invL = 1.f / L;
  #pragma unroll
  for (int c = 0; c < 16; ++c) {
    float s = 0.f;
    #pragma unroll
    for (int p = 0; p < 17; ++p) s += w[p] * accp[(size_t)(g*17+p)*4096 + r*64 + sg + c];
    av[((size_t)(bh*256 + qt*64 + r))*64 + sg + c] = s * invL;
  }
}

// fa1: Q = qkv.q*0.125; K from klsH/L [bh*256+m][64]; V^T from zavTH/L [bh][64][256].
// merged += P@V/l; also emits merged splits. grid (68, 16)
__global__ __launch_bounds__(256) void fa1_kernel(const float* __restrict__ qkv,
                                                  const unsigned short* __restrict__ klsH,
                                                  const unsigned short* __restrict__ klsL,
                                                  const unsigned short* __restrict__ zavTH,
                                                  const unsigned short* __restrict__ zavTL,
                                                  float* __restrict__ merged,
                                                  unsigned short* __restrict__ merH,
                                                  unsigned short* __restrict__ merL){
  int nt = blockIdx.x, bh = blockIdx.y;
  int b = bh >> 3, hh = bh & 7;
  int t = threadIdx.x;
  int w = t >> 6, l = t & 63;
  int lr = l & 15, lk = (l >> 4) << 3;
  int w16 = w * 16;
  int crb = (l >> 4) << 2;
  int n0 = nt * 64;
  __shared__ unsigned short KH[64][72], KL[64][72];
  __shared__ unsigned short PH[64][72], PL[64][72];
  __shared__ float Ss[64][68];
  __shared__ float redm[64][4];
  __shared__ float mrow[64], lrow[64], scales[64];
  bf16x8 qh[2], qlo[2];
  {
    const float* qrow = qkv + ((size_t)b * NPAD + n0 + w16 + lr) * NT + hh * 64;
    #pragma unroll
    for (int s = 0; s < 2; ++s) {
      #pragma unroll
      for (int e = 0; e < 8; ++e) {
        float v = 0.125f * qrow[s * 32 + lk + e];
        unsigned short hv = f2bf(v);
        qh[s][e]  = (short)hv;
        qlo[s][e] = (short)f2bf(v - bf2f(hv));
      }
    }
  }
  if (t < 64) { mrow[t] = -3.4e38f; lrow[t] = 0.f; }
  f32x4 acc[4];
  #pragma unroll
  for (int j = 0; j < 4; ++j) acc[j] = (f32x4){0.f,0.f,0.f,0.f};
  __syncthreads();
  int rr = t >> 2, sg = (t & 3) << 4;
  for (int tile = 0; tile < 4; ++tile) {
    int mbase = tile * 64;
    {
      const unsigned short* kbH = klsH + ((size_t)bh * 256 + mbase) * 64;
      const unsigned short* kbL = klsL + ((size_t)bh * 256 + mbase) * 64;
      #pragma unroll
      for (int u = 0; u < 2; ++u) {
        int i = t + u * 256;
        int r = i >> 3, c8 = (i & 7) << 3;
        *(bf16x8*)&KH[r][c8] = *(const bf16x8*)(kbH + (size_t)r * 64 + c8);
        *(bf16x8*)&KL[r][c8] = *(const bf16x8*)(kbL + (size_t)r * 64 + c8);
      }
    }
    __syncthreads();
    #pragma unroll
    for (int j = 0; j < 4; ++j) {
      f32x4 sf = (f32x4){0.f,0.f,0.f,0.f};
      #pragma unroll
      for (int s = 0; s < 2; ++s) {
        bf16x8 kh8 = *(const bf16x8*)&KH[j*16 + lr][s*32 + lk];
        bf16x8 kl8 = *(const bf16x8*)&KL[j*16 + lr][s*32 + lk];
        sf = __builtin_amdgcn_mfma_f32_16x16x32_bf16(qh[s],  kh8, sf, 0,0,0);
        sf = __builtin_amdgcn_mfma_f32_16x16x32_bf16(qh[s],  kl8, sf, 0,0,0);
        sf = __builtin_amdgcn_mfma_f32_16x16x32_bf16(qlo[s], kh8, sf, 0,0,0);
      }
      #pragma unroll
      for (int r = 0; r < 4; ++r) Ss[w16 + crb + r][j*16 + lr] = sf[r];
    }
    __syncthreads();
    {
      const unsigned short* vbH = zavTH + (size_t)bh * 64 * 256 + mbase;
      const unsigned short* vbL = zavTL + (size_t)bh * 64 * 256 + mbase;
      #pragma unroll
      for (int u = 0; u < 2; ++u) {
        int i = t + u * 256;
        int d = i >> 3, c8 = (i & 7) << 3;
        *(bf16x8*)&KH[d][c8] = *(const bf16x8*)(vbH + (size_t)d * 256 + c8);
        *(bf16x8*)&KL[d][c8] = *(const bf16x8*)(vbL + (size_t)d * 256 + c8);
      }
    }
    float lm = -3.4e38f;
    #pragma unroll
    for (int c = 0; c < 16; ++c) lm = fmaxf(lm, Ss[rr][sg + c]);
    redm[rr][t & 3] = lm;
    float mold = mrow[rr];
    float rm = fmaxf(fmaxf(redm[rr][0], redm[rr][1]), fmaxf(redm[rr][2], redm[rr][3]));
    float mnew = fmaxf(mold, rm);
    float sc_r = expf(mold - mnew);
    if ((t & 3) == 0) { scales[rr] = sc_r; mrow[rr] = mnew; }
    float ls = 0.f;
    #pragma unroll
    for (int c = 0; c < 16; ++c) {
      float p = expf(Ss[rr][sg + c] - mnew);
      unsigned short hv = f2bf(p);
      PH[rr][sg + c] = hv; PL[rr][sg + c] = f2bf(p - bf2f(hv));
      ls += p;
    }
    redm[rr][t & 3] = ls;
    __syncthreads();
    if ((t & 3) == 0) lrow[rr] = lrow[rr] * sc_r + redm[rr][0]+redm[rr][1]+redm[rr][2]+redm[rr][3];
    {
      float s0 = scales[w16 + crb], s1 = scales[w16 + crb + 1],
            s2 = scales[w16 + crb + 2], s3 = scales[w16 + crb + 3];
      #pragma unroll
      for (int j = 0; j < 4; ++j) { acc[j][0]*=s0; acc[j][1]*=s1; acc[j][2]*=s2; acc[j][3]*=s3; }
    }
    bf16x8 pah[2], pal[2];
    #pragma unroll
    for (int s = 0; s < 2; ++s) {
      pah[s] = *(const bf16x8*)&PH[w16 + lr][s*32 + lk];
      pal[s] = *(const bf16x8*)&PL[w16 + lr][s*32 + lk];
    }
    #pragma unroll
    for (int j = 0; j < 4; ++j) {
      #pragma unroll
      for (int s = 0; s < 2; ++s) {
        bf16x8 vh = *(const bf16x8*)&KH[j*16 + lr][s*32 + lk];
        bf16x8 vl = *(const bf16x8*)&KL[j*16 + lr][s*32 + lk];
        acc[j] = __builtin_amdgcn_mfma_f32_16x16x32_bf16(pah[s], vh, acc[j], 0,0,0);
        acc[j] = __builtin_amdgcn_mfma_f32_16x16x32_bf16(pah[s], vl, acc[j], 0,0,0);
        acc[j] = __builtin_amdgcn_mfma_f32_16x16x32_bf16(pal[s], vh, acc[j], 0,0,0);
      }
    }
    __syncthreads();
  }
  #pragma unroll
  for (int r = 0; r < 4; ++r) {
    float invl = 1.f / lrow[w16 + crb + r];
    size_t rowoff = ((size_t)b * NPAD + n0 + w16 + crb + r) * DIM + hh * 64;
    float* mp = &merged[rowoff];
    #pragma unroll
    for (int j = 0; j < 4; ++j) {
      float v = mp[j*16 + lr] + acc[j][r] * invl;
      mp[j*16 + lr] = v;
      unsigned short hv = f2bf(v);
      merH[rowoff + j*16 + lr] = hv;
      merL[rowoff + j*16 + lr] = f2bf(v - bf2f(hv));
    }
  }
}

// ---------------- depthwise 33x1 residual conv on v -> merged (LDS strip tiled) ----------------
__global__ __launch_bounds__(256) void conv_res(const float* __restrict__ qkv, const float* __restrict__ rk,
                                                float* __restrict__ merged){
  __shared__ float vt[288][16];
  __shared__ float rks[33];
  int n0 = blockIdx.x * 256;
  int c0 = blockIdx.y * 16;
  int b  = blockIdx.z;
  int t = threadIdx.x;
  int hh = c0 >> 6;
  if (t < 33) rks[t] = rk[hh * 33 + t];
  for (int i = t; i < 288 * 4; i += 256) {
    int sp = i >> 2, q = (i & 3) << 2;
    int n = n0 - 16 + sp;
    float4 v = make_float4(0.f,0.f,0.f,0.f);
    if (n >= 0 && n < NPAD)
      v = *(const float4*)&qkv[((size_t)b * NPAD + n) * NT + 1024 + c0 + q];
    vt[sp][q] = v.x; vt[sp][q+1] = v.y; vt[sp][q+2] = v.z; vt[sp][q+3] = v.w;
  }
  __syncthreads();
  int c = t & 15, g = t >> 4;
  for (int m = 0; m < 16; ++m) {
    int nl = g + m * 16;
    float acc = 0.f;
    #pragma unroll
    for (int kk = 0; kk < 33; ++kk) acc += rks[kk] * vt[nl + kk][c];
    merged[((size_t)b * NPAD + n0 + nl) * DIM + c0 + c] = acc;
  }
}

// ---------------- PPEG depthwise convs (LDS tiled) ----------------
__global__ __launch_bounds__(256) void dwconv(const float* __restrict__ hsrc,
    const float* __restrict__ w7, const float* __restrict__ b7,
    const float* __restrict__ w5, const float* __restrict__ b5,
    const float* __restrict__ w3, const float* __restrict__ b3,
    float* __restrict__ hdst){
  __shared__ float tile[484][16];
  __shared__ float wS7[49][16], wS5[25][16], wS3[9][16];
  int st = blockIdx.x;
  int y0 = (st >> 2) * 16, x0 = (st & 3) * 16;
  int c0 = blockIdx.y * 16;
  int b  = blockIdx.z;
  int t = threadIdx.x;
  const float* fb = hsrc + ((size_t)b * N1 + 1) * DIM;
  for (int i = t; i < 49 * 16; i += 256) { int k = i >> 4, c = i & 15; wS7[k][c] = w7[(size_t)(c0 + c) * 49 + k]; }
  for (int i = t; i < 25 * 16; i += 256) { int k = i >> 4, c = i & 15; wS5[k][c] = w5[(size_t)(c0 + c) * 25 + k]; }
  for (int i = t; i <  9 * 16; i += 256) { int k = i >> 4, c = i & 15; wS3[k][c] = w3[(size_t)(c0 + c) * 9 + k]; }
  for (int i = t; i < 484 * 4; i += 256) {
    int sp = i >> 2, q = (i & 3) << 2;
    int yy = y0 - 3 + sp / 22, xx = x0 - 3 + sp % 22;
    float4 v = make_float4(0.f,0.f,0.f,0.f);
    if (yy >= 0 && yy < 64 && xx >= 0 && xx < 64)
      v = *(const float4*)&fb[(size_t)(yy * 64 + xx) * DIM + c0 + q];
    tile[sp][q] = v.x; tile[sp][q+1] = v.y; tile[sp][q+2] = v.z; tile[sp][q+3] = v.w;
  }
  __syncthreads();
  int c = t & 15, g = t >> 4;
  float bsum = b7[c0 + c] + b5[c0 + c] + b3[c0 + c];
  for (int m = 0; m < 16; ++m) {
    int p = g + m * 16;
    int y = p >> 4, x = p & 15;
    float acc = tile[(y + 3) * 22 + (x + 3)][c] + bsum;
    #pragma unroll
    for (int ky = 0; ky < 7; ++ky)
      #pragma unroll
      for (int kx = 0; kx < 7; ++kx)
        acc += wS7[ky * 7 + kx][c] * tile[(y + ky) * 22 + (x + kx)][c];
    #pragma unroll
    for (int ky = 0; ky < 5; ++ky)
      #pragma unroll
      for (int kx = 0; kx < 5; ++kx)
        acc += wS5[ky * 5 + kx][c] * tile[(y + 1 + ky) * 22 + (x + 1 + kx)][c];
    #pragma unroll
    for (int ky = 0; ky < 3; ++ky)
      #pragma unroll
      for (int kx = 0; kx < 3; ++kx)
        acc += wS3[ky * 3 + kx][c] * tile[(y + 2 + ky) * 22 + (x + 2 + kx)][c];
    int spg = (y0 + y) * 64 + (x0 + x);
    hdst[((size_t)b * N1 + 1 + spg) * DIM + c0 + c] = acc;
  }
}

__global__ void set_cls(float* h, const float* cls){
  int t = threadIdx.x;
  if (t < 1024) { int b = t >> 9, c = t & 511; h[(size_t)b * N1 * DIM + c] = cls[c]; }
}
__global__ void copy_cls(float* dst, const float* src){
  int t = threadIdx.x;
  if (t < 1024) { int b = t >> 9, c = t & 511; dst[(size_t)b * N1 * DIM + c] = src[(size_t)b * N1 * DIM + c]; }
}

__global__ __launch_bounds__(256) void final_ln(const float* __restrict__ h2, const float* __restrict__ g,
                                                const float* __restrict__ bt, float* __restrict__ hcls){
  __shared__ double red[256];
  int b = blockIdx.x, t = threadIdx.x;
  const float* x = h2 + (size_t)b * N1 * DIM;
  double x0 = (double)x[t], x1 = (double)x[t + 256];
  double mu = blk_sumd(x0 + x1, red) * (1.0/512.0);
  double d0 = x0 - mu, d1 = x1 - mu;
  double var = blk_sumd(d0*d0 + d1*d1, red) * (1.0/512.0);
  double inv = 1.0 / sqrt(var + 1e-5);
  hcls[b * 512 + t]       = (float)(d0 * inv * (double)g[t]       + (double)bt[t]);
  hcls[b * 512 + t + 256] = (float)(d1 * inv * (double)g[t + 256] + (double)bt[t + 256]);
}

// xc rows (split-bf16 only; feeds dsl1 MFMA gemm)
__global__ void build_xc_split(const float* __restrict__ hcls, const float* __restrict__ reh,
                               unsigned short* __restrict__ xcH, unsigned short* __restrict__ xcL){
  size_t idx = (size_t)blockIdx.x * 256 + threadIdx.x;
  int row = (int)(idx >> 9), c = (int)(idx & 511);
  float v = (row < 2) ? hcls[row * 512 + c] : reh[(size_t)(row - 2) * 512 + c];
  unsigned short hh = f2bf(v);
  xcH[idx] = hh; xcL[idx] = f2bf(v - bf2f(hh));
}

__global__ __launch_bounds__(256) void norms_k(const float* __restrict__ xg, double* __restrict__ rn){
  __shared__ double red[256];
  int i = blockIdx.x, t = threadIdx.x;
  double a = (double)xg[(size_t)i * 512 + t], b = (double)xg[(size_t)i * 512 + t + 256];
  double s = blk_sumd(a*a + b*b, red);
  if (t == 0) rn[i] = sqrt(s);
}

__global__ __launch_bounds__(256) void topk_k(const float* __restrict__ xg, const double* __restrict__ rn,
                                              int* __restrict__ idxb){
  __shared__ double sc[256]; __shared__ double redv[256]; __shared__ int redi[256];
  int i = blockIdx.x, j = threadIdx.x;
  const float* xi = xg + (size_t)i * 512;
  const float* xj = xg + (size_t)j * 512;
  double s = 0.;
  for (int c = 0; c < 512; ++c) s += (double)xi[c] * (double)xj[c];
  s /= (rn[i] * rn[j]);
  sc[j] = s; __syncthreads();
  for (int r = 0; r < 4; ++r) {
    redv[j] = sc[j]; redi[j] = j; __syncthreads();
    for (int st = 128; st > 0; st >>= 1) {
      if (j < st) {
        if (redv[j + st] > redv[j] || (redv[j + st] == redv[j] && redi[j + st] < redi[j])) {
          redv[j] = redv[j + st]; redi[j] = redi[j + st];
        }
      }
      __syncthreads();
    }
    if (j == 0) { idxb[i * 4 + r] = redi[0]; sc[redi[0]] = -1e300; }
    __syncthreads();
  }
}

// edge = mean of 4 gathered xg rows; writes fp32 + split
__global__ void edge_k_split(const float* __restrict__ xg, const int* __restrict__ idxb,
                             float* __restrict__ edge,
                             unsigned short* __restrict__ eH, unsigned short* __restrict__ eL){
  size_t idx = (size_t)blockIdx.x * 256 + threadIdx.x;
  int i = (int)(idx >> 9), c = (int)(idx & 511);
  const int* id = idxb + i * 4;
  float v = 0.25f * (xg[(size_t)id[0]*512 + c] + xg[(size_t)id[1]*512 + c] +
                     xg[(size_t)id[2]*512 + c] + xg[(size_t)id[3]*512 + c]);
  edge[idx] = v;
  unsigned short hh = f2bf(v);
  eH[idx] = hh; eL[idx] = f2bf(v - bf2f(hh));
}
// h1pn = xg + edge (split only)
__global__ void vadd_split(const float* __restrict__ a, const float* __restrict__ b,
                           unsigned short* __restrict__ oH, unsigned short* __restrict__ oL){
  size_t idx = (size_t)blockIdx.x * 256 + threadIdx.x;
  float v = a[idx] + b[idx];
  unsigned short hh = f2bf(v);
  oH[idx] = hh; oL[idx] = f2bf(v - bf2f(hh));
}
// h1pn2 = h1 + mean(h1[idx]) (split only)
__global__ void h1gather_split(const float* __restrict__ h1, const int* __restrict__ idxb,
                               unsigned short* __restrict__ oH, unsigned short* __restrict__ oL){
  size_t idx = (size_t)blockIdx.x * 256 + threadIdx.x;
  int i = (int)(idx >> 9), c = (int)(idx & 511);
  const int* id = idxb + i * 4;
  float v = h1[idx] + 0.25f * (h1[(size_t)id[0]*512 + c] + h1[(size_t)id[1]*512 + c] +
                               h1[(size_t)id[2]*512 + c] + h1[(size_t)id[3]*512 + c]);
  unsigned short hh = f2bf(v);
  oH[idx] = hh; oL[idx] = f2bf(v - bf2f(hh));
}

__global__ void logits2(const float* __restrict__ src, const float* __restrict__ w,
                        const float* __restrict__ bias, float* __restrict__ out){
  int rc = blockIdx.x; int r = rc >> 1, c = rc & 1;
  int t = threadIdx.x; // 64
  double s = 0.;
  for (int k = t; k < 512; k += 64) s += (double)src[(size_t)r * 512 + k] * (double)w[(size_t)c * 512 + k];
  for (int off = 32; off > 0; off >>= 1) s += __shfl_down(s, off);
  if (t == 0) out[rc] = (float)(s + (double)bias[c]);
}

__global__ void sentinel_k(float* out){ if (threadIdx.x < 12) out[threadIdx.x] = 1e30f; }

// ---------------- host-side nystrom block ----------------
struct NysBufs {
  float *qkv, *ql, *kl, *klT, *av, *zav, *merged;
  float *a2f32, *scal, *accp, *mlp;
  unsigned short *padH, *padL, *merH, *merL, *wqH, *wqL, *owH, *owL;
  unsigned short *a2H, *a2L;
  unsigned short *zAH, *zAL, *zATH, *zATL;
  unsigned short *zBH, *zBL, *zBTH, *zBTL;
  unsigned short *azH, *azL, *t1TH, *t1TL, *t2TH, *t2TL;
  unsigned short *avTH, *avTL;
  unsigned short *KsH, *KsL, *VTH, *VTL;
  unsigned short *klsH, *klsL, *zavTH, *zavTL;
};

static void run_nystrom(hipStream_t stream, float* hbuf,
                        const float* lng, const float* lnb, const float* qkvw,
                        const float* outw, const float* outb, const float* rk,
                        const NysBufs& w)
{
  ln_pad_split<<<BB * NPAD, 256, 0, stream>>>(hbuf, w.padH, w.padL, lng, lnb);
  split_k<<<(NT * DIM / 4 + 255) / 256, 256, 0, stream>>>(qkvw, w.wqH, w.wqL, NT * DIM / 4);
  gemm_mfma<<<dim3(NT/128, (BB*NPAD)/128), 256, 0, stream>>>(w.padH, w.padL, w.wqH, w.wqL,
                                                             nullptr, nullptr, w.qkv,
                                                             BB*NPAD, NT, DIM, 0, nullptr, nullptr);
  split_kcols<<<BB * NPAD * 128 / 256, 256, 0, stream>>>(w.qkv, w.KsH, w.KsL);
  transpose_split_v<<<dim3(NPAD/64, 16), 256, 0, stream>>>(w.qkv, w.VTH, w.VTL);
  landmark<<<BB * NH * LM, 64, 0, stream>>>(w.qkv, w.ql, w.kl);
  transpose_kl<<<dim3(LM/64, 16), 256, 0, stream>>>(w.kl, w.klT);
  split_k<<<(16 * LM * DH / 4 + 255) / 256, 256, 0, stream>>>(w.kl, w.klsH, w.klsL, 16 * LM * DH / 4);
  fa3v_kernel<<<dim3(17, 4, 16), 256, 0, stream>>>(w.KsH, w.KsL, w.VTH, w.VTL, w.ql, w.accp, w.mlp);
  fa3v_combine<<<64, 256, 0, stream>>>(w.accp, w.mlp, w.av);
  split_T_av<<<1024, 256, 0, stream>>>(w.av, w.avTH, w.avTL);
  a2_kernel<<<BB * NH * LM, 256, 0, stream>>>(w.ql, w.klT, w.a2f32);
  colrow_max<<<16, 256, 0, stream>>>(w.a2f32, w.scal);
  scal_red<<<1, 64, 0, stream>>>(w.scal);
  split_k<<<(16 * 65536 / 4 + 255) / 256, 256, 0, stream>>>(w.a2f32, w.a2H, w.a2L, 16 * 65536 / 4);
  z0_split<<<4096, 256, 0, stream>>>(w.a2f32, w.scal, w.zAH, w.zAL, w.zATH, w.zATL);
  const unsigned short *zcH = w.zAH, *zcL = w.zAL, *zcTH = w.zATH, *zcTL = w.zATL;
  unsigned short *znH = w.zBH, *znL = w.zBL, *znTH = w.zBTH, *znTL = w.zBTL;
  for (int it = 0; it < 6; ++it) {
    mm_mfma<<<dim3(8,8,16), 64, 0, stream>>>(w.a2H, w.a2L, zcTH, zcTL,
        w.azH, w.azL, nullptr, nullptr, w.t1TH, w.t1TL, nullptr, 256, 1.f, 0.f, 7.f);
    mm_mfma<<<dim3(8,8,16), 64, 0, stream>>>(w.azH, w.azL, w.t1TH, w.t1TL,
        nullptr, nullptr, w.t2TH, w.t2TL, nullptr, nullptr, nullptr, 256, -1.f, 15.f, 0.f);
    mm_mfma<<<dim3(8,8,16), 64, 0, stream>>>(w.azH, w.azL, w.t2TH, w.t2TL,
        nullptr, nullptr, w.t1TH, w.t1TL, nullptr, nullptr, nullptr, 256, -1.f, 13.f, 0.f);
    mm_mfma<<<dim3(8,8,16), 64, 0, stream>>>(zcH, zcL, w.t1TH, w.t1TL,
        znH, znL, znTH, znTL, nullptr, nullptr, nullptr, 256, 0.25f, 0.f, 0.f);
    const unsigned short* t;
    t = zcH; zcH = znH; znH = (unsigned short*)t;
    t = zcL; zcL = znL; znL = (unsigned short*)t;
    t = zcTH; zcTH = znTH; znTH = (unsigned short*)t;
    t = zcTL; zcTL = znTL; znTL = (unsigned short*)t;
  }
  mm_mfma<<<dim3(2,8,16), 64, 0, stream>>>(zcH, zcL, w.avTH, w.avTL,
      nullptr, nullptr, nullptr, nullptr, nullptr, nullptr, w.zav, 64, 1.f, 0.f, 0.f);
  split_T_av<<<1024, 256, 0, stream>>>(w.zav, w.zavTH, w.zavTL);
  conv_res<<<dim3(17, 32, 2), 256, 0, stream>>>(w.qkv, rk, w.merged);
  fa1_kernel<<<dim3(NPAD/64, 16), 256, 0, stream>>>(w.qkv, w.klsH, w.klsL, w.zavTH, w.zavTL,
                                                    w.merged, w.merH, w.merL);
  split_k<<<(DIM*DIM/4 + 255) / 256, 256, 0, stream>>>(outw, w.owH, w.owL, DIM*DIM/4);
  for (int b = 0; b < BB; ++b)
    gemm_mfma<<<dim3(DIM/128, (N1+127)/128), 256, 0, stream>>>(
        w.merH + ((size_t)b*NPAD + PADR)*DIM, w.merL + ((size_t)b*NPAD + PADR)*DIM,
        w.owH, w.owL, outb,
        hbuf + (size_t)b*N1*DIM, hbuf + (size_t)b*N1*DIM,
        N1, DIM, DIM, 0, nullptr, nullptr);
}

extern "C" void kernel_launch(void* const* d_in, const int* in_sizes, int n_in,
                              void* d_out, int out_size, void* d_ws, size_t ws_size,
                              hipStream_t stream) {
  (void)in_sizes; (void)n_in; (void)out_size;
  const float* x        = (const float*)d_in[0];
  const float* fc1_w    = (const float*)d_in[1];
  const float* fc1_b    = (const float*)d_in[2];
  const float* cls_tok  = (const float*)d_in[3];
  const float* ln1_g    = (const float*)d_in[4];
  const float* ln1_b    = (const float*)d_in[5];
  const float* qkv1_w   = (const float*)d_in[6];
  const float* out1_w   = (const float*)d_in[7];
  const float* out1_b   = (const float*)d_in[8];
  const float* res1_k   = (const float*)d_in[9];
  const float* ppeg_w7  = (const float*)d_in[10];
  const float* ppeg_b7  = (const float*)d_in[11];
  const float* ppeg_w5  = (const float*)d_in[12];
  const float* ppeg_b5  = (const float*)d_in[13];
  const float* ppeg_w3  = (const float*)d_in[14];
  const float* ppeg_b3  = (const float*)d_in[15];
  const float* ln2_g    = (const float*)d_in[16];
  const float* ln2_b    = (const float*)d_in[17];
  const float* qkv2_w   = (const float*)d_in[18];
  const float* out2_w   = (const float*)d_in[19];
  const float* out2_b   = (const float*)d_in[20];
  const float* res2_k   = (const float*)d_in[21];
  const float* norm_g   = (const float*)d_in[22];
  const float* norm_b   = (const float*)d_in[23];
  const float* fc2_w    = (const float*)d_in[24];
  const float* fc2_b    = (const float*)d_in[25];
  const float* dsl_w1   = (const float*)d_in[26];
  const float* dsl_b1   = (const float*)d_in[27];
  const float* dsl_w2   = (const float*)d_in[28];
  const float* dsl_b2   = (const float*)d_in[29];
  const float* gcn_w1   = (const float*)d_in[30];
  const float* gcn_we   = (const float*)d_in[31];
  const float* gcn_b1   = (const float*)d_in[32];
  const float* gcn_w2   = (const float*)d_in[33];
  const float* gcn_b2   = (const float*)d_in[34];
  const float* gcn_hw   = (const float*)d_in[35];
  const float* gcn_hb   = (const float*)d_in[36];
  const float* gcn_dw   = (const float*)d_in[37];
  const float* gcn_db   = (const float*)d_in[38];
  const float* rehearsal= (const float*)d_in[39];
  float* out = (float*)d_out;

  char* base = (char*)d_ws;
  size_t off = 0;
  auto takeb = [&](size_t bytes) { void* p = base + off; off += (bytes + 255) & ~(size_t)255; return p; };

  float* h    = (float*)takeb((size_t)BB * N1 * DIM * 4);
  float* h2   = (float*)takeb((size_t)BB * N1 * DIM * 4);
  NysBufs nb;
  nb.padH   = (unsigned short*)takeb((size_t)BB * NPAD * DIM * 2);
  nb.padL   = (unsigned short*)takeb((size_t)BB * NPAD * DIM * 2);
  nb.qkv    = (float*)takeb((size_t)BB * NPAD * NT * 4);
  nb.ql     = (float*)takeb((size_t)BB * NH * LM * DH * 4);
  nb.kl     = (float*)takeb((size_t)BB * NH * LM * DH * 4);
  nb.klT    = (float*)takeb((size_t)BB * NH * LM * DH * 4);
  nb.av     = (float*)takeb((size_t)BB * NH * LM * DH * 4);
  nb.zav    = (float*)takeb((size_t)BB * NH * LM * DH * 4);
  nb.merged = (float*)takeb((size_t)BB * NPAD * DIM * 4);
  nb.merH   = (unsigned short*)takeb((size_t)BB * NPAD * DIM * 2);
  nb.merL   = (unsigned short*)takeb((size_t)BB * NPAD * DIM * 2);
  nb.wqH    = (unsigned short*)takeb((size_t)NT * DIM * 2);
  nb.wqL    = (unsigned short*)takeb((size_t)NT * DIM * 2);
  nb.owH    = (unsigned short*)takeb((size_t)DIM * DIM * 2);
  nb.owL    = (unsigned short*)takeb((size_t)DIM * DIM * 2);
  nb.avTH   = (unsigned short*)takeb((size_t)16 * 64 * 256 * 2);
  nb.avTL   = (unsigned short*)takeb((size_t)16 * 64 * 256 * 2);
  nb.klsH   = (unsigned short*)takeb((size_t)16 * LM * DH * 2);
  nb.klsL   = (unsigned short*)takeb((size_t)16 * LM * DH * 2);
  nb.zavTH  = (unsigned short*)takeb((size_t)16 * 64 * 256 * 2);
  nb.zavTL  = (unsigned short*)takeb((size_t)16 * 64 * 256 * 2);
  nb.scal   = (float*)takeb(64 * 4);
  nb.mlp    = (float*)takeb((size_t)1088 * 128 * 4);
  float* hcls = (float*)takeb((size_t)BB * DIM * 4);
  float* xg1  = (float*)takeb((size_t)256 * 256 * 4);
  float* xg   = (float*)takeb((size_t)256 * 512 * 4);
  double* rn  = (double*)takeb(256 * 8);
  int*   idxb = (int*)takeb(1024 * 4);
  float* edge = (float*)takeb((size_t)256 * 512 * 4);
  float* h1g  = (float*)takeb((size_t)256 * 512 * 4);
  float* h2g  = (float*)takeb((size_t)256 * 512 * 4);
  unsigned short* xcH   = (unsigned short*)takeb((size_t)256 * 512 * 2);
  unsigned short* xcL   = (unsigned short*)takeb((size_t)256 * 512 * 2);
  unsigned short* dw1H  = (unsigned short*)takeb((size_t)256 * 512 * 2);
  unsigned short* dw1L  = (unsigned short*)takeb((size_t)256 * 512 * 2);
  unsigned short* xg1H  = (unsigned short*)takeb((size_t)256 * 256 * 2);
  unsigned short* xg1L  = (unsigned short*)takeb((size_t)256 * 256 * 2);
  unsigned short* dw2H  = (unsigned short*)takeb((size_t)512 * 256 * 2);
  unsigned short* dw2L  = (unsigned short*)takeb((size_t)512 * 256 * 2);
  unsigned short* h1pH  = (unsigned short*)takeb((size_t)256 * 512 * 2);
  unsigned short* h1pL  = (unsigned short*)takeb((size_t)256 * 512 * 2);
  unsigned short* gw1H  = (unsigned short*)takeb((size_t)512 * 512 * 2);
  unsigned short* gw1L  = (unsigned short*)takeb((size_t)512 * 512 * 2);
  unsigned short* edgeH = (unsigned short*)takeb((size_t)256 * 512 * 2);
  unsigned short* edgeL = (unsigned short*)takeb((size_t)256 * 512 * 2);
  unsigned short* gweH  = (unsigned short*)takeb((size_t)512 * 512 * 2);
  unsigned short* gweL  = (unsigned short*)takeb((size_t)512 * 512 * 2);
  unsigned short* h1p2H = (unsigned short*)takeb((size_t)256 * 512 * 2);
  unsigned short* h1p2L = (unsigned short*)takeb((size_t)256 * 512 * 2);
  unsigned short* gw2H  = (unsigned short*)takeb((size_t)512 * 512 * 2);
  unsigned short* gw2L  = (unsigned short*)takeb((size_t)512 * 512 * 2);

  const size_t MB2 = (size_t)16 * 65536;
  unsigned short* pr = nb.padH;
  nb.a2H  = pr;            nb.a2L  = pr + MB2;
  nb.zAH  = pr + 2*MB2;    nb.zAL  = pr + 3*MB2;
  nb.zATH = pr + 4*MB2;    nb.zATL = pr + 5*MB2;
  nb.azH  = pr + 6*MB2;    nb.azL  = pr + 7*MB2;
  unsigned short* mr = (unsigned short*)nb.merged;
  nb.zBH  = mr;            nb.zBL  = mr + MB2;
  nb.zBTH = mr + 2*MB2;    nb.zBTL = mr + 3*MB2;
  nb.t1TH = mr + 4*MB2;    nb.t1TL = mr + 5*MB2;
  nb.t2TH = mr + 6*MB2;    nb.t2TL = mr + 7*MB2;
  nb.a2f32 = (float*)(mr + 4*MB2);
  nb.accp  = nb.merged;
  nb.KsH = nb.padH;
  nb.KsL = nb.padL;
  nb.VTH = nb.merH;
  nb.VTL = nb.merL;

  if (ws_size < off) { sentinel_k<<<1, 64, 0, stream>>>(out); return; }

  // --- stage A: fc1 (MFMA split-bf16) + cls ---
  set_cls<<<1, 1024, 0, stream>>>(h, cls_tok);
  split_k<<<(BB*NSEQ*DIM/4 + 255) / 256, 256, 0, stream>>>(x, nb.merH, nb.merL, BB*NSEQ*DIM/4);
  split_k<<<(DIM*DIM/4 + 255) / 256, 256, 0, stream>>>(fc1_w, nb.owH, nb.owL, DIM*DIM/4);
  for (int b = 0; b < BB; ++b)
    gemm_mfma<<<dim3(DIM/128, NSEQ/128), 256, 0, stream>>>(
        nb.merH + (size_t)b*NSEQ*DIM, nb.merL + (size_t)b*NSEQ*DIM,
        nb.owH, nb.owL, fc1_b, nullptr,
        h + ((size_t)b*N1 + 1)*DIM, NSEQ, DIM, DIM, 1, nullptr, nullptr);
  // --- nystrom block 1 (residual into h) ---
  run_nystrom(stream, h, ln1_g, ln1_b, qkv1_w, out1_w, out1_b, res1_k, nb);

  // --- PPEG ---
  copy_cls<<<1, 1024, 0, stream>>>(h2, h);
  dwconv<<<dim3(16, 32, 2), 256, 0, stream>>>(h, ppeg_w7, ppeg_b7, ppeg_w5, ppeg_b5,
                                              ppeg_w3, ppeg_b3, h2);
  // --- nystrom block 2 (residual into h2) ---
  run_nystrom(stream, h2, ln2_g, ln2_b, qkv2_w, out2_w, out2_b, res2_k, nb);

  // --- final LN (row 0) + heads ---
  final_ln<<<BB, 256, 0, stream>>>(h2, norm_g, norm_b, hcls);
  logits2<<<4, 64, 0, stream>>>(hcls, fc2_w, fc2_b, out + 0);

  // --- GCN branch (MFMA split-bf16, barrier-free gemms) ---
  build_xc_split<<<512, 256, 0, stream>>>(hcls, rehearsal, xcH, xcL);
  split_k<<<(256*512/4 + 255) / 256, 256, 0, stream>>>(dsl_w1, dw1H, dw1L, 256*512/4);
  split_k<<<(512*256/4 + 255) / 256, 256, 0, stream>>>(dsl_w2, dw2H, dw2L, 512*256/4);
  split_k<<<(512*512/4 + 255) / 256, 256, 0, stream>>>(gcn_w1, gw1H, gw1L, 512*512/4);
  split_k<<<(512*512/4 + 255) / 256, 256, 0, stream>>>(gcn_we, gweH, gweL, 512*512/4);
  split_k<<<(512*512/4 + 255) / 256, 256, 0, stream>>>(gcn_w2, gw2H, gw2L, 512*512/4);
  gemm_mfma<<<dim3(2, 2), 256, 0, stream>>>(xcH, xcL, dw1H, dw1L, dsl_b1, nullptr,
                                            xg1, 256, 256, 512, 2, xg1H, xg1L);
  gemm_mfma<<<dim3(4, 2), 256, 0, stream>>>(xg1H, xg1L, dw2H, dw2L, dsl_b2, nullptr,
                                            xg, 256, 512, 256, 2, nullptr, nullptr);
  norms_k<<<256, 256, 0, stream>>>(xg, rn);
  topk_k<<<256, 256, 0, stream>>>(xg, rn, idxb);
  edge_k_split<<<512, 256, 0, stream>>>(xg, idxb, edge, edgeH, edgeL);
  vadd_split<<<512, 256, 0, stream>>>(xg, edge, h1pH, h1pL);
  gemm_mfma<<<dim3(4, 2), 256, 0, stream>>>(h1pH, h1pL, gw1H, gw1L, nullptr, nullptr,
                                            h1g, 256, 512, 512, 0, nullptr, nullptr);
  gemm_mfma<<<dim3(4, 2), 256, 0, stream>>>(edgeH, edgeL, gweH, gweL, gcn_b1, h1g,
                                            h1g, 256, 512, 512, 1, nullptr, nullptr);
  h1gather_split<<<512, 256, 0, stream>>>(h1g, idxb, h1p2H, h1p2L);
  gemm_mfma<<<dim3(4, 2), 256, 0, stream>>>(h1p2H, h1p2L, gw2H, gw2L, gcn_b2, nullptr,
                                            h2g, 256, 512, 512, 0, nullptr, nullptr);
  logits2<<<4, 64, 0, stream>>>(h2g, gcn_hw, gcn_hb, out + 4);
  logits2<<<4, 64, 0, stream>>>(h1g, gcn_dw, gcn_db, out + 8);
}

// Round 19
// 1730.349 us; speedup vs baseline: 1.2145x; 1.0055x over previous
//
#include <hip/hip_runtime.h>
#include <math.h>

#define BB 2
#define NSEQ 4096
#define N1 4097
#define NPAD 4352
#define PADR 255
#define DIM 512
#define NH 8
#define DH 64
#define LM 256
#define NT 1536

typedef short bf16x8 __attribute__((ext_vector_type(8)));
typedef float f32x4 __attribute__((ext_vector_type(4)));

__device__ __forceinline__ unsigned short f2bf(float x){
  unsigned int u = __float_as_uint(x);
  unsigned int r = (u + 0x7FFFu + ((u >> 16) & 1u)) >> 16;
  return (unsigned short)r;
}
__device__ __forceinline__ float bf2f(unsigned short h){
  return __uint_as_float(((unsigned int)h) << 16);
}

// async global->LDS 16B: per-lane global source, wave-uniform LDS base (+lane*16 in HW)
__device__ __forceinline__ void async16(const unsigned short* g, unsigned short* lds){
  __builtin_amdgcn_global_load_lds(
      (const __attribute__((address_space(1))) unsigned int*)g,
      (__attribute__((address_space(3))) unsigned int*)lds, 16, 0, 0);
}

// ---------------- block reduce helpers (blockDim.x == 256) ----------------
__device__ __forceinline__ float blk_sum(float v, float* red){
  int t = threadIdx.x;
  red[t] = v; __syncthreads();
  for (int s = 128; s > 0; s >>= 1){ if (t < s) red[t] += red[t+s]; __syncthreads(); }
  float r = red[0]; __syncthreads(); return r;
}
__device__ __forceinline__ float blk_max(float v, float* red){
  int t = threadIdx.x;
  red[t] = v; __syncthreads();
  for (int s = 128; s > 0; s >>= 1){ if (t < s) red[t] = fmaxf(red[t], red[t+s]); __syncthreads(); }
  float r = red[0]; __syncthreads(); return r;
}
__device__ __forceinline__ double blk_sumd(double v, double* red){
  int t = threadIdx.x;
  red[t] = v; __syncthreads();
  for (int s = 128; s > 0; s >>= 1){ if (t < s) red[t] += red[t+s]; __syncthreads(); }
  double r = red[0]; __syncthreads(); return r;
}

// ---------------- MFMA split-bf16 GEMM: C = act(A @ W^T + bias + res) ----------------
// BK=32, linear 32KB LDS, global_load_lds(16B) async staging (m97 pattern),
// XCD-aware bijective block swizzle. K % 32 == 0, N % 128 == 0.
__global__ __launch_bounds__(256) void gemm_mfma(
    const unsigned short* __restrict__ Ah, const unsigned short* __restrict__ Al,
    const unsigned short* __restrict__ Wh, const unsigned short* __restrict__ Wl,
    const float* __restrict__ bias, const float* __restrict__ res,
    float* __restrict__ C, int M, int N, int K, int act,
    unsigned short* __restrict__ outH, unsigned short* __restrict__ outL)
{
  __shared__ unsigned short AsH[4096], AsL[4096], BsH[4096], BsL[4096];  // [128][32] linear
  int t = threadIdx.x;
  int w = t >> 6, l = t & 63;
  int wr = w >> 1, wc = w & 1;
  // XCD-aware bijective swizzle of linear block id (contiguous chunk per XCD, m204)
  int nbx = gridDim.x;
  int nwg = nbx * gridDim.y;
  int bid = blockIdx.y * nbx + blockIdx.x;
  int q = nwg >> 3, rr = nwg & 7;
  int xcd = bid & 7, pos = bid >> 3;
  int sbid = ((xcd < rr) ? (xcd * (q + 1)) : (rr * (q + 1) + (xcd - rr) * q)) + pos;
  int bx = sbid % nbx, by = sbid / nbx;
  int rowBase = by * 128;
  int colBase = bx * 128;
  int row0 = rowBase + wr * 64;
  int col0 = colBase + wc * 64;
  int lr = l & 15;
  int lk = (l >> 4) << 3;
  f32x4 acc[4][4];
  #pragma unroll
  for (int i = 0; i < 4; ++i)
    #pragma unroll
    for (int j = 0; j < 4; ++j) acc[i][j] = (f32x4){0.f, 0.f, 0.f, 0.f};

  // per-wave staging roles: wave 0->AsH, 1->AsL, 2->BsH, 3->BsL
  const unsigned short* G;
  unsigned short* Lb;
  int gbase; int doClamp;
  if (w == 0)      { G = Ah; Lb = AsH; gbase = rowBase; doClamp = 1; }
  else if (w == 1) { G = Al; Lb = AsL; gbase = rowBase; doClamp = 1; }
  else if (w == 2) { G = Wh; Lb = BsH; gbase = colBase; doClamp = 0; }
  else             { G = Wl; Lb = BsL; gbase = colBase; doClamp = 0; }
  int rsub = l >> 2;           // 0..15
  int csub = (l & 3) << 3;     // ushort col {0,8,16,24}

  for (int ks = 0; ks < K; ks += 32) {
    // issue 8 x 1KB async copies per wave (16 rows each)
    #pragma unroll
    for (int s = 0; s < 8; ++s) {
      int r = s * 16 + rsub;
      int gr = gbase + r;
      if (doClamp) gr = (gr < M) ? gr : (M - 1);
      async16(G + (size_t)gr * K + ks + csub, Lb + s * 512);
    }
    __syncthreads();
    bf16x8 ah[4], al4[4], bh[4], bl4[4];
    #pragma unroll
    for (int i = 0; i < 4; ++i) {
      ah[i]  = *(const bf16x8*)&AsH[(wr*64 + i*16 + lr) * 32 + lk];
      al4[i] = *(const bf16x8*)&AsL[(wr*64 + i*16 + lr) * 32 + lk];
      bh[i]  = *(const bf16x8*)&BsH[(wc*64 + i*16 + lr) * 32 + lk];
      bl4[i] = *(const bf16x8*)&BsL[(wc*64 + i*16 + lr) * 32 + lk];
    }
    #pragma unroll
    for (int i = 0; i < 4; ++i)
      #pragma unroll
      for (int j = 0; j < 4; ++j) {
        acc[i][j] = __builtin_amdgcn_mfma_f32_16x16x32_bf16(ah[i],  bh[j],  acc[i][j], 0, 0, 0);
        acc[i][j] = __builtin_amdgcn_mfma_f32_16x16x32_bf16(ah[i],  bl4[j], acc[i][j], 0, 0, 0);
        acc[i][j] = __builtin_amdgcn_mfma_f32_16x16x32_bf16(al4[i], bh[j],  acc[i][j], 0, 0, 0);
      }
    __syncthreads();
  }
  int crb = (l >> 4) << 2;
  #pragma unroll
  for (int i = 0; i < 4; ++i)
    #pragma unroll
    for (int r = 0; r < 4; ++r) {
      int row = row0 + i * 16 + crb + r;
      if (row >= M) continue;
      #pragma unroll
      for (int j = 0; j < 4; ++j) {
        int col = col0 + j * 16 + lr;
        float v = acc[i][j][r];
        if (bias) v += bias[col];
        if (res)  v += res[(size_t)row * N + col];
        if (act == 1) v = fmaxf(v, 0.f);
        else if (act == 2) v = (v >= 0.f) ? v : 0.01f * v;
        size_t o = (size_t)row * N + col;
        C[o] = v;
        if (outH) {
          unsigned short hh = f2bf(v);
          outH[o] = hh;
          outL[o] = f2bf(v - bf2f(hh));
        }
      }
    }
}

// ---------------- batched(16) MFMA split-bf16 mm for the pinv chain ----------------
__global__ __launch_bounds__(64) void mm_mfma(
    const unsigned short* __restrict__ AH, const unsigned short* __restrict__ AL,
    const unsigned short* __restrict__ BTH, const unsigned short* __restrict__ BTL,
    unsigned short* __restrict__ CH, unsigned short* __restrict__ CL,
    unsigned short* __restrict__ CTH, unsigned short* __restrict__ CTL,
    unsigned short* __restrict__ DTH, unsigned short* __restrict__ DTL,
    float* __restrict__ C32,
    int N, float alpha, float diag, float diag2)
{
  int bh = blockIdx.z;
  size_t offA  = (size_t)bh * 65536;
  size_t offBT = (size_t)bh * N * 256;
  size_t offC  = (size_t)bh * 256 * N;
  size_t offT  = (size_t)bh * 65536;
  int l = threadIdx.x;
  int lr = l & 15, lk = (l >> 4) << 3;
  int row0 = blockIdx.y * 32, col0 = blockIdx.x * 32;
  f32x4 acc[2][2];
  #pragma unroll
  for (int i = 0; i < 2; ++i)
    #pragma unroll
    for (int j = 0; j < 2; ++j) acc[i][j] = (f32x4){0.f,0.f,0.f,0.f};

  bf16x8 A0h[2], A0l[2], B0h[2], B0l[2];
  bf16x8 A1h[2], A1l[2], B1h[2], B1l[2];

#define LDF2(AH_, AL_, BH_, BL_, KS) do {                              \
    _Pragma("unroll")                                                  \
    for (int i = 0; i < 2; ++i) {                                      \
      size_t ao = offA + (size_t)(row0 + i*16 + lr) * 256 + (KS) + lk; \
      AH_[i] = *(const bf16x8*)(AH + ao);                              \
      AL_[i] = *(const bf16x8*)(AL + ao);                              \
      size_t bo = offBT + (size_t)(col0 + i*16 + lr) * 256 + (KS) + lk;\
      BH_[i] = *(const bf16x8*)(BTH + bo);                             \
      BL_[i] = *(const bf16x8*)(BTL + bo);                             \
    } } while (0)

#define DOMFMA2(AH_, AL_, BH_, BL_) do {                               \
    _Pragma("unroll")                                                  \
    for (int i = 0; i < 2; ++i)                                        \
      _Pragma("unroll")                                                \
      for (int j = 0; j < 2; ++j) {                                    \
        acc[i][j] = __builtin_amdgcn_mfma_f32_16x16x32_bf16(AH_[i], BH_[j], acc[i][j], 0,0,0); \
        acc[i][j] = __builtin_amdgcn_mfma_f32_16x16x32_bf16(AH_[i], BL_[j], acc[i][j], 0,0,0); \
        acc[i][j] = __builtin_amdgcn_mfma_f32_16x16x32_bf16(AL_[i], BH_[j], acc[i][j], 0,0,0); \
      } } while (0)

  LDF2(A0h, A0l, B0h, B0l, 0);
  for (int ks = 0; ks < 256; ks += 64) {
    LDF2(A1h, A1l, B1h, B1l, ks + 32);
    DOMFMA2(A0h, A0l, B0h, B0l);
    if (ks + 64 < 256) LDF2(A0h, A0l, B0h, B0l, ks + 64);
    DOMFMA2(A1h, A1l, B1h, B1l);
  }
#undef LDF2
#undef DOMFMA2

  int crb = (l >> 4) << 2;
  #pragma unroll
  for (int i = 0; i < 2; ++i) {
    int rbase = row0 + i*16 + crb;
    #pragma unroll
    for (int j = 0; j < 2; ++j) {
      int colg = col0 + j*16 + lr;
      float v[4];
      #pragma unroll
      for (int r = 0; r < 4; ++r)
        v[r] = alpha * acc[i][j][r] + (((rbase + r) == colg) ? diag : 0.f);
      if (C32) {
        #pragma unroll
        for (int r = 0; r < 4; ++r) C32[offC + (size_t)(rbase + r) * N + colg] = v[r];
      }
      if (CH) {
        #pragma unroll
        for (int r = 0; r < 4; ++r) {
          unsigned short hh = f2bf(v[r]);
          CH[offC + (size_t)(rbase + r) * N + colg] = hh;
          CL[offC + (size_t)(rbase + r) * N + colg] = f2bf(v[r] - bf2f(hh));
        }
      }
      if (CTH) {
        ushort4 th, tl;
        unsigned short* ph = (unsigned short*)&th;
        unsigned short* pl = (unsigned short*)&tl;
        #pragma unroll
        for (int r = 0; r < 4; ++r) { ph[r] = f2bf(v[r]); pl[r] = f2bf(v[r] - bf2f(ph[r])); }
        *(ushort4*)&CTH[offT + (size_t)colg * 256 + rbase] = th;
        *(ushort4*)&CTL[offT + (size_t)colg * 256 + rbase] = tl;
      }
      if (DTH) {
        ushort4 th, tl;
        unsigned short* ph = (unsigned short*)&th;
        unsigned short* pl = (unsigned short*)&tl;
        #pragma unroll
        for (int r = 0; r < 4; ++r) {
          float dv = (((rbase + r) == colg) ? diag2 : 0.f) - v[r];
          ph[r] = f2bf(dv); pl[r] = f2bf(dv - bf2f(ph[r]));
        }
        *(ushort4*)&DTH[offT + (size_t)colg * 256 + rbase] = th;
        *(ushort4*)&DTL[offT + (size_t)colg * 256 + rbase] = tl;
      }
    }
  }
}

// elementwise split fp32 -> (hi, lo) bf16; n4 = count/4
__global__ void split_k(const float* __restrict__ src, unsigned short* __restrict__ dh,
                        unsigned short* __restrict__ dl, int n4){
  int i = blockIdx.x * 256 + threadIdx.x;
  if (i >= n4) return;
  float4 v = ((const float4*)src)[i];
  ushort4 H, L;
  H.x = f2bf(v.x); L.x = f2bf(v.x - bf2f(H.x));
  H.y = f2bf(v.y); L.y = f2bf(v.y - bf2f(H.y));
  H.z = f2bf(v.z); L.z = f2bf(v.z - bf2f(H.z));
  H.w = f2bf(v.w); L.w = f2bf(v.w - bf2f(H.w));
  ((ushort4*)dh)[i] = H;
  ((ushort4*)dl)[i] = L;
}

// split K columns of qkv (cols 512..1024) into compact [row][512] hi/lo; grid 4352
__global__ void split_kcols(const float* __restrict__ qkv,
                            unsigned short* __restrict__ dh, unsigned short* __restrict__ dl){
  size_t idx = (size_t)blockIdx.x * 256 + threadIdx.x;   // BB*NPAD*128 total
  size_t row = idx >> 7;
  int c4 = (int)(idx & 127) << 2;
  float4 v = *(const float4*)&qkv[row * NT + 512 + c4];
  ushort4 H, L;
  H.x = f2bf(v.x); L.x = f2bf(v.x - bf2f(H.x));
  H.y = f2bf(v.y); L.y = f2bf(v.y - bf2f(H.y));
  H.z = f2bf(v.z); L.z = f2bf(v.z - bf2f(H.z));
  H.w = f2bf(v.w); L.w = f2bf(v.w - bf2f(H.w));
  *(ushort4*)&dh[row * 512 + c4] = H;
  *(ushort4*)&dl[row * 512 + c4] = L;
}

// transpose-split V: VT[bh][d][n] hi/lo; grid (NPAD/64, 16)
__global__ __launch_bounds__(256) void transpose_split_v(const float* __restrict__ qkv,
    unsigned short* __restrict__ VTH, unsigned short* __restrict__ VTL){
  __shared__ float tile[64][65];
  int bh = blockIdx.y;
  int n0 = blockIdx.x * 64;
  int b = bh >> 3, hh = bh & 7;
  int t = threadIdx.x;
  for (int i = t; i < 4096; i += 256) {
    int r = i >> 6, c = i & 63;
    tile[r][c] = qkv[((size_t)b * NPAD + n0 + r) * NT + 1024 + hh * 64 + c];
  }
  __syncthreads();
  for (int i = t; i < 4096; i += 256) {
    int d = i >> 6, n = i & 63;
    float v = tile[n][d];
    unsigned short hv = f2bf(v);
    size_t o = ((size_t)bh * 64 + d) * NPAD + n0 + n;
    VTH[o] = hv; VTL[o] = f2bf(v - bf2f(hv));
  }
}

// z0 = a2^T * s : write z (normal, hi/lo) and zT (hi/lo).
__global__ void z0_split(const float* __restrict__ a2, const float* __restrict__ scal,
                         unsigned short* __restrict__ zH, unsigned short* __restrict__ zL,
                         unsigned short* __restrict__ zTH, unsigned short* __restrict__ zTL){
  size_t idx = (size_t)blockIdx.x * 256 + threadIdx.x;   // grid 4096
  size_t bh = idx >> 16;
  int rc = (int)(idx & 65535);
  int r = rc >> 8, c = rc & 255;
  float v = a2[idx] * scal[32];
  unsigned short hh = f2bf(v), ll = f2bf(v - bf2f(hh));
  zTH[idx] = hh; zTL[idx] = ll;
  size_t tidx = (bh << 16) + (size_t)c * 256 + r;
  zH[tidx] = hh; zL[tidx] = ll;
}

// src (bh,256,64) fp32 -> dst (bh,64,256) hi/lo  (used for av and zav)
__global__ void split_T_av(const float* __restrict__ av,
                           unsigned short* __restrict__ TH, unsigned short* __restrict__ TL){
  size_t idx = (size_t)blockIdx.x * 256 + threadIdx.x;   // grid 1024 (16*16384)
  size_t bh = idx >> 14;
  int md = (int)(idx & 16383);
  int m = md >> 6, d = md & 63;
  float v = av[idx];
  unsigned short hh = f2bf(v);
  size_t tix = (bh << 14) + (size_t)d * 256 + m;
  TH[tix] = hh; TL[tix] = f2bf(v - bf2f(hh));
}

// ---------------- LN + front zero-pad, emitting split-bf16 halves ----------------
__global__ __launch_bounds__(256) void ln_pad_split(const float* __restrict__ hsrc,
    unsigned short* __restrict__ dH, unsigned short* __restrict__ dL,
    const float* __restrict__ g, const float* __restrict__ bt){
  __shared__ double red[256];
  int row = blockIdx.x;
  int b = row / NPAD, r = row % NPAD;
  unsigned short* rh = dH + (size_t)row * DIM;
  unsigned short* rl = dL + (size_t)row * DIM;
  int t = threadIdx.x;
  if (r < PADR) { rh[t] = 0; rh[t+256] = 0; rl[t] = 0; rl[t+256] = 0; return; }
  const float* x = hsrc + ((size_t)b * N1 + (r - PADR)) * DIM;
  double x0 = (double)x[t], x1 = (double)x[t + 256];
  double mu = blk_sumd(x0 + x1, red) * (1.0/512.0);
  double d0 = x0 - mu, d1 = x1 - mu;
  double var = blk_sumd(d0*d0 + d1*d1, red) * (1.0/512.0);
  double inv = 1.0 / sqrt(var + 1e-5);
  float y0 = (float)(d0 * inv * (double)g[t]       + (double)bt[t]);
  float y1 = (float)(d1 * inv * (double)g[t + 256] + (double)bt[t + 256]);
  unsigned short h0 = f2bf(y0), h1 = f2bf(y1);
  rh[t] = h0;       rl[t] = f2bf(y0 - bf2f(h0));
  rh[t + 256] = h1; rl[t + 256] = f2bf(y1 - bf2f(h1));
}

// ---------------- landmarks: ql (scaled by 1/8), kl ----------------
__global__ void landmark(const float* __restrict__ qkv, float* __restrict__ ql, float* __restrict__ kl){
  int blk = blockIdx.x;            // bh*256 + m
  int bh = blk >> 8, m = blk & 255;
  int b = bh >> 3, hh = bh & 7;
  int d = threadIdx.x;             // 64
  float sq = 0.f, sk = 0.f;
  for (int l = 0; l < 17; ++l) {
    size_t o = ((size_t)b * NPAD + m * 17 + l) * NT + hh * 64 + d;
    sq += qkv[o];
    sk += qkv[o + 512];
  }
  ql[((size_t)bh * 256 + m) * 64 + d] = 0.125f * sq / 17.f;
  kl[((size_t)bh * 256 + m) * 64 + d] = sk / 17.f;
}

// klT[bh][d][m] = kl[bh][m][d]; grid (LM/64, 16)
__global__ __launch_bounds__(256) void transpose_kl(const float* __restrict__ kl, float* __restrict__ klT){
  __shared__ float tile[64][65];
  int bh = blockIdx.y;
  int m0 = blockIdx.x * 64;
  int t = threadIdx.x;
  for (int i = t; i < 4096; i += 256) {
    int r = i >> 6, c = i & 63;
    tile[r][c] = kl[((size_t)bh * 256 + m0 + r) * 64 + c];
  }
  __syncthreads();
  float* kb = klT + (size_t)bh * 64 * 256;
  for (int i = t; i < 4096; i += 256) {
    int d = i >> 6, mm = i & 63;
    kb[(size_t)d * 256 + m0 + mm] = tile[mm][d];
  }
}

// ---------------- a2 = softmax(ql @ kl^T) ----------------
__global__ __launch_bounds__(256) void a2_kernel(const float* __restrict__ ql, const float* __restrict__ klT,
                                                 float* __restrict__ a2){
  __shared__ float qs[64]; __shared__ float red[256];
  int blk = blockIdx.x;            // bh*256 + i
  int bh = blk >> 8, i = blk & 255;
  int t = threadIdx.x;
  if (t < 64) qs[t] = ql[((size_t)bh * 256 + i) * 64 + t];
  __syncthreads();
  const float* kb = klT + (size_t)bh * 16384;
  float s = 0.f;
  #pragma unroll
  for (int d = 0; d < 64; ++d) s += qs[d] * kb[d * 256 + t];
  float mx = blk_max(s, red);
  float e = expf(s - mx);
  float sum = blk_sum(e, red);
  a2[((size_t)bh * 256 + i) * 256 + t] = e / sum;
}

// per-(b,h) max colsum / rowsum
__global__ __launch_bounds__(256) void colrow_max(const float* __restrict__ a2, float* __restrict__ scal){
  __shared__ float red[256];
  int bh = blockIdx.x, t = threadIdx.x;
  const float* A = a2 + (size_t)bh * 65536;
  float cs = 0.f, rs = 0.f;
  for (int i = 0; i < 256; ++i) cs += A[(size_t)i * 256 + t];
  for (int j = 0; j < 256; ++j) rs += A[(size_t)t * 256 + j];
  float cmax = blk_max(cs, red);
  float rmax = blk_max(rs, red);
  if (t == 0) { scal[bh] = cmax; scal[16 + bh] = rmax; }
}
__global__ void scal_red(float* scal){
  if (threadIdx.x == 0) {
    float cm = scal[0], rm = scal[16];
    for (int i = 1; i < 16; ++i) { cm = fmaxf(cm, scal[i]); rm = fmaxf(rm, scal[16 + i]); }
    scal[32] = 1.f / (rm * cm);
  }
}

// ================= flash-attention tiles (split-bf16 MFMA matmuls, fp32 online softmax) =================
// fa3v: Q=ql (64 rows/block), K from KsH/KsL [row][512], V^T from VTH/VTL [bh][64][NPAD].
// grid (17, 4, 16)
__global__ __launch_bounds__(256) void fa3v_kernel(const unsigned short* __restrict__ KsH,
                                                   const unsigned short* __restrict__ KsL,
                                                   const unsigned short* __restrict__ VTH,
                                                   const unsigned short* __restrict__ VTL,
                                                   const float* __restrict__ ql,
                                                   float* __restrict__ accp, float* __restrict__ mlp){
  int part = blockIdx.x, qt = blockIdx.y, bh = blockIdx.z;
  int b = bh >> 3, hh = bh & 7;
  int t = threadIdx.x;
  int w = t >> 6, l = t & 63;
  int lr = l & 15, lk = (l >> 4) << 3;
  int w16 = w * 16;
  int crb = (l >> 4) << 2;
  __shared__ unsigned short KH[64][72], KL[64][72];   // K [krow][d]; later V^T [d][krow]
  __shared__ unsigned short PH[64][72], PL[64][72];   // P [qrow][krow]
  __shared__ float Ss[64][68];
  __shared__ float redm[64][4];
  __shared__ float mrow[64], lrow[64], scales[64];
  bf16x8 qh[2], qlo[2];
  {
    const float* qrow = ql + ((size_t)bh * 256 + qt * 64 + w16 + lr) * 64;
    #pragma unroll
    for (int s = 0; s < 2; ++s) {
      #pragma unroll
      for (int e = 0; e < 8; ++e) {
        float v = qrow[s * 32 + lk + e];
        unsigned short hv = f2bf(v);
        qh[s][e]  = (short)hv;
        qlo[s][e] = (short)f2bf(v - bf2f(hv));
      }
    }
  }
  if (t < 64) { mrow[t] = -3.4e38f; lrow[t] = 0.f; }
  f32x4 acc[4];
  #pragma unroll
  for (int j = 0; j < 4; ++j) acc[j] = (f32x4){0.f,0.f,0.f,0.f};
  __syncthreads();
  int rr = t >> 2, sg = (t & 3) << 4;
  for (int tile = 0; tile < 4; ++tile) {
    int nbase = part * 256 + tile * 64;
    // stage K (pure ushort8 copies)
    {
      const unsigned short* kbH = KsH + ((size_t)b * NPAD + nbase) * 512 + hh * 64;
      const unsigned short* kbL = KsL + ((size_t)b * NPAD + nbase) * 512 + hh * 64;
      #pragma unroll
      for (int u = 0; u < 2; ++u) {
        int i = t + u * 256;
        int r = i >> 3, c8 = (i & 7) << 3;
        *(bf16x8*)&KH[r][c8] = *(const bf16x8*)(kbH + (size_t)r * 512 + c8);
        *(bf16x8*)&KL[r][c8] = *(const bf16x8*)(kbL + (size_t)r * 512 + c8);
      }
    }
    __syncthreads();
    #pragma unroll
    for (int j = 0; j < 4; ++j) {
      f32x4 sf = (f32x4){0.f,0.f,0.f,0.f};
      #pragma unroll
      for (int s = 0; s < 2; ++s) {
        bf16x8 kh8 = *(const bf16x8*)&KH[j*16 + lr][s*32 + lk];
        bf16x8 kl8 = *(const bf16x8*)&KL[j*16 + lr][s*32 + lk];
        sf = __builtin_amdgcn_mfma_f32_16x16x32_bf16(qh[s],  kh8, sf, 0,0,0);
        sf = __builtin_amdgcn_mfma_f32_16x16x32_bf16(qh[s],  kl8, sf, 0,0,0);
        sf = __builtin_amdgcn_mfma_f32_16x16x32_bf16(qlo[s], kh8, sf, 0,0,0);
      }
      #pragma unroll
      for (int r = 0; r < 4; ++r) Ss[w16 + crb + r][j*16 + lr] = sf[r];
    }
    __syncthreads();   // S complete; K reads done
    // stage V^T (row-contiguous copies)
    {
      const unsigned short* vbH = VTH + (size_t)bh * 64 * NPAD + nbase;
      const unsigned short* vbL = VTL + (size_t)bh * 64 * NPAD + nbase;
      #pragma unroll
      for (int u = 0; u < 2; ++u) {
        int i = t + u * 256;
        int d = i >> 3, c8 = (i & 7) << 3;
        *(bf16x8*)&KH[d][c8] = *(const bf16x8*)(vbH + (size_t)d * NPAD + c8);
        *(bf16x8*)&KL[d][c8] = *(const bf16x8*)(vbL + (size_t)d * NPAD + c8);
      }
    }
    float lm = -3.4e38f;
    #pragma unroll
    for (int c = 0; c < 16; ++c) lm = fmaxf(lm, Ss[rr][sg + c]);
    redm[rr][t & 3] = lm;
    float mold = mrow[rr];
    float rm = fmaxf(fmaxf(redm[rr][0], redm[rr][1]), fmaxf(redm[rr][2], redm[rr][3]));
    float mnew = fmaxf(mold, rm);
    float sc_r = expf(mold - mnew);
    if ((t & 3) == 0) { scales[rr] = sc_r; mrow[rr] = mnew; }
    float ls = 0.f;
    #pragma unroll
    for (int c = 0; c < 16; ++c) {
      float p = expf(Ss[rr][sg + c] - mnew);
      unsigned short hv = f2bf(p);
      PH[rr][sg + c] = hv; PL[rr][sg + c] = f2bf(p - bf2f(hv));
      ls += p;
    }
    redm[rr][t & 3] = ls;
    __syncthreads();   // V^T staged, P split, scales ready
    if ((t & 3) == 0) lrow[rr] = lrow[rr] * sc_r + redm[rr][0]+redm[rr][1]+redm[rr][2]+redm[rr][3];
    {
      float s0 = scales[w16 + crb], s1 = scales[w16 + crb + 1],
            s2 = scales[w16 + crb + 2], s3 = scales[w16 + crb + 3];
      #pragma unroll
      for (int j = 0; j < 4; ++j) { acc[j][0]*=s0; acc[j][1]*=s1; acc[j][2]*=s2; acc[j][3]*=s3; }
    }
    bf16x8 pah[2], pal[2];
    #pragma unroll
    for (int s = 0; s < 2; ++s) {
      pah[s] = *(const bf16x8*)&PH[w16 + lr][s*32 + lk];
      pal[s] = *(const bf16x8*)&PL[w16 + lr][s*32 + lk];
    }
    #pragma unroll
    for (int j = 0; j < 4; ++j) {
      #pragma unroll
      for (int s = 0; s < 2; ++s) {
        bf16x8 vh = *(const bf16x8*)&KH[j*16 + lr][s*32 + lk];
        bf16x8 vl = *(const bf16x8*)&KL[j*16 + lr][s*32 + lk];
        acc[j] = __builtin_amdgcn_mfma_f32_16x16x32_bf16(pah[s], vh, acc[j], 0,0,0);
        acc[j] = __builtin_amdgcn_mfma_f32_16x16x32_bf16(pah[s], vl, acc[j], 0,0,0);
        acc[j] = __builtin_amdgcn_mfma_f32_16x16x32_bf16(pal[s], vh, acc[j], 0,0,0);
      }
    }
    __syncthreads();   // before next tile overwrites KH/PH
  }
  int blk = (bh * 4 + qt) * 17 + part;
  float* ap = accp + (size_t)blk * 4096;
  #pragma unroll
  for (int j = 0; j < 4; ++j)
    #pragma unroll
    for (int r = 0; r < 4; ++r)
      ap[(w16 + crb + r) * 64 + j*16 + lr] = acc[j][r];
  if (t < 64) { mlp[(size_t)blk*128 + t] = mrow[t]; mlp[(size_t)blk*128 + 64 + t] = lrow[t]; }
}

// combine 17 partials -> av ; grid 64 = bh*4+qt
__global__ __launch_bounds__(256) void fa3v_combine(const float* __restrict__ accp, const float* __restrict__ mlp,
                                                    float* __restrict__ av){
  int g = blockIdx.x;
  int t = threadIdx.x;
  int r = t >> 2, sg = (t & 3) << 4;
  int bh = g >> 2, qt = g & 3;
  float mp[17], lp[17];
  #pragma unroll
  for (int p = 0; p < 17; ++p) {
    mp[p] = mlp[(size_t)(g*17+p)*128 + r];
    lp[p] = mlp[(size_t)(g*17+p)*128 + 64 + r];
  }
  float M = mp[0];
  #pragma unroll
  for (int p = 1; p < 17; ++p) M = fmaxf(M, mp[p]);
  float w[17]; float L = 0.f;
  #pragma unroll
  for (int p = 0; p < 17; ++p) { w[p] = expf(mp[p] - M); L += w[p] * lp[p]; }
  float invL = 1.f / L;
  #pragma unroll
  for (int c = 0; c < 16; ++c) {
    float s = 0.f;
    #pragma unroll
    for (int p = 0; p < 17; ++p) s += w[p] * accp[(size_t)(g*17+p)*4096 + r*64 + sg + c];
    av[((size_t)(bh*256 + qt*64 + r))*64 + sg + c] = s * invL;
  }
}

// fa1: Q = qkv.q*0.125; K from klsH/L [bh*256+m][64]; V^T from zavTH/L [bh][64][256].
// merged += P@V/l; also emits merged splits. grid (68, 16)
__global__ __launch_bounds__(256) void fa1_kernel(const float* __restrict__ qkv,
                                                  const unsigned short* __restrict__ klsH,
                                                  const unsigned short* __restrict__ klsL,
                                                  const unsigned short* __restrict__ zavTH,
                                                  const unsigned short* __restrict__ zavTL,
                                                  float* __restrict__ merged,
                                                  unsigned short* __restrict__ merH,
                                                  unsigned short* __restrict__ merL){
  int nt = blockIdx.x, bh = blockIdx.y;
  int b = bh >> 3, hh = bh & 7;
  int t = threadIdx.x;
  int w = t >> 6, l = t & 63;
  int lr = l & 15, lk = (l >> 4) << 3;
  int w16 = w * 16;
  int crb = (l >> 4) << 2;
  int n0 = nt * 64;
  __shared__ unsigned short KH[64][72], KL[64][72];
  __shared__ unsigned short PH[64][72], PL[64][72];
  __shared__ float Ss[64][68];
  __shared__ float redm[64][4];
  __shared__ float mrow[64], lrow[64], scales[64];
  bf16x8 qh[2], qlo[2];
  {
    const float* qrow = qkv + ((size_t)b * NPAD + n0 + w16 + lr) * NT + hh * 64;
    #pragma unroll
    for (int s = 0; s < 2; ++s) {
      #pragma unroll
      for (int e = 0; e < 8; ++e) {
        float v = 0.125f * qrow[s * 32 + lk + e];
        unsigned short hv = f2bf(v);
        qh[s][e]  = (short)hv;
        qlo[s][e] = (short)f2bf(v - bf2f(hv));
      }
    }
  }
  if (t < 64) { mrow[t] = -3.4e38f; lrow[t] = 0.f; }
  f32x4 acc[4];
  #pragma unroll
  for (int j = 0; j < 4; ++j) acc[j] = (f32x4){0.f,0.f,0.f,0.f};
  __syncthreads();
  int rr = t >> 2, sg = (t & 3) << 4;
  for (int tile = 0; tile < 4; ++tile) {
    int mbase = tile * 64;
    {
      const unsigned short* kbH = klsH + ((size_t)bh * 256 + mbase) * 64;
      const unsigned short* kbL = klsL + ((size_t)bh * 256 + mbase) * 64;
      #pragma unroll
      for (int u = 0; u < 2; ++u) {
        int i = t + u * 256;
        int r = i >> 3, c8 = (i & 7) << 3;
        *(bf16x8*)&KH[r][c8] = *(const bf16x8*)(kbH + (size_t)r * 64 + c8);
        *(bf16x8*)&KL[r][c8] = *(const bf16x8*)(kbL + (size_t)r * 64 + c8);
      }
    }
    __syncthreads();
    #pragma unroll
    for (int j = 0; j < 4; ++j) {
      f32x4 sf = (f32x4){0.f,0.f,0.f,0.f};
      #pragma unroll
      for (int s = 0; s < 2; ++s) {
        bf16x8 kh8 = *(const bf16x8*)&KH[j*16 + lr][s*32 + lk];
        bf16x8 kl8 = *(const bf16x8*)&KL[j*16 + lr][s*32 + lk];
        sf = __builtin_amdgcn_mfma_f32_16x16x32_bf16(qh[s],  kh8, sf, 0,0,0);
        sf = __builtin_amdgcn_mfma_f32_16x16x32_bf16(qh[s],  kl8, sf, 0,0,0);
        sf = __builtin_amdgcn_mfma_f32_16x16x32_bf16(qlo[s], kh8, sf, 0,0,0);
      }
      #pragma unroll
      for (int r = 0; r < 4; ++r) Ss[w16 + crb + r][j*16 + lr] = sf[r];
    }
    __syncthreads();
    {
      const unsigned short* vbH = zavTH + (size_t)bh * 64 * 256 + mbase;
      const unsigned short* vbL = zavTL + (size_t)bh * 64 * 256 + mbase;
      #pragma unroll
      for (int u = 0; u < 2; ++u) {
        int i = t + u * 256;
        int d = i >> 3, c8 = (i & 7) << 3;
        *(bf16x8*)&KH[d][c8] = *(const bf16x8*)(vbH + (size_t)d * 256 + c8);
        *(bf16x8*)&KL[d][c8] = *(const bf16x8*)(vbL + (size_t)d * 256 + c8);
      }
    }
    float lm = -3.4e38f;
    #pragma unroll
    for (int c = 0; c < 16; ++c) lm = fmaxf(lm, Ss[rr][sg + c]);
    redm[rr][t & 3] = lm;
    float mold = mrow[rr];
    float rm = fmaxf(fmaxf(redm[rr][0], redm[rr][1]), fmaxf(redm[rr][2], redm[rr][3]));
    float mnew = fmaxf(mold, rm);
    float sc_r = expf(mold - mnew);
    if ((t & 3) == 0) { scales[rr] = sc_r; mrow[rr] = mnew; }
    float ls = 0.f;
    #pragma unroll
    for (int c = 0; c < 16; ++c) {
      float p = expf(Ss[rr][sg + c] - mnew);
      unsigned short hv = f2bf(p);
      PH[rr][sg + c] = hv; PL[rr][sg + c] = f2bf(p - bf2f(hv));
      ls += p;
    }
    redm[rr][t & 3] = ls;
    __syncthreads();
    if ((t & 3) == 0) lrow[rr] = lrow[rr] * sc_r + redm[rr][0]+redm[rr][1]+redm[rr][2]+redm[rr][3];
    {
      float s0 = scales[w16 + crb], s1 = scales[w16 + crb + 1],
            s2 = scales[w16 + crb + 2], s3 = scales[w16 + crb + 3];
      #pragma unroll
      for (int j = 0; j < 4; ++j) { acc[j][0]*=s0; acc[j][1]*=s1; acc[j][2]*=s2; acc[j][3]*=s3; }
    }
    bf16x8 pah[2], pal[2];
    #pragma unroll
    for (int s = 0; s < 2; ++s) {
      pah[s] = *(const bf16x8*)&PH[w16 + lr][s*32 + lk];
      pal[s] = *(const bf16x8*)&PL[w16 + lr][s*32 + lk];
    }
    #pragma unroll
    for (int j = 0; j < 4; ++j) {
      #pragma unroll
      for (int s = 0; s < 2; ++s) {
        bf16x8 vh = *(const bf16x8*)&KH[j*16 + lr][s*32 + lk];
        bf16x8 vl = *(const bf16x8*)&KL[j*16 + lr][s*32 + lk];
        acc[j] = __builtin_amdgcn_mfma_f32_16x16x32_bf16(pah[s], vh, acc[j], 0,0,0);
        acc[j] = __builtin_amdgcn_mfma_f32_16x16x32_bf16(pah[s], vl, acc[j], 0,0,0);
        acc[j] = __builtin_amdgcn_mfma_f32_16x16x32_bf16(pal[s], vh, acc[j], 0,0,0);
      }
    }
    __syncthreads();
  }
  #pragma unroll
  for (int r = 0; r < 4; ++r) {
    float invl = 1.f / lrow[w16 + crb + r];
    size_t rowoff = ((size_t)b * NPAD + n0 + w16 + crb + r) * DIM + hh * 64;
    float* mp = &merged[rowoff];
    #pragma unroll
    for (int j = 0; j < 4; ++j) {
      float v = mp[j*16 + lr] + acc[j][r] * invl;
      mp[j*16 + lr] = v;
      unsigned short hv = f2bf(v);
      merH[rowoff + j*16 + lr] = hv;
      merL[rowoff + j*16 + lr] = f2bf(v - bf2f(hv));
    }
  }
}

// ---------------- depthwise 33x1 residual conv on v -> merged (LDS strip tiled) ----------------
__global__ __launch_bounds__(256) void conv_res(const float* __restrict__ qkv, const float* __restrict__ rk,
                                                float* __restrict__ merged){
  __shared__ float vt[288][16];
  __shared__ float rks[33];
  int n0 = blockIdx.x * 256;
  int c0 = blockIdx.y * 16;
  int b  = blockIdx.z;
  int t = threadIdx.x;
  int hh = c0 >> 6;
  if (t < 33) rks[t] = rk[hh * 33 + t];
  for (int i = t; i < 288 * 4; i += 256) {
    int sp = i >> 2, q = (i & 3) << 2;
    int n = n0 - 16 + sp;
    float4 v = make_float4(0.f,0.f,0.f,0.f);
    if (n >= 0 && n < NPAD)
      v = *(const float4*)&qkv[((size_t)b * NPAD + n) * NT + 1024 + c0 + q];
    vt[sp][q] = v.x; vt[sp][q+1] = v.y; vt[sp][q+2] = v.z; vt[sp][q+3] = v.w;
  }
  __syncthreads();
  int c = t & 15, g = t >> 4;
  for (int m = 0; m < 16; ++m) {
    int nl = g + m * 16;
    float acc = 0.f;
    #pragma unroll
    for (int kk = 0; kk < 33; ++kk) acc += rks[kk] * vt[nl + kk][c];
    merged[((size_t)b * NPAD + n0 + nl) * DIM + c0 + c] = acc;
  }
}

// ---------------- PPEG depthwise convs (LDS tiled) ----------------
__global__ __launch_bounds__(256) void dwconv(const float* __restrict__ hsrc,
    const float* __restrict__ w7, const float* __restrict__ b7,
    const float* __restrict__ w5, const float* __restrict__ b5,
    const float* __restrict__ w3, const float* __restrict__ b3,
    float* __restrict__ hdst){
  __shared__ float tile[484][16];
  __shared__ float wS7[49][16], wS5[25][16], wS3[9][16];
  int st = blockIdx.x;
  int y0 = (st >> 2) * 16, x0 = (st & 3) * 16;
  int c0 = blockIdx.y * 16;
  int b  = blockIdx.z;
  int t = threadIdx.x;
  const float* fb = hsrc + ((size_t)b * N1 + 1) * DIM;
  for (int i = t; i < 49 * 16; i += 256) { int k = i >> 4, c = i & 15; wS7[k][c] = w7[(size_t)(c0 + c) * 49 + k]; }
  for (int i = t; i < 25 * 16; i += 256) { int k = i >> 4, c = i & 15; wS5[k][c] = w5[(size_t)(c0 + c) * 25 + k]; }
  for (int i = t; i <  9 * 16; i += 256) { int k = i >> 4, c = i & 15; wS3[k][c] = w3[(size_t)(c0 + c) * 9 + k]; }
  for (int i = t; i < 484 * 4; i += 256) {
    int sp = i >> 2, q = (i & 3) << 2;
    int yy = y0 - 3 + sp / 22, xx = x0 - 3 + sp % 22;
    float4 v = make_float4(0.f,0.f,0.f,0.f);
    if (yy >= 0 && yy < 64 && xx >= 0 && xx < 64)
      v = *(const float4*)&fb[(size_t)(yy * 64 + xx) * DIM + c0 + q];
    tile[sp][q] = v.x; tile[sp][q+1] = v.y; tile[sp][q+2] = v.z; tile[sp][q+3] = v.w;
  }
  __syncthreads();
  int c = t & 15, g = t >> 4;
  float bsum = b7[c0 + c] + b5[c0 + c] + b3[c0 + c];
  for (int m = 0; m < 16; ++m) {
    int p = g + m * 16;
    int y = p >> 4, x = p & 15;
    float acc = tile[(y + 3) * 22 + (x + 3)][c] + bsum;
    #pragma unroll
    for (int ky = 0; ky < 7; ++ky)
      #pragma unroll
      for (int kx = 0; kx < 7; ++kx)
        acc += wS7[ky * 7 + kx][c] * tile[(y + ky) * 22 + (x + kx)][c];
    #pragma unroll
    for (int ky = 0; ky < 5; ++ky)
      #pragma unroll
      for (int kx = 0; kx < 5; ++kx)
        acc += wS5[ky * 5 + kx][c] * tile[(y + 1 + ky) * 22 + (x + 1 + kx)][c];
    #pragma unroll
    for (int ky = 0; ky < 3; ++ky)
      #pragma unroll
      for (int kx = 0; kx < 3; ++kx)
        acc += wS3[ky * 3 + kx][c] * tile[(y + 2 + ky) * 22 + (x + 2 + kx)][c];
    int spg = (y0 + y) * 64 + (x0 + x);
    hdst[((size_t)b * N1 + 1 + spg) * DIM + c0 + c] = acc;
  }
}

__global__ void set_cls(float* h, const float* cls){
  int t = threadIdx.x;
  if (t < 1024) { int b = t >> 9, c = t & 511; h[(size_t)b * N1 * DIM + c] = cls[c]; }
}
__global__ void copy_cls(float* dst, const float* src){
  int t = threadIdx.x;
  if (t < 1024) { int b = t >> 9, c = t & 511; dst[(size_t)b * N1 * DIM + c] = src[(size_t)b * N1 * DIM + c]; }
}

__global__ __launch_bounds__(256) void final_ln(const float* __restrict__ h2, const float* __restrict__ g,
                                                const float* __restrict__ bt, float* __restrict__ hcls){
  __shared__ double red[256];
  int b = blockIdx.x, t = threadIdx.x;
  const float* x = h2 + (size_t)b * N1 * DIM;
  double x0 = (double)x[t], x1 = (double)x[t + 256];
  double mu = blk_sumd(x0 + x1, red) * (1.0/512.0);
  double d0 = x0 - mu, d1 = x1 - mu;
  double var = blk_sumd(d0*d0 + d1*d1, red) * (1.0/512.0);
  double inv = 1.0 / sqrt(var + 1e-5);
  hcls[b * 512 + t]       = (float)(d0 * inv * (double)g[t]       + (double)bt[t]);
  hcls[b * 512 + t + 256] = (float)(d1 * inv * (double)g[t + 256] + (double)bt[t + 256]);
}

// xc rows (split-bf16 only; feeds dsl1 MFMA gemm)
__global__ void build_xc_split(const float* __restrict__ hcls, const float* __restrict__ reh,
                               unsigned short* __restrict__ xcH, unsigned short* __restrict__ xcL){
  size_t idx = (size_t)blockIdx.x * 256 + threadIdx.x;
  int row = (int)(idx >> 9), c = (int)(idx & 511);
  float v = (row < 2) ? hcls[row * 512 + c] : reh[(size_t)(row - 2) * 512 + c];
  unsigned short hh = f2bf(v);
  xcH[idx] = hh; xcL[idx] = f2bf(v - bf2f(hh));
}

__global__ __launch_bounds__(256) void norms_k(const float* __restrict__ xg, double* __restrict__ rn){
  __shared__ double red[256];
  int i = blockIdx.x, t = threadIdx.x;
  double a = (double)xg[(size_t)i * 512 + t], b = (double)xg[(size_t)i * 512 + t + 256];
  double s = blk_sumd(a*a + b*b, red);
  if (t == 0) rn[i] = sqrt(s);
}

__global__ __launch_bounds__(256) void topk_k(const float* __restrict__ xg, const double* __restrict__ rn,
                                              int* __restrict__ idxb){
  __shared__ double sc[256]; __shared__ double redv[256]; __shared__ int redi[256];
  int i = blockIdx.x, j = threadIdx.x;
  const float* xi = xg + (size_t)i * 512;
  const float* xj = xg + (size_t)j * 512;
  double s = 0.;
  for (int c = 0; c < 512; ++c) s += (double)xi[c] * (double)xj[c];
  s /= (rn[i] * rn[j]);
  sc[j] = s; __syncthreads();
  for (int r = 0; r < 4; ++r) {
    redv[j] = sc[j]; redi[j] = j; __syncthreads();
    for (int st = 128; st > 0; st >>= 1) {
      if (j < st) {
        if (redv[j + st] > redv[j] || (redv[j + st] == redv[j] && redi[j + st] < redi[j])) {
          redv[j] = redv[j + st]; redi[j] = redi[j + st];
        }
      }
      __syncthreads();
    }
    if (j == 0) { idxb[i * 4 + r] = redi[0]; sc[redi[0]] = -1e300; }
    __syncthreads();
  }
}

// edge = mean of 4 gathered xg rows; writes fp32 + split
__global__ void edge_k_split(const float* __restrict__ xg, const int* __restrict__ idxb,
                             float* __restrict__ edge,
                             unsigned short* __restrict__ eH, unsigned short* __restrict__ eL){
  size_t idx = (size_t)blockIdx.x * 256 + threadIdx.x;
  int i = (int)(idx >> 9), c = (int)(idx & 511);
  const int* id = idxb + i * 4;
  float v = 0.25f * (xg[(size_t)id[0]*512 + c] + xg[(size_t)id[1]*512 + c] +
                     xg[(size_t)id[2]*512 + c] + xg[(size_t)id[3]*512 + c]);
  edge[idx] = v;
  unsigned short hh = f2bf(v);
  eH[idx] = hh; eL[idx] = f2bf(v - bf2f(hh));
}
// h1pn = xg + edge (split only)
__global__ void vadd_split(const float* __restrict__ a, const float* __restrict__ b,
                           unsigned short* __restrict__ oH, unsigned short* __restrict__ oL){
  size_t idx = (size_t)blockIdx.x * 256 + threadIdx.x;
  float v = a[idx] + b[idx];
  unsigned short hh = f2bf(v);
  oH[idx] = hh; oL[idx] = f2bf(v - bf2f(hh));
}
// h1pn2 = h1 + mean(h1[idx]) (split only)
__global__ void h1gather_split(const float* __restrict__ h1, const int* __restrict__ idxb,
                               unsigned short* __restrict__ oH, unsigned short* __restrict__ oL){
  size_t idx = (size_t)blockIdx.x * 256 + threadIdx.x;
  int i = (int)(idx >> 9), c = (int)(idx & 511);
  const int* id = idxb + i * 4;
  float v = h1[idx] + 0.25f * (h1[(size_t)id[0]*512 + c] + h1[(size_t)id[1]*512 + c] +
                               h1[(size_t)id[2]*512 + c] + h1[(size_t)id[3]*512 + c]);
  unsigned short hh = f2bf(v);
  oH[idx] = hh; oL[idx] = f2bf(v - bf2f(hh));
}

__global__ void logits2(const float* __restrict__ src, const float* __restrict__ w,
                        const float* __restrict__ bias, float* __restrict__ out){
  int rc = blockIdx.x; int r = rc >> 1, c = rc & 1;
  int t = threadIdx.x; // 64
  double s = 0.;
  for (int k = t; k < 512; k += 64) s += (double)src[(size_t)r * 512 + k] * (double)w[(size_t)c * 512 + k];
  for (int off = 32; off > 0; off >>= 1) s += __shfl_down(s, off);
  if (t == 0) out[rc] = (float)(s + (double)bias[c]);
}

__global__ void sentinel_k(float* out){ if (threadIdx.x < 12) out[threadIdx.x] = 1e30f; }

// ---------------- host-side nystrom block ----------------
struct NysBufs {
  float *qkv, *ql, *kl, *klT, *av, *zav, *merged;
  float *a2f32, *scal, *accp, *mlp;
  unsigned short *padH, *padL, *merH, *merL, *wqH, *wqL, *owH, *owL;
  unsigned short *a2H, *a2L;
  unsigned short *zAH, *zAL, *zATH, *zATL;
  unsigned short *zBH, *zBL, *zBTH, *zBTL;
  unsigned short *azH, *azL, *t1TH, *t1TL, *t2TH, *t2TL;
  unsigned short *avTH, *avTL;
  unsigned short *KsH, *KsL, *VTH, *VTL;
  unsigned short *klsH, *klsL, *zavTH, *zavTL;
};

static void run_nystrom(hipStream_t stream, float* hbuf,
                        const float* lng, const float* lnb, const float* qkvw,
                        const float* outw, const float* outb, const float* rk,
                        const NysBufs& w)
{
  ln_pad_split<<<BB * NPAD, 256, 0, stream>>>(hbuf, w.padH, w.padL, lng, lnb);
  split_k<<<(NT * DIM / 4 + 255) / 256, 256, 0, stream>>>(qkvw, w.wqH, w.wqL, NT * DIM / 4);
  gemm_mfma<<<dim3(NT/128, (BB*NPAD)/128), 256, 0, stream>>>(w.padH, w.padL, w.wqH, w.wqL,
                                                             nullptr, nullptr, w.qkv,
                                                             BB*NPAD, NT, DIM, 0, nullptr, nullptr);
  split_kcols<<<BB * NPAD * 128 / 256, 256, 0, stream>>>(w.qkv, w.KsH, w.KsL);
  transpose_split_v<<<dim3(NPAD/64, 16), 256, 0, stream>>>(w.qkv, w.VTH, w.VTL);
  landmark<<<BB * NH * LM, 64, 0, stream>>>(w.qkv, w.ql, w.kl);
  transpose_kl<<<dim3(LM/64, 16), 256, 0, stream>>>(w.kl, w.klT);
  split_k<<<(16 * LM * DH / 4 + 255) / 256, 256, 0, stream>>>(w.kl, w.klsH, w.klsL, 16 * LM * DH / 4);
  fa3v_kernel<<<dim3(17, 4, 16), 256, 0, stream>>>(w.KsH, w.KsL, w.VTH, w.VTL, w.ql, w.accp, w.mlp);
  fa3v_combine<<<64, 256, 0, stream>>>(w.accp, w.mlp, w.av);
  split_T_av<<<1024, 256, 0, stream>>>(w.av, w.avTH, w.avTL);
  a2_kernel<<<BB * NH * LM, 256, 0, stream>>>(w.ql, w.klT, w.a2f32);
  colrow_max<<<16, 256, 0, stream>>>(w.a2f32, w.scal);
  scal_red<<<1, 64, 0, stream>>>(w.scal);
  split_k<<<(16 * 65536 / 4 + 255) / 256, 256, 0, stream>>>(w.a2f32, w.a2H, w.a2L, 16 * 65536 / 4);
  z0_split<<<4096, 256, 0, stream>>>(w.a2f32, w.scal, w.zAH, w.zAL, w.zATH, w.zATL);
  const unsigned short *zcH = w.zAH, *zcL = w.zAL, *zcTH = w.zATH, *zcTL = w.zATL;
  unsigned short *znH = w.zBH, *znL = w.zBL, *znTH = w.zBTH, *znTL = w.zBTL;
  for (int it = 0; it < 6; ++it) {
    mm_mfma<<<dim3(8,8,16), 64, 0, stream>>>(w.a2H, w.a2L, zcTH, zcTL,
        w.azH, w.azL, nullptr, nullptr, w.t1TH, w.t1TL, nullptr, 256, 1.f, 0.f, 7.f);
    mm_mfma<<<dim3(8,8,16), 64, 0, stream>>>(w.azH, w.azL, w.t1TH, w.t1TL,
        nullptr, nullptr, w.t2TH, w.t2TL, nullptr, nullptr, nullptr, 256, -1.f, 15.f, 0.f);
    mm_mfma<<<dim3(8,8,16), 64, 0, stream>>>(w.azH, w.azL, w.t2TH, w.t2TL,
        nullptr, nullptr, w.t1TH, w.t1TL, nullptr, nullptr, nullptr, 256, -1.f, 13.f, 0.f);
    mm_mfma<<<dim3(8,8,16), 64, 0, stream>>>(zcH, zcL, w.t1TH, w.t1TL,
        znH, znL, znTH, znTL, nullptr, nullptr, nullptr, 256, 0.25f, 0.f, 0.f);
    const unsigned short* t;
    t = zcH; zcH = znH; znH = (unsigned short*)t;
    t = zcL; zcL = znL; znL = (unsigned short*)t;
    t = zcTH; zcTH = znTH; znTH = (unsigned short*)t;
    t = zcTL; zcTL = znTL; znTL = (unsigned short*)t;
  }
  mm_mfma<<<dim3(2,8,16), 64, 0, stream>>>(zcH, zcL, w.avTH, w.avTL,
      nullptr, nullptr, nullptr, nullptr, nullptr, nullptr, w.zav, 64, 1.f, 0.f, 0.f);
  split_T_av<<<1024, 256, 0, stream>>>(w.zav, w.zavTH, w.zavTL);
  conv_res<<<dim3(17, 32, 2), 256, 0, stream>>>(w.qkv, rk, w.merged);
  fa1_kernel<<<dim3(NPAD/64, 16), 256, 0, stream>>>(w.qkv, w.klsH, w.klsL, w.zavTH, w.zavTL,
                                                    w.merged, w.merH, w.merL);
  split_k<<<(DIM*DIM/4 + 255) / 256, 256, 0, stream>>>(outw, w.owH, w.owL, DIM*DIM/4);
  for (int b = 0; b < BB; ++b)
    gemm_mfma<<<dim3(DIM/128, (N1+127)/128), 256, 0, stream>>>(
        w.merH + ((size_t)b*NPAD + PADR)*DIM, w.merL + ((size_t)b*NPAD + PADR)*DIM,
        w.owH, w.owL, outb,
        hbuf + (size_t)b*N1*DIM, hbuf + (size_t)b*N1*DIM,
        N1, DIM, DIM, 0, nullptr, nullptr);
}

extern "C" void kernel_launch(void* const* d_in, const int* in_sizes, int n_in,
                              void* d_out, int out_size, void* d_ws, size_t ws_size,
                              hipStream_t stream) {
  (void)in_sizes; (void)n_in; (void)out_size;
  const float* x        = (const float*)d_in[0];
  const float* fc1_w    = (const float*)d_in[1];
  const float* fc1_b    = (const float*)d_in[2];
  const float* cls_tok  = (const float*)d_in[3];
  const float* ln1_g    = (const float*)d_in[4];
  const float* ln1_b    = (const float*)d_in[5];
  const float* qkv1_w   = (const float*)d_in[6];
  const float* out1_w   = (const float*)d_in[7];
  const float* out1_b   = (const float*)d_in[8];
  const float* res1_k   = (const float*)d_in[9];
  const float* ppeg_w7  = (const float*)d_in[10];
  const float* ppeg_b7  = (const float*)d_in[11];
  const float* ppeg_w5  = (const float*)d_in[12];
  const float* ppeg_b5  = (const float*)d_in[13];
  const float* ppeg_w3  = (const float*)d_in[14];
  const float* ppeg_b3  = (const float*)d_in[15];
  const float* ln2_g    = (const float*)d_in[16];
  const float* ln2_b    = (const float*)d_in[17];
  const float* qkv2_w   = (const float*)d_in[18];
  const float* out2_w   = (const float*)d_in[19];
  const float* out2_b   = (const float*)d_in[20];
  const float* res2_k   = (const float*)d_in[21];
  const float* norm_g   = (const float*)d_in[22];
  const float* norm_b   = (const float*)d_in[23];
  const float* fc2_w    = (const float*)d_in[24];
  const float* fc2_b    = (const float*)d_in[25];
  const float* dsl_w1   = (const float*)d_in[26];
  const float* dsl_b1   = (const float*)d_in[27];
  const float* dsl_w2   = (const float*)d_in[28];
  const float* dsl_b2   = (const float*)d_in[29];
  const float* gcn_w1   = (const float*)d_in[30];
  const float* gcn_we   = (const float*)d_in[31];
  const float* gcn_b1   = (const float*)d_in[32];
  const float* gcn_w2   = (const float*)d_in[33];
  const float* gcn_b2   = (const float*)d_in[34];
  const float* gcn_hw   = (const float*)d_in[35];
  const float* gcn_hb   = (const float*)d_in[36];
  const float* gcn_dw   = (const float*)d_in[37];
  const float* gcn_db   = (const float*)d_in[38];
  const float* rehearsal= (const float*)d_in[39];
  float* out = (float*)d_out;

  char* base = (char*)d_ws;
  size_t off = 0;
  auto takeb = [&](size_t bytes) { void* p = base + off; off += (bytes + 255) & ~(size_t)255; return p; };

  float* h    = (float*)takeb((size_t)BB * N1 * DIM * 4);
  float* h2   = (float*)takeb((size_t)BB * N1 * DIM * 4);
  NysBufs nb;
  nb.padH   = (unsigned short*)takeb((size_t)BB * NPAD * DIM * 2);
  nb.padL   = (unsigned short*)takeb((size_t)BB * NPAD * DIM * 2);
  nb.qkv    = (float*)takeb((size_t)BB * NPAD * NT * 4);
  nb.ql     = (float*)takeb((size_t)BB * NH * LM * DH * 4);
  nb.kl     = (float*)takeb((size_t)BB * NH * LM * DH * 4);
  nb.klT    = (float*)takeb((size_t)BB * NH * LM * DH * 4);
  nb.av     = (float*)takeb((size_t)BB * NH * LM * DH * 4);
  nb.zav    = (float*)takeb((size_t)BB * NH * LM * DH * 4);
  nb.merged = (float*)takeb((size_t)BB * NPAD * DIM * 4);
  nb.merH   = (unsigned short*)takeb((size_t)BB * NPAD * DIM * 2);
  nb.merL   = (unsigned short*)takeb((size_t)BB * NPAD * DIM * 2);
  nb.wqH    = (unsigned short*)takeb((size_t)NT * DIM * 2);
  nb.wqL    = (unsigned short*)takeb((size_t)NT * DIM * 2);
  nb.owH    = (unsigned short*)takeb((size_t)DIM * DIM * 2);
  nb.owL    = (unsigned short*)takeb((size_t)DIM * DIM * 2);
  nb.avTH   = (unsigned short*)takeb((size_t)16 * 64 * 256 * 2);
  nb.avTL   = (unsigned short*)takeb((size_t)16 * 64 * 256 * 2);
  nb.klsH   = (unsigned short*)takeb((size_t)16 * LM * DH * 2);
  nb.klsL   = (unsigned short*)takeb((size_t)16 * LM * DH * 2);
  nb.zavTH  = (unsigned short*)takeb((size_t)16 * 64 * 256 * 2);
  nb.zavTL  = (unsigned short*)takeb((size_t)16 * 64 * 256 * 2);
  nb.scal   = (float*)takeb(64 * 4);
  nb.mlp    = (float*)takeb((size_t)1088 * 128 * 4);
  float* hcls = (float*)takeb((size_t)BB * DIM * 4);
  float* xg1  = (float*)takeb((size_t)256 * 256 * 4);
  float* xg   = (float*)takeb((size_t)256 * 512 * 4);
  double* rn  = (double*)takeb(256 * 8);
  int*   idxb = (int*)takeb(1024 * 4);
  float* edge = (float*)takeb((size_t)256 * 512 * 4);
  float* h1g  = (float*)takeb((size_t)256 * 512 * 4);
  float* h2g  = (float*)takeb((size_t)256 * 512 * 4);
  unsigned short* xcH   = (unsigned short*)takeb((size_t)256 * 512 * 2);
  unsigned short* xcL   = (unsigned short*)takeb((size_t)256 * 512 * 2);
  unsigned short* dw1H  = (unsigned short*)takeb((size_t)256 * 512 * 2);
  unsigned short* dw1L  = (unsigned short*)takeb((size_t)256 * 512 * 2);
  unsigned short* xg1H  = (unsigned short*)takeb((size_t)256 * 256 * 2);
  unsigned short* xg1L  = (unsigned short*)takeb((size_t)256 * 256 * 2);
  unsigned short* dw2H  = (unsigned short*)takeb((size_t)512 * 256 * 2);
  unsigned short* dw2L  = (unsigned short*)takeb((size_t)512 * 256 * 2);
  unsigned short* h1pH  = (unsigned short*)takeb((size_t)256 * 512 * 2);
  unsigned short* h1pL  = (unsigned short*)takeb((size_t)256 * 512 * 2);
  unsigned short* gw1H  = (unsigned short*)takeb((size_t)512 * 512 * 2);
  unsigned short* gw1L  = (unsigned short*)takeb((size_t)512 * 512 * 2);
  unsigned short* edgeH = (unsigned short*)takeb((size_t)256 * 512 * 2);
  unsigned short* edgeL = (unsigned short*)takeb((size_t)256 * 512 * 2);
  unsigned short* gweH  = (unsigned short*)takeb((size_t)512 * 512 * 2);
  unsigned short* gweL  = (unsigned short*)takeb((size_t)512 * 512 * 2);
  unsigned short* h1p2H = (unsigned short*)takeb((size_t)256 * 512 * 2);
  unsigned short* h1p2L = (unsigned short*)takeb((size_t)256 * 512 * 2);
  unsigned short* gw2H  = (unsigned short*)takeb((size_t)512 * 512 * 2);
  unsigned short* gw2L  = (unsigned short*)takeb((size_t)512 * 512 * 2);

  const size_t MB2 = (size_t)16 * 65536;
  unsigned short* pr = nb.padH;
  nb.a2H  = pr;            nb.a2L  = pr + MB2;
  nb.zAH  = pr + 2*MB2;    nb.zAL  = pr + 3*MB2;
  nb.zATH = pr + 4*MB2;    nb.zATL = pr + 5*MB2;
  nb.azH  = pr + 6*MB2;    nb.azL  = pr + 7*MB2;
  unsigned short* mr = (unsigned short*)nb.merged;
  nb.zBH  = mr;            nb.zBL  = mr + MB2;
  nb.zBTH = mr + 2*MB2;    nb.zBTL = mr + 3*MB2;
  nb.t1TH = mr + 4*MB2;    nb.t1TL = mr + 5*MB2;
  nb.t2TH = mr + 6*MB2;    nb.t2TL = mr + 7*MB2;
  nb.a2f32 = (float*)(mr + 4*MB2);
  nb.accp  = nb.merged;
  nb.KsH = nb.padH;
  nb.KsL = nb.padL;
  nb.VTH = nb.merH;
  nb.VTL = nb.merL;

  if (ws_size < off) { sentinel_k<<<1, 64, 0, stream>>>(out); return; }

  // --- stage A: fc1 (MFMA split-bf16) + cls ---
  set_cls<<<1, 1024, 0, stream>>>(h, cls_tok);
  split_k<<<(BB*NSEQ*DIM/4 + 255) / 256, 256, 0, stream>>>(x, nb.merH, nb.merL, BB*NSEQ*DIM/4);
  split_k<<<(DIM*DIM/4 + 255) / 256, 256, 0, stream>>>(fc1_w, nb.owH, nb.owL, DIM*DIM/4);
  for (int b = 0; b < BB; ++b)
    gemm_mfma<<<dim3(DIM/128, NSEQ/128), 256, 0, stream>>>(
        nb.merH + (size_t)b*NSEQ*DIM, nb.merL + (size_t)b*NSEQ*DIM,
        nb.owH, nb.owL, fc1_b, nullptr,
        h + ((size_t)b*N1 + 1)*DIM, NSEQ, DIM, DIM, 1, nullptr, nullptr);
  // --- nystrom block 1 (residual into h) ---
  run_nystrom(stream, h, ln1_g, ln1_b, qkv1_w, out1_w, out1_b, res1_k, nb);

  // --- PPEG ---
  copy_cls<<<1, 1024, 0, stream>>>(h2, h);
  dwconv<<<dim3(16, 32, 2), 256, 0, stream>>>(h, ppeg_w7, ppeg_b7, ppeg_w5, ppeg_b5,
                                              ppeg_w3, ppeg_b3, h2);
  // --- nystrom block 2 (residual into h2) ---
  run_nystrom(stream, h2, ln2_g, ln2_b, qkv2_w, out2_w, out2_b, res2_k, nb);

  // --- final LN (row 0) + heads ---
  final_ln<<<BB, 256, 0, stream>>>(h2, norm_g, norm_b, hcls);
  logits2<<<4, 64, 0, stream>>>(hcls, fc2_w, fc2_b, out + 0);

  // --- GCN branch (MFMA split-bf16, barrier-free gemms) ---
  build_xc_split<<<512, 256, 0, stream>>>(hcls, rehearsal, xcH, xcL);
  split_k<<<(256*512/4 + 255) / 256, 256, 0, stream>>>(dsl_w1, dw1H, dw1L, 256*512/4);
  split_k<<<(512*256/4 + 255) / 256, 256, 0, stream>>>(dsl_w2, dw2H, dw2L, 512*256/4);
  split_k<<<(512*512/4 + 255) / 256, 256, 0, stream>>>(gcn_w1, gw1H, gw1L, 512*512/4);
  split_k<<<(512*512/4 + 255) / 256, 256, 0, stream>>>(gcn_we, gweH, gweL, 512*512/4);
  split_k<<<(512*512/4 + 255) / 256, 256, 0, stream>>>(gcn_w2, gw2H, gw2L, 512*512/4);
  gemm_mfma<<<dim3(2, 2), 256, 0, stream>>>(xcH, xcL, dw1H, dw1L, dsl_b1, nullptr,
                                            xg1, 256, 256, 512, 2, xg1H, xg1L);
  gemm_mfma<<<dim3(4, 2), 256, 0, stream>>>(xg1H, xg1L, dw2H, dw2L, dsl_b2, nullptr,
                                            xg, 256, 512, 256, 2, nullptr, nullptr);
  norms_k<<<256, 256, 0, stream>>>(xg, rn);
  topk_k<<<256, 256, 0, stream>>>(xg, rn, idxb);
  edge_k_split<<<512, 256, 0, stream>>>(xg, idxb, edge, edgeH, edgeL);
  vadd_split<<<512, 256, 0, stream>>>(xg, edge, h1pH, h1pL);
  gemm_mfma<<<dim3(4, 2), 256, 0, stream>>>(h1pH, h1pL, gw1H, gw1L, nullptr, nullptr,
                                            h1g, 256, 512, 512, 0, nullptr, nullptr);
  gemm_mfma<<<dim3(4, 2), 256, 0, stream>>>(edgeH, edgeL, gweH, gweL, gcn_b1, h1g,
                                            h1g, 256, 512, 512, 1, nullptr, nullptr);
  h1gather_split<<<512, 256, 0, stream>>>(h1g, idxb, h1p2H, h1p2L);
  gemm_mfma<<<dim3(4, 2), 256, 0, stream>>>(h1p2H, h1p2L, gw2H, gw2L, gcn_b2, nullptr,
                                            h2g, 256, 512, 512, 0, nullptr, nullptr);
  logits2<<<4, 64, 0, stream>>>(h2g, gcn_hw, gcn_hb, out + 4);
  logits2<<<4, 64, 0, stream>>>(h1g, gcn_dw, gcn_db, out + 8);
}